// Round 15
// baseline (174.837 us; speedup 1.0000x reference)
//
#include <hip/hip_runtime.h>
#include <math.h>

// Problem constants
#define B_  8
#define N_  196
#define C_  12
#define D_  768
#define H_  12
#define R_  (B_*N_*C_)      // 18816 rows
#define KDIM 768
#define NQKV_PAD 768        // 720 real qkv cols padded to 768

typedef _Float16 f16x8 __attribute__((ext_vector_type(8)));   // 8 f16 = 4 VGPR
typedef __attribute__((ext_vector_type(4))) float f32x4;

__device__ inline unsigned short f2h(float f) {
    union { _Float16 h; unsigned short u; } v; v.h = (_Float16)f; return v.u;
}
__device__ inline float h2f(unsigned short u) {
    union { unsigned short u; _Float16 h; } v; v.u = u; return (float)v.h;
}
__device__ inline unsigned packh2(float a, float b) {
    return (unsigned)f2h(a) | ((unsigned)f2h(b) << 16);
}

// ---------------------------------------------------------------------------
// fp32 -> f16 elementwise. n must be a multiple of 4.
// ---------------------------------------------------------------------------
__global__ __launch_bounds__(256) void convert_f16(
    const float* __restrict__ in, unsigned short* __restrict__ outh, int n)
{
    int i = (blockIdx.x * 256 + threadIdx.x) * 4;
    if (i >= n) return;
    float4 v = *reinterpret_cast<const float4*>(in + i);
    ushort4 h;
    h.x = f2h(v.x); h.y = f2h(v.y); h.z = f2h(v.z); h.w = f2h(v.w);
    *reinterpret_cast<ushort4*>(outh + i) = h;
}

// One launch: wqkv (packed 768x768, rows 720+ zero) and wp, single f16 each.
__global__ __launch_bounds__(256) void convert_weights(
    const float* __restrict__ wc, const float* __restrict__ ws,
    const float* __restrict__ wp,
    unsigned short* __restrict__ wqkv_h, unsigned short* __restrict__ wp_h)
{
    int i = (blockIdx.x * 256 + threadIdx.x) * 4;
    unsigned short* dh; float4 v; int off;
    if (i < 768 * 768) {
        const int r = i / 768, k = i % 768;
        v = make_float4(0.f, 0.f, 0.f, 0.f);
        if (r < 144)      v = *reinterpret_cast<const float4*>(wc + r * 768 + k);
        else if (r < 720) v = *reinterpret_cast<const float4*>(ws + (r - 144) * 768 + k);
        dh = wqkv_h; off = i;
    } else {
        off = i - 768 * 768;
        if (off >= 768 * 768) return;
        v = *reinterpret_cast<const float4*>(wp + off);
        dh = wp_h;
    }
    ushort4 h;
    h.x = f2h(v.x); h.y = f2h(v.y); h.z = f2h(v.z); h.w = f2h(v.w);
    *reinterpret_cast<ushort4*>(dh + off) = h;
}

// ---------------------------------------------------------------------------
// Plain single-f16 MFMA GEMM (r14-verified, unchanged).
// ---------------------------------------------------------------------------
#define BM 128
#define BN 128
#define BK 32

__device__ inline void gload16(const unsigned short* src, void* ldsbase) {
    __builtin_amdgcn_global_load_lds(
        (const __attribute__((address_space(1))) unsigned int*)src,
        (__attribute__((address_space(3))) unsigned int*)ldsbase, 16, 0, 0);
}

__global__ __launch_bounds__(256) void gemm_f16(
    const unsigned short* __restrict__ Ah, const unsigned short* __restrict__ Bh,
    const float* __restrict__ bias,
    float* __restrict__ outp, int M, int Nt, int K, int ntiles)
{
    __shared__ unsigned short sA[2][BM][BK], sB[2][BN][BK];

    const int nwg = gridDim.x;
    const int bid = blockIdx.x;
    const int xcd = bid & 7, slot = bid >> 3;
    const int q = nwg >> 3, r = nwg & 7;
    const int wg = (xcd < r ? xcd * (q + 1) : r * (q + 1) + (xcd - r) * q) + slot;
    const int mt = wg / ntiles, nt = wg - mt * ntiles;   // nt fast: A-panel reuse
    const int m0 = mt * BM, n0 = nt * BN;

    const int tid = threadIdx.x;
    const int w = tid >> 6, l = tid & 63;
    const int wr = (w >> 1) * 64, wc = (w & 1) * 64;

    f32x4 acc[4][4];
    #pragma unroll
    for (int i = 0; i < 4; ++i)
        #pragma unroll
        for (int j = 0; j < 4; ++j)
            acc[i][j] = (f32x4){0.f, 0.f, 0.f, 0.f};

    const int seg0 = w * 1024, seg1 = 4096 + w * 1024;
    const int o0 = seg0 + l * 16, o1 = seg1 + l * 16;
    const int r0 = o0 >> 6, c0 = (o0 & 63) >> 1;
    const int r1 = o1 >> 6, c1 = (o1 & 63) >> 1;

    const int lr = l & 15;
    const int kb = (l >> 4) * 8;

#define STAGE(buf, kk)                                                                   \
    gload16(Ah + (size_t)(m0 + r0) * K + (kk) + c0, (char*)sA + (buf) * 8192 + seg0);    \
    gload16(Ah + (size_t)(m0 + r1) * K + (kk) + c1, (char*)sA + (buf) * 8192 + seg1);    \
    gload16(Bh + (size_t)(n0 + r0) * K + (kk) + c0, (char*)sB + (buf) * 8192 + seg0);    \
    gload16(Bh + (size_t)(n0 + r1) * K + (kk) + c1, (char*)sB + (buf) * 8192 + seg1);

    STAGE(0, 0);                       // 4 loads in flight

    const int KT = K / BK;             // 24
    int cur = 0;
    for (int t = 0; t < KT; ++t) {
        if (t + 1 < KT) {
            STAGE(cur ^ 1, (t + 1) * BK);                      // +4 -> 8 in flight
            asm volatile("s_waitcnt vmcnt(4)" ::: "memory");   // drain tile t only
        } else {
            asm volatile("s_waitcnt vmcnt(0)" ::: "memory");
        }
        asm volatile("s_barrier" ::: "memory");                // tile t visible

        f16x8 ah[4];
        #pragma unroll
        for (int fm = 0; fm < 4; ++fm)
            ah[fm] = *reinterpret_cast<const f16x8*>(&sA[cur][wr + fm * 16 + lr][kb]);
        #pragma unroll
        for (int fn = 0; fn < 4; ++fn) {
            const f16x8 bf = *reinterpret_cast<const f16x8*>(&sB[cur][wc + fn * 16 + lr][kb]);
            #pragma unroll
            for (int fm = 0; fm < 4; ++fm)
                acc[fm][fn] = __builtin_amdgcn_mfma_f32_16x16x32_f16(ah[fm], bf, acc[fm][fn], 0, 0, 0);
        }
        asm volatile("s_barrier" ::: "memory");   // WAR fence before restaging [cur]
        cur ^= 1;
    }
#undef STAGE

    const int rg = (l >> 4) * 4;
    #pragma unroll
    for (int fm = 0; fm < 4; ++fm) {
        #pragma unroll
        for (int fn = 0; fn < 4; ++fn) {
            const int row = m0 + wr + fm * 16 + rg;
            const int col = n0 + wc + fn * 16 + lr;
            const float bv = bias ? bias[col] : 0.f;
            #pragma unroll
            for (int rr = 0; rr < 4; ++rr)
                outp[(size_t)(row + rr) * Nt + col] = acc[fm][fn][rr] + bv;
        }
    }
}

// ---------------------------------------------------------------------------
// MFMA spatial attention. THIS ROUND:
//  - P redistribution C-frag -> B-frag via 8x ds_bpermute (register-local,
//    per-j independent -> j-loop pipelines; Pb LDS buffer deleted)
//  - Bq[j] hoisted out of ch loop (28 -> 4 ds_reads)
//  - float4 staging (784 items instead of 3136 scalars)
//  - exp2 with log2(e) folded into Q scale (identical p values)
// Within 4-lane group {fl+16g}: target g needs local krows 8g..8g+7 =
//   {T0|T1 halves} of lanes srcA=fl+16*(2g&3), srcB=fl+16*((2g+1)&3),
//   taking T0-derived words (u0,u1) if g<2 else T1-derived (u2,u3).
// ---------------------------------------------------------------------------
__global__ __launch_bounds__(256) void spatial_attn_mfma(
    const float* __restrict__ qkv,
    float* __restrict__ xs_out)
{
    __shared__ unsigned short Kl[224][40];     // f16: Khi(0..15) Klo(16..31) pad
    __shared__ unsigned short Ql[208][24];     // f16: Q(0..15) pad
    __shared__ unsigned short Vt[16][232];     // f16 V^T [d][k]

    const int bid = blockIdx.x;                // 1152 = 8*12*12
    const int c = bid % 12;
    const int h = (bid / 12) % 12;
    const int b = bid / 144;
    const int tid = threadIdx.x;
    const int w = tid >> 6, l = tid & 63;
    const int fl = l & 15, g = l >> 4;

    // ---- staging: float4 loads, 784 items (n, 4-elem group) ----
    const float qs = 0.25f * 1.4426950408889634f;   // fold softmax scale * log2(e)
    for (int idx = tid; idx < N_ * 4; idx += 256) {
        const int n = idx >> 2, eq = (idx & 3) * 4;
        const float* base = qkv + (size_t)((b * N_ + n) * 12 + c) * NQKV_PAD + 144 + h * 16 + eq;
        const float4 qv = *reinterpret_cast<const float4*>(base);
        const float4 kv = *reinterpret_cast<const float4*>(base + 192);
        const float4 vv = *reinterpret_cast<const float4*>(base + 384);
        ushort4 qh;
        qh.x = f2h(qv.x * qs); qh.y = f2h(qv.y * qs);
        qh.z = f2h(qv.z * qs); qh.w = f2h(qv.w * qs);
        *reinterpret_cast<ushort4*>(&Ql[n][eq]) = qh;
        ushort4 kh, klo;
        kh.x = f2h(kv.x); klo.x = f2h(kv.x - h2f(kh.x));
        kh.y = f2h(kv.y); klo.y = f2h(kv.y - h2f(kh.y));
        kh.z = f2h(kv.z); klo.z = f2h(kv.z - h2f(kh.z));
        kh.w = f2h(kv.w); klo.w = f2h(kv.w - h2f(kh.w));
        *reinterpret_cast<ushort4*>(&Kl[n][eq])      = kh;
        *reinterpret_cast<ushort4*>(&Kl[n][16 + eq]) = klo;
        Vt[eq + 0][n] = f2h(vv.x);
        Vt[eq + 1][n] = f2h(vv.y);
        Vt[eq + 2][n] = f2h(vv.z);
        Vt[eq + 3][n] = f2h(vv.w);
    }
    for (int idx = tid; idx < 16 * 28; idx += 256) {
        const int d = idx / 28, n = 196 + idx % 28;
        Vt[d][n] = 0;
    }
    __syncthreads();

    f32x4 accO[4];
    float lsum[4];
    #pragma unroll
    for (int j = 0; j < 4; ++j) {
        accO[j] = (f32x4){0.f, 0.f, 0.f, 0.f};
        lsum[j] = 0.f;
    }
    const f32x4 zf = (f32x4){0.f, 0.f, 0.f, 0.f};

    // hoisted Q fragments (ch-invariant); clamp inactive rows in-bounds
    f16x8 Bq[4];
    #pragma unroll
    for (int j = 0; j < 4; ++j) {
        const int qt = w + 4 * j;
        const int qrow = (qt > 12 ? 12 : qt) * 16 + fl;
        Bq[j] = *reinterpret_cast<const f16x8*>(&Ql[qrow][8 * (g & 1)]);
    }

    // bpermute source lanes for P redistribution
    const int lA = fl + 16 * ((2 * g) & 3);
    const int lB = fl + 16 * ((2 * g + 1) & 3);

    for (int ch = 0; ch < 7; ++ch) {
        const int kb0 = ch * 32;
        const f16x8 A1a = *reinterpret_cast<const f16x8*>(&Kl[kb0 + fl][8 * g]);
        const f16x8 A1b = *reinterpret_cast<const f16x8*>(&Kl[kb0 + 16 + fl][8 * g]);
        const f16x8 Av  = *reinterpret_cast<const f16x8*>(&Vt[fl][kb0 + 8 * g]);

        #pragma unroll
        for (int j = 0; j < 4; ++j) {
            const int qt = w + 4 * j;
            if (qt > 12) continue;

            f32x4 T0 = __builtin_amdgcn_mfma_f32_16x16x32_f16(A1a, Bq[j], zf, 0, 0, 0);
            f32x4 T1 = __builtin_amdgcn_mfma_f32_16x16x32_f16(A1b, Bq[j], zf, 0, 0, 0);

            float s0 = T0[0], s1 = T0[1], s2 = T0[2], s3 = T0[3];
            float s4 = T1[0], s5 = T1[1], s6 = T1[2], s7 = T1[3];
            if (ch == 6) {                      // mask pad k-rows (exp2(-1e30)=0)
                const int kg = kb0 + 4 * g;
                if (kg + 0 >= 196) s0 = -1e30f;
                if (kg + 1 >= 196) s1 = -1e30f;
                if (kg + 2 >= 196) s2 = -1e30f;
                if (kg + 3 >= 196) s3 = -1e30f;
                s4 = -1e30f; s5 = -1e30f; s6 = -1e30f; s7 = -1e30f;
            }
            const float p0 = exp2f(s0), p1 = exp2f(s1);
            const float p2 = exp2f(s2), p3 = exp2f(s3);
            const float p4 = exp2f(s4), p5 = exp2f(s5);
            const float p6 = exp2f(s6), p7 = exp2f(s7);
            lsum[j] += ((p0 + p1) + (p2 + p3)) + ((p4 + p5) + (p6 + p7));

            // pack: u0,u1 = T0 krows (4g..4g+3); u2,u3 = T1 krows (16+4g..+3)
            const int u0 = (int)packh2(p0, p1);
            const int u1 = (int)packh2(p2, p3);
            const int u2 = (int)packh2(p4, p5);
            const int u3 = (int)packh2(p6, p7);

            // redistribute to B-frag: lane needs krows 8g..8g+7
            const int x0 = __shfl(u0, lA, 64), x1 = __shfl(u1, lA, 64);
            const int x2 = __shfl(u2, lA, 64), x3 = __shfl(u3, lA, 64);
            const int y0 = __shfl(u0, lB, 64), y1 = __shfl(u1, lB, 64);
            const int y2 = __shfl(u2, lB, 64), y3 = __shfl(u3, lB, 64);

            union { int i[4]; f16x8 v; } bp;
            bp.i[0] = (g < 2) ? x0 : x2;
            bp.i[1] = (g < 2) ? x1 : x3;
            bp.i[2] = (g < 2) ? y0 : y2;
            bp.i[3] = (g < 2) ? y1 : y3;

            accO[j] = __builtin_amdgcn_mfma_f32_16x16x32_f16(Av, bp.v, accO[j], 0, 0, 0);
        }
    }

    #pragma unroll
    for (int j = 0; j < 4; ++j) {
        const int qt = w + 4 * j;
        if (qt > 12) continue;
        float ls = lsum[j];
        ls += __shfl_xor(ls, 16);
        ls += __shfl_xor(ls, 32);
        const int n = qt * 16 + fl;
        if (n < 196) {
            const float inv = 1.f / ls;
            float4 o;
            o.x = accO[j][0] * inv; o.y = accO[j][1] * inv;
            o.z = accO[j][2] * inv; o.w = accO[j][3] * inv;
            const size_t base = ((size_t)((b * 12 + h) * N_ + n) * 12 + c) * 16 + 4 * g;
            *reinterpret_cast<float4*>(&xs_out[base]) = o;
        }
    }
}

// ---------------------------------------------------------------------------
// Channel attention + outer-product combine, 4 rows per 256-thread block.
// Emits y as single f16. (r14-verified, unchanged)
// ---------------------------------------------------------------------------
__global__ __launch_bounds__(256) void chan_attn_combine4(
    const float* __restrict__ qkv,
    const float* __restrict__ xs,
    unsigned short* __restrict__ yh)
{
    const int sub = threadIdx.x >> 6;
    const int t = threadIdx.x & 63;
    const int flat = blockIdx.x * 4 + sub;     // (b*12+h)*196 + n
    const int n = flat % 196;
    const int h = (flat / 196) % 12;
    const int b = flat / 2352;

    __shared__ float sQ[4][12][4], sK[4][12][4], sV[4][12][4], sXc[4][12][4];
    __shared__ float sXs[4][12][16];

    for (int idx = t; idx < 144; idx += 64) {
        const int c = idx / 12, rem = idx % 12, s = rem >> 2, e = rem & 3;
        const float v = qkv[(size_t)((b * N_ + n) * 12 + c) * NQKV_PAD + s * 48 + h * 4 + e];
        if (s == 0) sQ[sub][c][e] = v;
        else if (s == 1) sK[sub][c][e] = v;
        else sV[sub][c][e] = v;
    }
    for (int idx = t; idx < 192; idx += 64) {
        const int c = idx >> 4, j = idx & 15;
        sXs[sub][c][j] = xs[((size_t)flat * 12 + c) * 16 + j];
    }
    __syncthreads();

    if (t < 12) {
        const int c = t;
        float s[12];
        float m = -INFINITY;
        #pragma unroll
        for (int c2 = 0; c2 < 12; ++c2) {
            float d = 0.f;
            #pragma unroll
            for (int e = 0; e < 4; ++e) d += sQ[sub][c][e] * sK[sub][c2][e];
            s[c2] = d * 0.5f;
            m = fmaxf(m, s[c2]);
        }
        float lsum = 0.f;
        #pragma unroll
        for (int c2 = 0; c2 < 12; ++c2) { s[c2] = __expf(s[c2] - m); lsum += s[c2]; }
        const float inv = 1.f / lsum;
        #pragma unroll
        for (int i = 0; i < 4; ++i) {
            float a = 0.f;
            #pragma unroll
            for (int c2 = 0; c2 < 12; ++c2) a += s[c2] * sV[sub][c2][i];
            sXc[sub][c][i] = a * inv;
        }
    }
    __syncthreads();

    const size_t yrow = ((size_t)(b * N_ + n) * 12 + h) * (size_t)D_;
    #pragma unroll
    for (int k = 0; k < 12; ++k) {
        const float v = sXc[sub][k][t >> 4] * sXs[sub][k][t & 15];
        yh[yrow + k * 64 + t] = f2h(v);
    }
}

// ---------------------------------------------------------------------------
extern "C" void kernel_launch(void* const* d_in, const int* in_sizes, int n_in,
                              void* d_out, int out_size, void* d_ws, size_t ws_size,
                              hipStream_t stream) {
    const float* x       = (const float*)d_in[0];
    const float* w_qkv_c = (const float*)d_in[1];
    const float* w_qkv_s = (const float*)d_in[2];
    const float* w_proj  = (const float*)d_in[3];
    const float* b_proj  = (const float*)d_in[4];
    float* out = (float*)d_out;

    unsigned short* xh     = (unsigned short*)d_ws;               // R x 768 f16
    unsigned short* wqkv_h = xh + (size_t)R_ * KDIM;              // 768 x 768
    unsigned short* wp_h   = wqkv_h + (size_t)768 * 768;
    float* qkv = (float*)(wp_h + (size_t)768 * 768);              // R x 768 fp32
    float* xs  = qkv + (size_t)R_ * NQKV_PAD;
    unsigned short* yh = xh;   // alias: x f16 dead after qkv GEMM

    convert_f16<<<(R_ * KDIM) / 1024, 256, 0, stream>>>(x, xh, R_ * KDIM);
    convert_weights<<<(2 * 768 * 768) / 1024, 256, 0, stream>>>(
        w_qkv_c, w_qkv_s, w_proj, wqkv_h, wp_h);

    {
        const int mtiles = R_ / BM, ntiles = NQKV_PAD / BN;
        gemm_f16<<<mtiles * ntiles, 256, 0, stream>>>(
            xh, wqkv_h, nullptr, qkv, R_, NQKV_PAD, KDIM, ntiles);
    }
    spatial_attn_mfma<<<B_ * H_ * C_, 256, 0, stream>>>(qkv, xs);
    chan_attn_combine4<<<(B_ * H_ * N_) / 4, 256, 0, stream>>>(qkv, xs, yh);
    {
        const int mtiles = R_ / BM, ntiles = D_ / BN;
        gemm_f16<<<mtiles * ntiles, 256, 0, stream>>>(
            yh, wp_h, b_proj, out, R_, D_, KDIM, ntiles);
    }
}

// Round 18
// 155.864 us; speedup vs baseline: 1.1217x; 1.1217x over previous
//
#include <hip/hip_runtime.h>
#include <math.h>

// Problem constants
#define B_  8
#define N_  196
#define C_  12
#define D_  768
#define H_  12
#define R_  (B_*N_*C_)      // 18816 rows
#define KDIM 768
#define NQKV_PAD 768        // 720 real qkv cols padded to 768

typedef _Float16 f16x8 __attribute__((ext_vector_type(8)));   // 8 f16 = 4 VGPR
typedef __attribute__((ext_vector_type(4))) float f32x4;

__device__ inline unsigned short f2h(float f) {
    union { _Float16 h; unsigned short u; } v; v.h = (_Float16)f; return v.u;
}
__device__ inline float h2f(unsigned short u) {
    union { unsigned short u; _Float16 h; } v; v.u = u; return (float)v.h;
}
__device__ inline unsigned packh2(float a, float b) {
    return (unsigned)f2h(a) | ((unsigned)f2h(b) << 16);
}

// ---------------------------------------------------------------------------
// fp32 -> f16 elementwise. n must be a multiple of 4.
// ---------------------------------------------------------------------------
__global__ __launch_bounds__(256) void convert_f16(
    const float* __restrict__ in, unsigned short* __restrict__ outh, int n)
{
    int i = (blockIdx.x * 256 + threadIdx.x) * 4;
    if (i >= n) return;
    float4 v = *reinterpret_cast<const float4*>(in + i);
    ushort4 h;
    h.x = f2h(v.x); h.y = f2h(v.y); h.z = f2h(v.z); h.w = f2h(v.w);
    *reinterpret_cast<ushort4*>(outh + i) = h;
}

// One launch: wqkv (packed 768x768, rows 720+ zero) and wp, single f16 each.
__global__ __launch_bounds__(256) void convert_weights(
    const float* __restrict__ wc, const float* __restrict__ ws,
    const float* __restrict__ wp,
    unsigned short* __restrict__ wqkv_h, unsigned short* __restrict__ wp_h)
{
    int i = (blockIdx.x * 256 + threadIdx.x) * 4;
    unsigned short* dh; float4 v; int off;
    if (i < 768 * 768) {
        const int r = i / 768, k = i % 768;
        v = make_float4(0.f, 0.f, 0.f, 0.f);
        if (r < 144)      v = *reinterpret_cast<const float4*>(wc + r * 768 + k);
        else if (r < 720) v = *reinterpret_cast<const float4*>(ws + (r - 144) * 768 + k);
        dh = wqkv_h; off = i;
    } else {
        off = i - 768 * 768;
        if (off >= 768 * 768) return;
        v = *reinterpret_cast<const float4*>(wp + off);
        dh = wp_h;
    }
    ushort4 h;
    h.x = f2h(v.x); h.y = f2h(v.y); h.z = f2h(v.z); h.w = f2h(v.w);
    *reinterpret_cast<ushort4*>(dh + off) = h;
}

// ---------------------------------------------------------------------------
// Single-f16 MFMA GEMM, BK=64 (12 K-steps, 32 MFMA/step/wave) with
// both-sides XOR chunk swizzle (rule #21 / m201 pattern):
//   linear LDS dest; SOURCE chunk = (l&7)^(l>>3); READ col = ((ks*4+g)^(fl&7))*8
//   -> 16 lanes spread over 8 chunk-slots = 2-way bank access (free, m136).
// Per-buffer size = 128*64*2 = 16384 B (r17 bug was buf*32768 — OOB into sB).
// 2-phase dbuf (LDS 64KB), counted vmcnt(8), chunked XCD swizzle, nt-fast.
// ---------------------------------------------------------------------------
#define BM 128
#define BN 128
#define BK 64

__device__ inline void gload16(const unsigned short* src, void* ldsbase) {
    __builtin_amdgcn_global_load_lds(
        (const __attribute__((address_space(1))) unsigned int*)src,
        (__attribute__((address_space(3))) unsigned int*)ldsbase, 16, 0, 0);
}

__global__ __launch_bounds__(256) void gemm_f16(
    const unsigned short* __restrict__ Ah, const unsigned short* __restrict__ Bh,
    const float* __restrict__ bias,
    float* __restrict__ outp, int M, int Nt, int K, int ntiles)
{
    __shared__ unsigned short sA[2][BM][BK];   // 2 x 16 KB
    __shared__ unsigned short sB[2][BN][BK];   // 2 x 16 KB

    const int nwg = gridDim.x;
    const int bid = blockIdx.x;
    const int xcd = bid & 7, slot = bid >> 3;
    const int q = nwg >> 3, r = nwg & 7;
    const int wg = (xcd < r ? xcd * (q + 1) : r * (q + 1) + (xcd - r) * q) + slot;
    const int mt = wg / ntiles, nt = wg - mt * ntiles;   // nt fast: A-panel reuse
    const int m0 = mt * BM, n0 = nt * BN;

    const int tid = threadIdx.x;
    const int w = tid >> 6, l = tid & 63;
    const int fl = l & 15, g = l >> 4;
    const int wr = (w >> 1) * 64, wc = (w & 1) * 64;

    f32x4 acc[4][4];
    #pragma unroll
    for (int i = 0; i < 4; ++i)
        #pragma unroll
        for (int j = 0; j < 4; ++j)
            acc[i][j] = (f32x4){0.f, 0.f, 0.f, 0.f};

    // staging: tile [128][64] = 16KB/array; wave w covers rows w*32..w*32+31
    // via 4 insts of 1KB. dest linear: row = w*32 + i*8 + (l>>3), chunk = l&7.
    // source chunk pre-swizzled so LDS[row][cb] holds source chunk cb^(row&7).
    const int srow = w * 32 + (l >> 3);
    const int scol = ((l & 7) ^ (l >> 3)) * 8;     // source element offset

#define STAGE(buf, kk) {                                                                    \
    const unsigned short* pa = Ah + (size_t)(m0 + srow) * K + (kk) + scol;                  \
    const unsigned short* pb = Bh + (size_t)(n0 + srow) * K + (kk) + scol;                  \
    char* da = (char*)sA + (buf) * 16384 + w * 4096;                                        \
    char* db = (char*)sB + (buf) * 16384 + w * 4096;                                        \
    gload16(pa,           da);                                                              \
    gload16(pa +  8 * K,  da + 1024);                                                       \
    gload16(pa + 16 * K,  da + 2048);                                                       \
    gload16(pa + 24 * K,  da + 3072);                                                       \
    gload16(pb,           db);                                                              \
    gload16(pb +  8 * K,  db + 1024);                                                       \
    gload16(pb + 16 * K,  db + 2048);                                                       \
    gload16(pb + 24 * K,  db + 3072); }

    STAGE(0, 0);                       // 8 loads in flight

    const int KT = K / BK;             // 12
    int cur = 0;
    for (int t = 0; t < KT; ++t) {
        if (t + 1 < KT) {
            STAGE(cur ^ 1, (t + 1) * BK);                      // +8 -> 16 in flight
            asm volatile("s_waitcnt vmcnt(8)" ::: "memory");   // drain tile t only
        } else {
            asm volatile("s_waitcnt vmcnt(0)" ::: "memory");
        }
        asm volatile("s_barrier" ::: "memory");                // tile t visible

        #pragma unroll
        for (int ks = 0; ks < 2; ++ks) {
            const int rcol = ((ks * 4 + g) ^ (fl & 7)) * 8;    // swizzled read col
            f16x8 ah[4];
            #pragma unroll
            for (int fm = 0; fm < 4; ++fm)
                ah[fm] = *reinterpret_cast<const f16x8*>(&sA[cur][wr + fm * 16 + fl][rcol]);
            #pragma unroll
            for (int fn = 0; fn < 4; ++fn) {
                const f16x8 bf = *reinterpret_cast<const f16x8*>(&sB[cur][wc + fn * 16 + fl][rcol]);
                #pragma unroll
                for (int fm = 0; fm < 4; ++fm)
                    acc[fm][fn] = __builtin_amdgcn_mfma_f32_16x16x32_f16(ah[fm], bf, acc[fm][fn], 0, 0, 0);
            }
        }
        asm volatile("s_barrier" ::: "memory");   // WAR fence before restaging [cur]
        cur ^= 1;
    }
#undef STAGE

    const int rg = g * 4;
    #pragma unroll
    for (int fm = 0; fm < 4; ++fm) {
        #pragma unroll
        for (int fn = 0; fn < 4; ++fn) {
            const int row = m0 + wr + fm * 16 + rg;
            const int col = n0 + wc + fn * 16 + fl;
            const float bv = bias ? bias[col] : 0.f;
            #pragma unroll
            for (int rr = 0; rr < 4; ++rr)
                outp[(size_t)(row + rr) * Nt + col] = acc[fm][fn][rr] + bv;
        }
    }
}

// ---------------------------------------------------------------------------
// MFMA spatial attention (r15-verified: bpermute P-redistribution, hoisted Bq,
// float4 staging, exp2). Unchanged.
// ---------------------------------------------------------------------------
__global__ __launch_bounds__(256) void spatial_attn_mfma(
    const float* __restrict__ qkv,
    float* __restrict__ xs_out)
{
    __shared__ unsigned short Kl[224][40];     // f16: Khi(0..15) Klo(16..31) pad
    __shared__ unsigned short Ql[208][24];     // f16: Q(0..15) pad
    __shared__ unsigned short Vt[16][232];     // f16 V^T [d][k]

    const int bid = blockIdx.x;                // 1152 = 8*12*12
    const int c = bid % 12;
    const int h = (bid / 12) % 12;
    const int b = bid / 144;
    const int tid = threadIdx.x;
    const int w = tid >> 6, l = tid & 63;
    const int fl = l & 15, g = l >> 4;

    const float qs = 0.25f * 1.4426950408889634f;   // softmax scale * log2(e)
    for (int idx = tid; idx < N_ * 4; idx += 256) {
        const int n = idx >> 2, eq = (idx & 3) * 4;
        const float* base = qkv + (size_t)((b * N_ + n) * 12 + c) * NQKV_PAD + 144 + h * 16 + eq;
        const float4 qv = *reinterpret_cast<const float4*>(base);
        const float4 kv = *reinterpret_cast<const float4*>(base + 192);
        const float4 vv = *reinterpret_cast<const float4*>(base + 384);
        ushort4 qh;
        qh.x = f2h(qv.x * qs); qh.y = f2h(qv.y * qs);
        qh.z = f2h(qv.z * qs); qh.w = f2h(qv.w * qs);
        *reinterpret_cast<ushort4*>(&Ql[n][eq]) = qh;
        ushort4 kh, klo;
        kh.x = f2h(kv.x); klo.x = f2h(kv.x - h2f(kh.x));
        kh.y = f2h(kv.y); klo.y = f2h(kv.y - h2f(kh.y));
        kh.z = f2h(kv.z); klo.z = f2h(kv.z - h2f(kh.z));
        kh.w = f2h(kv.w); klo.w = f2h(kv.w - h2f(kh.w));
        *reinterpret_cast<ushort4*>(&Kl[n][eq])      = kh;
        *reinterpret_cast<ushort4*>(&Kl[n][16 + eq]) = klo;
        Vt[eq + 0][n] = f2h(vv.x);
        Vt[eq + 1][n] = f2h(vv.y);
        Vt[eq + 2][n] = f2h(vv.z);
        Vt[eq + 3][n] = f2h(vv.w);
    }
    for (int idx = tid; idx < 16 * 28; idx += 256) {
        const int d = idx / 28, n = 196 + idx % 28;
        Vt[d][n] = 0;
    }
    __syncthreads();

    f32x4 accO[4];
    float lsum[4];
    #pragma unroll
    for (int j = 0; j < 4; ++j) {
        accO[j] = (f32x4){0.f, 0.f, 0.f, 0.f};
        lsum[j] = 0.f;
    }
    const f32x4 zf = (f32x4){0.f, 0.f, 0.f, 0.f};

    f16x8 Bq[4];
    #pragma unroll
    for (int j = 0; j < 4; ++j) {
        const int qt = w + 4 * j;
        const int qrow = (qt > 12 ? 12 : qt) * 16 + fl;
        Bq[j] = *reinterpret_cast<const f16x8*>(&Ql[qrow][8 * (g & 1)]);
    }

    const int lA = fl + 16 * ((2 * g) & 3);
    const int lB = fl + 16 * ((2 * g + 1) & 3);

    for (int ch = 0; ch < 7; ++ch) {
        const int kb0 = ch * 32;
        const f16x8 A1a = *reinterpret_cast<const f16x8*>(&Kl[kb0 + fl][8 * g]);
        const f16x8 A1b = *reinterpret_cast<const f16x8*>(&Kl[kb0 + 16 + fl][8 * g]);
        const f16x8 Av  = *reinterpret_cast<const f16x8*>(&Vt[fl][kb0 + 8 * g]);

        #pragma unroll
        for (int j = 0; j < 4; ++j) {
            const int qt = w + 4 * j;
            if (qt > 12) continue;

            f32x4 T0 = __builtin_amdgcn_mfma_f32_16x16x32_f16(A1a, Bq[j], zf, 0, 0, 0);
            f32x4 T1 = __builtin_amdgcn_mfma_f32_16x16x32_f16(A1b, Bq[j], zf, 0, 0, 0);

            float s0 = T0[0], s1 = T0[1], s2 = T0[2], s3 = T0[3];
            float s4 = T1[0], s5 = T1[1], s6 = T1[2], s7 = T1[3];
            if (ch == 6) {                      // mask pad k-rows (exp2(-1e30)=0)
                const int kg = kb0 + 4 * g;
                if (kg + 0 >= 196) s0 = -1e30f;
                if (kg + 1 >= 196) s1 = -1e30f;
                if (kg + 2 >= 196) s2 = -1e30f;
                if (kg + 3 >= 196) s3 = -1e30f;
                s4 = -1e30f; s5 = -1e30f; s6 = -1e30f; s7 = -1e30f;
            }
            const float p0 = exp2f(s0), p1 = exp2f(s1);
            const float p2 = exp2f(s2), p3 = exp2f(s3);
            const float p4 = exp2f(s4), p5 = exp2f(s5);
            const float p6 = exp2f(s6), p7 = exp2f(s7);
            lsum[j] += ((p0 + p1) + (p2 + p3)) + ((p4 + p5) + (p6 + p7));

            const int u0 = (int)packh2(p0, p1);
            const int u1 = (int)packh2(p2, p3);
            const int u2 = (int)packh2(p4, p5);
            const int u3 = (int)packh2(p6, p7);

            const int x0 = __shfl(u0, lA, 64), x1 = __shfl(u1, lA, 64);
            const int x2 = __shfl(u2, lA, 64), x3 = __shfl(u3, lA, 64);
            const int y0 = __shfl(u0, lB, 64), y1 = __shfl(u1, lB, 64);
            const int y2 = __shfl(u2, lB, 64), y3 = __shfl(u3, lB, 64);

            union { int i[4]; f16x8 v; } bp;
            bp.i[0] = (g < 2) ? x0 : x2;
            bp.i[1] = (g < 2) ? x1 : x3;
            bp.i[2] = (g < 2) ? y0 : y2;
            bp.i[3] = (g < 2) ? y1 : y3;

            accO[j] = __builtin_amdgcn_mfma_f32_16x16x32_f16(Av, bp.v, accO[j], 0, 0, 0);
        }
    }

    #pragma unroll
    for (int j = 0; j < 4; ++j) {
        const int qt = w + 4 * j;
        if (qt > 12) continue;
        float ls = lsum[j];
        ls += __shfl_xor(ls, 16);
        ls += __shfl_xor(ls, 32);
        const int n = qt * 16 + fl;
        if (n < 196) {
            const float inv = 1.f / ls;
            float4 o;
            o.x = accO[j][0] * inv; o.y = accO[j][1] * inv;
            o.z = accO[j][2] * inv; o.w = accO[j][3] * inv;
            const size_t base = ((size_t)((b * 12 + h) * N_ + n) * 12 + c) * 16 + 4 * g;
            *reinterpret_cast<float4*>(&xs_out[base]) = o;
        }
    }
}

// ---------------------------------------------------------------------------
// Channel attention + outer-product combine, 4 rows per 256-thread block.
// Emits y as single f16. (r14-verified, unchanged)
// ---------------------------------------------------------------------------
__global__ __launch_bounds__(256) void chan_attn_combine4(
    const float* __restrict__ qkv,
    const float* __restrict__ xs,
    unsigned short* __restrict__ yh)
{
    const int sub = threadIdx.x >> 6;
    const int t = threadIdx.x & 63;
    const int flat = blockIdx.x * 4 + sub;     // (b*12+h)*196 + n
    const int n = flat % 196;
    const int h = (flat / 196) % 12;
    const int b = flat / 2352;

    __shared__ float sQ[4][12][4], sK[4][12][4], sV[4][12][4], sXc[4][12][4];
    __shared__ float sXs[4][12][16];

    for (int idx = t; idx < 144; idx += 64) {
        const int c = idx / 12, rem = idx % 12, s = rem >> 2, e = rem & 3;
        const float v = qkv[(size_t)((b * N_ + n) * 12 + c) * NQKV_PAD + s * 48 + h * 4 + e];
        if (s == 0) sQ[sub][c][e] = v;
        else if (s == 1) sK[sub][c][e] = v;
        else sV[sub][c][e] = v;
    }
    for (int idx = t; idx < 192; idx += 64) {
        const int c = idx >> 4, j = idx & 15;
        sXs[sub][c][j] = xs[((size_t)flat * 12 + c) * 16 + j];
    }
    __syncthreads();

    if (t < 12) {
        const int c = t;
        float s[12];
        float m = -INFINITY;
        #pragma unroll
        for (int c2 = 0; c2 < 12; ++c2) {
            float d = 0.f;
            #pragma unroll
            for (int e = 0; e < 4; ++e) d += sQ[sub][c][e] * sK[sub][c2][e];
            s[c2] = d * 0.5f;
            m = fmaxf(m, s[c2]);
        }
        float lsum = 0.f;
        #pragma unroll
        for (int c2 = 0; c2 < 12; ++c2) { s[c2] = __expf(s[c2] - m); lsum += s[c2]; }
        const float inv = 1.f / lsum;
        #pragma unroll
        for (int i = 0; i < 4; ++i) {
            float a = 0.f;
            #pragma unroll
            for (int c2 = 0; c2 < 12; ++c2) a += s[c2] * sV[sub][c2][i];
            sXc[sub][c][i] = a * inv;
        }
    }
    __syncthreads();

    const size_t yrow = ((size_t)(b * N_ + n) * 12 + h) * (size_t)D_;
    #pragma unroll
    for (int k = 0; k < 12; ++k) {
        const float v = sXc[sub][k][t >> 4] * sXs[sub][k][t & 15];
        yh[yrow + k * 64 + t] = f2h(v);
    }
}

// ---------------------------------------------------------------------------
extern "C" void kernel_launch(void* const* d_in, const int* in_sizes, int n_in,
                              void* d_out, int out_size, void* d_ws, size_t ws_size,
                              hipStream_t stream) {
    const float* x       = (const float*)d_in[0];
    const float* w_qkv_c = (const float*)d_in[1];
    const float* w_qkv_s = (const float*)d_in[2];
    const float* w_proj  = (const float*)d_in[3];
    const float* b_proj  = (const float*)d_in[4];
    float* out = (float*)d_out;

    unsigned short* xh     = (unsigned short*)d_ws;               // R x 768 f16
    unsigned short* wqkv_h = xh + (size_t)R_ * KDIM;              // 768 x 768
    unsigned short* wp_h   = wqkv_h + (size_t)768 * 768;
    float* qkv = (float*)(wp_h + (size_t)768 * 768);              // R x 768 fp32
    float* xs  = qkv + (size_t)R_ * NQKV_PAD;
    unsigned short* yh = xh;   // alias: x f16 dead after qkv GEMM

    convert_f16<<<(R_ * KDIM) / 1024, 256, 0, stream>>>(x, xh, R_ * KDIM);
    convert_weights<<<(2 * 768 * 768) / 1024, 256, 0, stream>>>(
        w_qkv_c, w_qkv_s, w_proj, wqkv_h, wp_h);

    {
        const int mtiles = R_ / BM, ntiles = NQKV_PAD / BN;
        gemm_f16<<<mtiles * ntiles, 256, 0, stream>>>(
            xh, wqkv_h, nullptr, qkv, R_, NQKV_PAD, KDIM, ntiles);
    }
    spatial_attn_mfma<<<B_ * H_ * C_, 256, 0, stream>>>(qkv, xs);
    chan_attn_combine4<<<(B_ * H_ * N_) / 4, 256, 0, stream>>>(qkv, xs, yh);
    {
        const int mtiles = R_ / BM, ntiles = D_ / BN;
        gemm_f16<<<mtiles * ntiles, 256, 0, stream>>>(
            yh, wp_h, b_proj, out, R_, D_, KDIM, ntiles);
    }
}

// Round 19
// 153.683 us; speedup vs baseline: 1.1376x; 1.0142x over previous
//
#include <hip/hip_runtime.h>
#include <math.h>

// Problem constants
#define B_  8
#define N_  196
#define C_  12
#define D_  768
#define H_  12
#define R_  (B_*N_*C_)      // 18816 rows
#define KDIM 768
#define NQKV_PAD 768        // 720 real qkv cols padded to 768

typedef _Float16 f16x8 __attribute__((ext_vector_type(8)));   // 8 f16 = 4 VGPR
typedef _Float16 f16x4 __attribute__((ext_vector_type(4)));   // 4 f16 = 2 VGPR
typedef __attribute__((ext_vector_type(4))) float f32x4;

__device__ inline unsigned short f2h(float f) {
    union { _Float16 h; unsigned short u; } v; v.h = (_Float16)f; return v.u;
}
__device__ inline float h2f(unsigned short u) {
    union { unsigned short u; _Float16 h; } v; v.u = u; return (float)v.h;
}
__device__ inline unsigned packh2(float a, float b) {
    return (unsigned)f2h(a) | ((unsigned)f2h(b) << 16);
}

// ---------------------------------------------------------------------------
// fp32 -> f16 elementwise. n must be a multiple of 4.
// ---------------------------------------------------------------------------
__global__ __launch_bounds__(256) void convert_f16(
    const float* __restrict__ in, unsigned short* __restrict__ outh, int n)
{
    int i = (blockIdx.x * 256 + threadIdx.x) * 4;
    if (i >= n) return;
    float4 v = *reinterpret_cast<const float4*>(in + i);
    ushort4 h;
    h.x = f2h(v.x); h.y = f2h(v.y); h.z = f2h(v.z); h.w = f2h(v.w);
    *reinterpret_cast<ushort4*>(outh + i) = h;
}

// One launch: wqkv (packed 768x768, rows 720+ zero) and wp, single f16 each.
__global__ __launch_bounds__(256) void convert_weights(
    const float* __restrict__ wc, const float* __restrict__ ws,
    const float* __restrict__ wp,
    unsigned short* __restrict__ wqkv_h, unsigned short* __restrict__ wp_h)
{
    int i = (blockIdx.x * 256 + threadIdx.x) * 4;
    unsigned short* dh; float4 v; int off;
    if (i < 768 * 768) {
        const int r = i / 768, k = i % 768;
        v = make_float4(0.f, 0.f, 0.f, 0.f);
        if (r < 144)      v = *reinterpret_cast<const float4*>(wc + r * 768 + k);
        else if (r < 720) v = *reinterpret_cast<const float4*>(ws + (r - 144) * 768 + k);
        dh = wqkv_h; off = i;
    } else {
        off = i - 768 * 768;
        if (off >= 768 * 768) return;
        v = *reinterpret_cast<const float4*>(wp + off);
        dh = wp_h;
    }
    ushort4 h;
    h.x = f2h(v.x); h.y = f2h(v.y); h.z = f2h(v.z); h.w = f2h(v.w);
    *reinterpret_cast<ushort4*>(dh + off) = h;
}

// ---------------------------------------------------------------------------
// Single-f16 MFMA GEMM, BK=64 (r18-verified). Unchanged.
// ---------------------------------------------------------------------------
#define BM 128
#define BN 128
#define BK 64

__device__ inline void gload16(const unsigned short* src, void* ldsbase) {
    __builtin_amdgcn_global_load_lds(
        (const __attribute__((address_space(1))) unsigned int*)src,
        (__attribute__((address_space(3))) unsigned int*)ldsbase, 16, 0, 0);
}

__global__ __launch_bounds__(256) void gemm_f16(
    const unsigned short* __restrict__ Ah, const unsigned short* __restrict__ Bh,
    const float* __restrict__ bias,
    float* __restrict__ outp, int M, int Nt, int K, int ntiles)
{
    __shared__ unsigned short sA[2][BM][BK];   // 2 x 16 KB
    __shared__ unsigned short sB[2][BN][BK];   // 2 x 16 KB

    const int nwg = gridDim.x;
    const int bid = blockIdx.x;
    const int xcd = bid & 7, slot = bid >> 3;
    const int q = nwg >> 3, r = nwg & 7;
    const int wg = (xcd < r ? xcd * (q + 1) : r * (q + 1) + (xcd - r) * q) + slot;
    const int mt = wg / ntiles, nt = wg - mt * ntiles;   // nt fast: A-panel reuse
    const int m0 = mt * BM, n0 = nt * BN;

    const int tid = threadIdx.x;
    const int w = tid >> 6, l = tid & 63;
    const int fl = l & 15, g = l >> 4;
    const int wr = (w >> 1) * 64, wc = (w & 1) * 64;

    f32x4 acc[4][4];
    #pragma unroll
    for (int i = 0; i < 4; ++i)
        #pragma unroll
        for (int j = 0; j < 4; ++j)
            acc[i][j] = (f32x4){0.f, 0.f, 0.f, 0.f};

    const int srow = w * 32 + (l >> 3);
    const int scol = ((l & 7) ^ (l >> 3)) * 8;     // pre-swizzled source chunk

#define STAGE(buf, kk) {                                                                    \
    const unsigned short* pa = Ah + (size_t)(m0 + srow) * K + (kk) + scol;                  \
    const unsigned short* pb = Bh + (size_t)(n0 + srow) * K + (kk) + scol;                  \
    char* da = (char*)sA + (buf) * 16384 + w * 4096;                                        \
    char* db = (char*)sB + (buf) * 16384 + w * 4096;                                        \
    gload16(pa,           da);                                                              \
    gload16(pa +  8 * K,  da + 1024);                                                       \
    gload16(pa + 16 * K,  da + 2048);                                                       \
    gload16(pa + 24 * K,  da + 3072);                                                       \
    gload16(pb,           db);                                                              \
    gload16(pb +  8 * K,  db + 1024);                                                       \
    gload16(pb + 16 * K,  db + 2048);                                                       \
    gload16(pb + 24 * K,  db + 3072); }

    STAGE(0, 0);                       // 8 loads in flight

    const int KT = K / BK;             // 12
    int cur = 0;
    for (int t = 0; t < KT; ++t) {
        if (t + 1 < KT) {
            STAGE(cur ^ 1, (t + 1) * BK);                      // +8 -> 16 in flight
            asm volatile("s_waitcnt vmcnt(8)" ::: "memory");   // drain tile t only
        } else {
            asm volatile("s_waitcnt vmcnt(0)" ::: "memory");
        }
        asm volatile("s_barrier" ::: "memory");                // tile t visible

        #pragma unroll
        for (int ks = 0; ks < 2; ++ks) {
            const int rcol = ((ks * 4 + g) ^ (fl & 7)) * 8;    // swizzled read col
            f16x8 ah[4];
            #pragma unroll
            for (int fm = 0; fm < 4; ++fm)
                ah[fm] = *reinterpret_cast<const f16x8*>(&sA[cur][wr + fm * 16 + fl][rcol]);
            #pragma unroll
            for (int fn = 0; fn < 4; ++fn) {
                const f16x8 bf = *reinterpret_cast<const f16x8*>(&sB[cur][wc + fn * 16 + fl][rcol]);
                #pragma unroll
                for (int fm = 0; fm < 4; ++fm)
                    acc[fm][fn] = __builtin_amdgcn_mfma_f32_16x16x32_f16(ah[fm], bf, acc[fm][fn], 0, 0, 0);
            }
        }
        asm volatile("s_barrier" ::: "memory");   // WAR fence before restaging [cur]
        cur ^= 1;
    }
#undef STAGE

    const int rg = g * 4;
    #pragma unroll
    for (int fm = 0; fm < 4; ++fm) {
        #pragma unroll
        for (int fn = 0; fn < 4; ++fn) {
            const int row = m0 + wr + fm * 16 + rg;
            const int col = n0 + wc + fn * 16 + fl;
            const float bv = bias ? bias[col] : 0.f;
            #pragma unroll
            for (int rr = 0; rr < 4; ++rr)
                outp[(size_t)(row + rr) * Nt + col] = acc[fm][fn][rr] + bv;
        }
    }
}

// ---------------------------------------------------------------------------
// MFMA spatial attention. THIS ROUND: PV via 2x mfma_f32_16x16x16f16 whose
// B-frag layout (lane fl+16g: k=4g..4g+3, n=fl) EXACTLY matches the QK^T
// C-frag — P feeds PV directly from registers. Deletes all 8 bpermutes +
// 4 selects per (ch,j). A-operand = Vt[fl][kb0(+16)+4g..+3], hoisted per ch.
// ---------------------------------------------------------------------------
__global__ __launch_bounds__(256) void spatial_attn_mfma(
    const float* __restrict__ qkv,
    float* __restrict__ xs_out)
{
    __shared__ unsigned short Kl[224][40];     // f16: Khi(0..15) Klo(16..31) pad
    __shared__ unsigned short Ql[208][24];     // f16: Q(0..15) pad
    __shared__ unsigned short Vt[16][232];     // f16 V^T [d][k]

    const int bid = blockIdx.x;                // 1152 = 8*12*12
    const int c = bid % 12;
    const int h = (bid / 12) % 12;
    const int b = bid / 144;
    const int tid = threadIdx.x;
    const int w = tid >> 6, l = tid & 63;
    const int fl = l & 15, g = l >> 4;

    const float qs = 0.25f * 1.4426950408889634f;   // softmax scale * log2(e)
    for (int idx = tid; idx < N_ * 4; idx += 256) {
        const int n = idx >> 2, eq = (idx & 3) * 4;
        const float* base = qkv + (size_t)((b * N_ + n) * 12 + c) * NQKV_PAD + 144 + h * 16 + eq;
        const float4 qv = *reinterpret_cast<const float4*>(base);
        const float4 kv = *reinterpret_cast<const float4*>(base + 192);
        const float4 vv = *reinterpret_cast<const float4*>(base + 384);
        ushort4 qh;
        qh.x = f2h(qv.x * qs); qh.y = f2h(qv.y * qs);
        qh.z = f2h(qv.z * qs); qh.w = f2h(qv.w * qs);
        *reinterpret_cast<ushort4*>(&Ql[n][eq]) = qh;
        ushort4 kh, klo;
        kh.x = f2h(kv.x); klo.x = f2h(kv.x - h2f(kh.x));
        kh.y = f2h(kv.y); klo.y = f2h(kv.y - h2f(kh.y));
        kh.z = f2h(kv.z); klo.z = f2h(kv.z - h2f(kh.z));
        kh.w = f2h(kv.w); klo.w = f2h(kv.w - h2f(kh.w));
        *reinterpret_cast<ushort4*>(&Kl[n][eq])      = kh;
        *reinterpret_cast<ushort4*>(&Kl[n][16 + eq]) = klo;
        Vt[eq + 0][n] = f2h(vv.x);
        Vt[eq + 1][n] = f2h(vv.y);
        Vt[eq + 2][n] = f2h(vv.z);
        Vt[eq + 3][n] = f2h(vv.w);
    }
    for (int idx = tid; idx < 16 * 28; idx += 256) {
        const int d = idx / 28, n = 196 + idx % 28;
        Vt[d][n] = 0;
    }
    __syncthreads();

    f32x4 accO[4];
    float lsum[4];
    #pragma unroll
    for (int j = 0; j < 4; ++j) {
        accO[j] = (f32x4){0.f, 0.f, 0.f, 0.f};
        lsum[j] = 0.f;
    }
    const f32x4 zf = (f32x4){0.f, 0.f, 0.f, 0.f};

    f16x8 Bq[4];
    #pragma unroll
    for (int j = 0; j < 4; ++j) {
        const int qt = w + 4 * j;
        const int qrow = (qt > 12 ? 12 : qt) * 16 + fl;
        Bq[j] = *reinterpret_cast<const f16x8*>(&Ql[qrow][8 * (g & 1)]);
    }

    for (int ch = 0; ch < 7; ++ch) {
        const int kb0 = ch * 32;
        const f16x8 A1a = *reinterpret_cast<const f16x8*>(&Kl[kb0 + fl][8 * g]);
        const f16x8 A1b = *reinterpret_cast<const f16x8*>(&Kl[kb0 + 16 + fl][8 * g]);
        // V^T A-frags for the two K=16 PV MFMAs (lane: m=fl, k=4g..4g+3)
        const f16x4 Av0 = *reinterpret_cast<const f16x4*>(&Vt[fl][kb0 + 4 * g]);
        const f16x4 Av1 = *reinterpret_cast<const f16x4*>(&Vt[fl][kb0 + 16 + 4 * g]);

        #pragma unroll
        for (int j = 0; j < 4; ++j) {
            const int qt = w + 4 * j;
            if (qt > 12) continue;

            f32x4 T0 = __builtin_amdgcn_mfma_f32_16x16x32_f16(A1a, Bq[j], zf, 0, 0, 0);
            f32x4 T1 = __builtin_amdgcn_mfma_f32_16x16x32_f16(A1b, Bq[j], zf, 0, 0, 0);

            float s0 = T0[0], s1 = T0[1], s2 = T0[2], s3 = T0[3];
            float s4 = T1[0], s5 = T1[1], s6 = T1[2], s7 = T1[3];
            if (ch == 6) {                      // mask pad k-rows (exp2(-1e30)=0)
                const int kg = kb0 + 4 * g;
                if (kg + 0 >= 196) s0 = -1e30f;
                if (kg + 1 >= 196) s1 = -1e30f;
                if (kg + 2 >= 196) s2 = -1e30f;
                if (kg + 3 >= 196) s3 = -1e30f;
                s4 = -1e30f; s5 = -1e30f; s6 = -1e30f; s7 = -1e30f;
            }
            const float p0 = exp2f(s0), p1 = exp2f(s1);
            const float p2 = exp2f(s2), p3 = exp2f(s3);
            const float p4 = exp2f(s4), p5 = exp2f(s5);
            const float p6 = exp2f(s6), p7 = exp2f(s7);
            lsum[j] += ((p0 + p1) + (p2 + p3)) + ((p4 + p5) + (p6 + p7));

            // B-frags for K=16 PV: word0={p0,p1}, word1={p2,p3} (k=4g+r, n=fl)
            union { unsigned u[2]; f16x4 v; } pa, pb;
            pa.u[0] = packh2(p0, p1); pa.u[1] = packh2(p2, p3);
            pb.u[0] = packh2(p4, p5); pb.u[1] = packh2(p6, p7);

            accO[j] = __builtin_amdgcn_mfma_f32_16x16x16f16(Av0, pa.v, accO[j], 0, 0, 0);
            accO[j] = __builtin_amdgcn_mfma_f32_16x16x16f16(Av1, pb.v, accO[j], 0, 0, 0);
        }
    }

    #pragma unroll
    for (int j = 0; j < 4; ++j) {
        const int qt = w + 4 * j;
        if (qt > 12) continue;
        float ls = lsum[j];
        ls += __shfl_xor(ls, 16);
        ls += __shfl_xor(ls, 32);
        const int n = qt * 16 + fl;
        if (n < 196) {
            const float inv = 1.f / ls;
            float4 o;
            o.x = accO[j][0] * inv; o.y = accO[j][1] * inv;
            o.z = accO[j][2] * inv; o.w = accO[j][3] * inv;
            const size_t base = ((size_t)((b * 12 + h) * N_ + n) * 12 + c) * 16 + 4 * g;
            *reinterpret_cast<float4*>(&xs_out[base]) = o;
        }
    }
}

// ---------------------------------------------------------------------------
// Channel attention + outer-product combine, 4 rows per 256-thread block.
// Emits y as single f16. (r14-verified, unchanged)
// ---------------------------------------------------------------------------
__global__ __launch_bounds__(256) void chan_attn_combine4(
    const float* __restrict__ qkv,
    const float* __restrict__ xs,
    unsigned short* __restrict__ yh)
{
    const int sub = threadIdx.x >> 6;
    const int t = threadIdx.x & 63;
    const int flat = blockIdx.x * 4 + sub;     // (b*12+h)*196 + n
    const int n = flat % 196;
    const int h = (flat / 196) % 12;
    const int b = flat / 2352;

    __shared__ float sQ[4][12][4], sK[4][12][4], sV[4][12][4], sXc[4][12][4];
    __shared__ float sXs[4][12][16];

    for (int idx = t; idx < 144; idx += 64) {
        const int c = idx / 12, rem = idx % 12, s = rem >> 2, e = rem & 3;
        const float v = qkv[(size_t)((b * N_ + n) * 12 + c) * NQKV_PAD + s * 48 + h * 4 + e];
        if (s == 0) sQ[sub][c][e] = v;
        else if (s == 1) sK[sub][c][e] = v;
        else sV[sub][c][e] = v;
    }
    for (int idx = t; idx < 192; idx += 64) {
        const int c = idx >> 4, j = idx & 15;
        sXs[sub][c][j] = xs[((size_t)flat * 12 + c) * 16 + j];
    }
    __syncthreads();

    if (t < 12) {
        const int c = t;
        float s[12];
        float m = -INFINITY;
        #pragma unroll
        for (int c2 = 0; c2 < 12; ++c2) {
            float d = 0.f;
            #pragma unroll
            for (int e = 0; e < 4; ++e) d += sQ[sub][c][e] * sK[sub][c2][e];
            s[c2] = d * 0.5f;
            m = fmaxf(m, s[c2]);
        }
        float lsum = 0.f;
        #pragma unroll
        for (int c2 = 0; c2 < 12; ++c2) { s[c2] = __expf(s[c2] - m); lsum += s[c2]; }
        const float inv = 1.f / lsum;
        #pragma unroll
        for (int i = 0; i < 4; ++i) {
            float a = 0.f;
            #pragma unroll
            for (int c2 = 0; c2 < 12; ++c2) a += s[c2] * sV[sub][c2][i];
            sXc[sub][c][i] = a * inv;
        }
    }
    __syncthreads();

    const size_t yrow = ((size_t)(b * N_ + n) * 12 + h) * (size_t)D_;
    #pragma unroll
    for (int k = 0; k < 12; ++k) {
        const float v = sXc[sub][k][t >> 4] * sXs[sub][k][t & 15];
        yh[yrow + k * 64 + t] = f2h(v);
    }
}

// ---------------------------------------------------------------------------
extern "C" void kernel_launch(void* const* d_in, const int* in_sizes, int n_in,
                              void* d_out, int out_size, void* d_ws, size_t ws_size,
                              hipStream_t stream) {
    const float* x       = (const float*)d_in[0];
    const float* w_qkv_c = (const float*)d_in[1];
    const float* w_qkv_s = (const float*)d_in[2];
    const float* w_proj  = (const float*)d_in[3];
    const float* b_proj  = (const float*)d_in[4];
    float* out = (float*)d_out;

    unsigned short* xh     = (unsigned short*)d_ws;               // R x 768 f16
    unsigned short* wqkv_h = xh + (size_t)R_ * KDIM;              // 768 x 768
    unsigned short* wp_h   = wqkv_h + (size_t)768 * 768;
    float* qkv = (float*)(wp_h + (size_t)768 * 768);              // R x 768 fp32
    float* xs  = qkv + (size_t)R_ * NQKV_PAD;
    unsigned short* yh = xh;   // alias: x f16 dead after qkv GEMM

    convert_f16<<<(R_ * KDIM) / 1024, 256, 0, stream>>>(x, xh, R_ * KDIM);
    convert_weights<<<(2 * 768 * 768) / 1024, 256, 0, stream>>>(
        w_qkv_c, w_qkv_s, w_proj, wqkv_h, wp_h);

    {
        const int mtiles = R_ / BM, ntiles = NQKV_PAD / BN;
        gemm_f16<<<mtiles * ntiles, 256, 0, stream>>>(
            xh, wqkv_h, nullptr, qkv, R_, NQKV_PAD, KDIM, ntiles);
    }
    spatial_attn_mfma<<<B_ * H_ * C_, 256, 0, stream>>>(qkv, xs);
    chan_attn_combine4<<<(B_ * H_ * N_) / 4, 256, 0, stream>>>(qkv, xs, yh);
    {
        const int mtiles = R_ / BM, ntiles = D_ / BN;
        gemm_f16<<<mtiles * ntiles, 256, 0, stream>>>(
            yh, wp_h, b_proj, out, R_, D_, KDIM, ntiles);
    }
}

// Round 20
// 142.741 us; speedup vs baseline: 1.2249x; 1.0767x over previous
//
#include <hip/hip_runtime.h>
#include <math.h>

// Problem constants
#define B_  8
#define N_  196
#define C_  12
#define D_  768
#define H_  12
#define R_  (B_*N_*C_)      // 18816 rows
#define KDIM 768
#define NQKV_PAD 768        // 720 real qkv cols padded to 768

typedef _Float16 f16x8 __attribute__((ext_vector_type(8)));   // 8 f16 = 4 VGPR
typedef _Float16 f16x4 __attribute__((ext_vector_type(4)));   // 4 f16 = 2 VGPR
typedef __attribute__((ext_vector_type(4))) float f32x4;

__device__ inline unsigned short f2h(float f) {
    union { _Float16 h; unsigned short u; } v; v.h = (_Float16)f; return v.u;
}
__device__ inline float h2f(unsigned short u) {
    union { unsigned short u; _Float16 h; } v; v.u = u; return (float)v.h;
}
__device__ inline unsigned packh2(float a, float b) {
    return (unsigned)f2h(a) | ((unsigned)f2h(b) << 16);
}

// ---------------------------------------------------------------------------
// fp32 -> f16 elementwise. n must be a multiple of 4.
// ---------------------------------------------------------------------------
__global__ __launch_bounds__(256) void convert_f16(
    const float* __restrict__ in, unsigned short* __restrict__ outh, int n)
{
    int i = (blockIdx.x * 256 + threadIdx.x) * 4;
    if (i >= n) return;
    float4 v = *reinterpret_cast<const float4*>(in + i);
    ushort4 h;
    h.x = f2h(v.x); h.y = f2h(v.y); h.z = f2h(v.z); h.w = f2h(v.w);
    *reinterpret_cast<ushort4*>(outh + i) = h;
}

// One launch: wqkv (packed 768x768, rows 720+ zero) and wp, single f16 each.
__global__ __launch_bounds__(256) void convert_weights(
    const float* __restrict__ wc, const float* __restrict__ ws,
    const float* __restrict__ wp,
    unsigned short* __restrict__ wqkv_h, unsigned short* __restrict__ wp_h)
{
    int i = (blockIdx.x * 256 + threadIdx.x) * 4;
    unsigned short* dh; float4 v; int off;
    if (i < 768 * 768) {
        const int r = i / 768, k = i % 768;
        v = make_float4(0.f, 0.f, 0.f, 0.f);
        if (r < 144)      v = *reinterpret_cast<const float4*>(wc + r * 768 + k);
        else if (r < 720) v = *reinterpret_cast<const float4*>(ws + (r - 144) * 768 + k);
        dh = wqkv_h; off = i;
    } else {
        off = i - 768 * 768;
        if (off >= 768 * 768) return;
        v = *reinterpret_cast<const float4*>(wp + off);
        dh = wp_h;
    }
    ushort4 h;
    h.x = f2h(v.x); h.y = f2h(v.y); h.z = f2h(v.z); h.w = f2h(v.w);
    *reinterpret_cast<ushort4*>(dh + off) = h;
}

// ---------------------------------------------------------------------------
// Single-f16 MFMA GEMM, BK=64 (r18-verified structure). THIS ROUND: optional
// f16 output (outh != nullptr) for the qkv GEMM; f32+bias path for proj.
// ---------------------------------------------------------------------------
#define BM 128
#define BN 128
#define BK 64

__device__ inline void gload16(const unsigned short* src, void* ldsbase) {
    __builtin_amdgcn_global_load_lds(
        (const __attribute__((address_space(1))) unsigned int*)src,
        (__attribute__((address_space(3))) unsigned int*)ldsbase, 16, 0, 0);
}

__global__ __launch_bounds__(256) void gemm_f16(
    const unsigned short* __restrict__ Ah, const unsigned short* __restrict__ Bh,
    const float* __restrict__ bias,
    float* __restrict__ outp, unsigned short* __restrict__ outh,
    int M, int Nt, int K, int ntiles)
{
    __shared__ unsigned short sA[2][BM][BK];   // 2 x 16 KB
    __shared__ unsigned short sB[2][BN][BK];   // 2 x 16 KB

    const int nwg = gridDim.x;
    const int bid = blockIdx.x;
    const int xcd = bid & 7, slot = bid >> 3;
    const int q = nwg >> 3, r = nwg & 7;
    const int wg = (xcd < r ? xcd * (q + 1) : r * (q + 1) + (xcd - r) * q) + slot;
    const int mt = wg / ntiles, nt = wg - mt * ntiles;   // nt fast: A-panel reuse
    const int m0 = mt * BM, n0 = nt * BN;

    const int tid = threadIdx.x;
    const int w = tid >> 6, l = tid & 63;
    const int fl = l & 15, g = l >> 4;
    const int wr = (w >> 1) * 64, wc = (w & 1) * 64;

    f32x4 acc[4][4];
    #pragma unroll
    for (int i = 0; i < 4; ++i)
        #pragma unroll
        for (int j = 0; j < 4; ++j)
            acc[i][j] = (f32x4){0.f, 0.f, 0.f, 0.f};

    const int srow = w * 32 + (l >> 3);
    const int scol = ((l & 7) ^ (l >> 3)) * 8;     // pre-swizzled source chunk

#define STAGE(buf, kk) {                                                                    \
    const unsigned short* pa = Ah + (size_t)(m0 + srow) * K + (kk) + scol;                  \
    const unsigned short* pb = Bh + (size_t)(n0 + srow) * K + (kk) + scol;                  \
    char* da = (char*)sA + (buf) * 16384 + w * 4096;                                        \
    char* db = (char*)sB + (buf) * 16384 + w * 4096;                                        \
    gload16(pa,           da);                                                              \
    gload16(pa +  8 * K,  da + 1024);                                                       \
    gload16(pa + 16 * K,  da + 2048);                                                       \
    gload16(pa + 24 * K,  da + 3072);                                                       \
    gload16(pb,           db);                                                              \
    gload16(pb +  8 * K,  db + 1024);                                                       \
    gload16(pb + 16 * K,  db + 2048);                                                       \
    gload16(pb + 24 * K,  db + 3072); }

    STAGE(0, 0);                       // 8 loads in flight

    const int KT = K / BK;             // 12
    int cur = 0;
    for (int t = 0; t < KT; ++t) {
        if (t + 1 < KT) {
            STAGE(cur ^ 1, (t + 1) * BK);                      // +8 -> 16 in flight
            asm volatile("s_waitcnt vmcnt(8)" ::: "memory");   // drain tile t only
        } else {
            asm volatile("s_waitcnt vmcnt(0)" ::: "memory");
        }
        asm volatile("s_barrier" ::: "memory");                // tile t visible

        #pragma unroll
        for (int ks = 0; ks < 2; ++ks) {
            const int rcol = ((ks * 4 + g) ^ (fl & 7)) * 8;    // swizzled read col
            f16x8 ah[4];
            #pragma unroll
            for (int fm = 0; fm < 4; ++fm)
                ah[fm] = *reinterpret_cast<const f16x8*>(&sA[cur][wr + fm * 16 + fl][rcol]);
            #pragma unroll
            for (int fn = 0; fn < 4; ++fn) {
                const f16x8 bf = *reinterpret_cast<const f16x8*>(&sB[cur][wc + fn * 16 + fl][rcol]);
                #pragma unroll
                for (int fm = 0; fm < 4; ++fm)
                    acc[fm][fn] = __builtin_amdgcn_mfma_f32_16x16x32_f16(ah[fm], bf, acc[fm][fn], 0, 0, 0);
            }
        }
        asm volatile("s_barrier" ::: "memory");   // WAR fence before restaging [cur]
        cur ^= 1;
    }
#undef STAGE

    const int rg = g * 4;
    if (outh) {
        #pragma unroll
        for (int fm = 0; fm < 4; ++fm)
            #pragma unroll
            for (int fn = 0; fn < 4; ++fn) {
                const int row = m0 + wr + fm * 16 + rg;
                const int col = n0 + wc + fn * 16 + fl;
                #pragma unroll
                for (int rr = 0; rr < 4; ++rr)
                    outh[(size_t)(row + rr) * Nt + col] = f2h(acc[fm][fn][rr]);
            }
    } else {
        #pragma unroll
        for (int fm = 0; fm < 4; ++fm)
            #pragma unroll
            for (int fn = 0; fn < 4; ++fn) {
                const int row = m0 + wr + fm * 16 + rg;
                const int col = n0 + wc + fn * 16 + fl;
                const float bv = bias ? bias[col] : 0.f;
                #pragma unroll
                for (int rr = 0; rr < 4; ++rr)
                    outp[(size_t)(row + rr) * Nt + col] = acc[fm][fn][rr] + bv;
            }
    }
}

// ---------------------------------------------------------------------------
// MFMA spatial attention, all-f16 I/O. QK via 2x mfma_f32_16x16x16f16:
//   A = K-frag  (lane: m=krow=fl, k=d=4g..4g+3)  -> Kl[kb+fl][4g..]
//   B = Q-frag  (lane: n=q=fl,    k=d=4g..4g+3)  -> Ql[fl][4g..], hoisted
//   C: col=q=fl, row=krow=4g+r  (same layout as before)
// PV direct-feed (r19): 2x mfma_f32_16x16x16f16, P from registers.
// xs written as f16. LDS ~28KB.
// ---------------------------------------------------------------------------
__global__ __launch_bounds__(256) void spatial_attn_mfma(
    const unsigned short* __restrict__ qkv,
    unsigned short* __restrict__ xs_out)
{
    __shared__ unsigned short Kl[224][24];     // f16 K, pad cols
    __shared__ unsigned short Ql[208][24];     // f16 Q (pre-scaled)
    __shared__ unsigned short Vt[16][232];     // f16 V^T [d][k]

    const int bid = blockIdx.x;                // 1152 = 8*12*12
    const int c = bid % 12;
    const int h = (bid / 12) % 12;
    const int b = bid / 144;
    const int tid = threadIdx.x;
    const int w = tid >> 6, l = tid & 63;
    const int fl = l & 15, g = l >> 4;

    const float qs = 0.25f * 1.4426950408889634f;   // softmax scale * log2(e)
    for (int idx = tid; idx < N_ * 4; idx += 256) {
        const int n = idx >> 2, eq = (idx & 3) * 4;
        const unsigned short* base =
            qkv + (size_t)((b * N_ + n) * 12 + c) * NQKV_PAD + 144 + h * 16 + eq;
        const ushort4 qv = *reinterpret_cast<const ushort4*>(base);
        const ushort4 kv = *reinterpret_cast<const ushort4*>(base + 192);
        const ushort4 vv = *reinterpret_cast<const ushort4*>(base + 384);
        ushort4 qsc;
        qsc.x = f2h(h2f(qv.x) * qs); qsc.y = f2h(h2f(qv.y) * qs);
        qsc.z = f2h(h2f(qv.z) * qs); qsc.w = f2h(h2f(qv.w) * qs);
        *reinterpret_cast<ushort4*>(&Ql[n][eq]) = qsc;
        *reinterpret_cast<ushort4*>(&Kl[n][eq]) = kv;
        Vt[eq + 0][n] = vv.x;
        Vt[eq + 1][n] = vv.y;
        Vt[eq + 2][n] = vv.z;
        Vt[eq + 3][n] = vv.w;
    }
    for (int idx = tid; idx < 16 * 28; idx += 256) {
        const int d = idx / 28, n = 196 + idx % 28;
        Vt[d][n] = 0;
    }
    __syncthreads();

    f32x4 accO[4];
    float lsum[4];
    #pragma unroll
    for (int j = 0; j < 4; ++j) {
        accO[j] = (f32x4){0.f, 0.f, 0.f, 0.f};
        lsum[j] = 0.f;
    }
    const f32x4 zf = (f32x4){0.f, 0.f, 0.f, 0.f};

    // hoisted Q fragments (ch-invariant); clamp inactive rows in-bounds
    f16x4 Bq[4];
    #pragma unroll
    for (int j = 0; j < 4; ++j) {
        const int qt = w + 4 * j;
        const int qrow = (qt > 12 ? 12 : qt) * 16 + fl;
        Bq[j] = *reinterpret_cast<const f16x4*>(&Ql[qrow][4 * g]);
    }

    for (int ch = 0; ch < 7; ++ch) {
        const int kb0 = ch * 32;
        // K A-frags (m=krow=fl, k=4g..4g+3)
        const f16x4 Ak0 = *reinterpret_cast<const f16x4*>(&Kl[kb0 + fl][4 * g]);
        const f16x4 Ak1 = *reinterpret_cast<const f16x4*>(&Kl[kb0 + 16 + fl][4 * g]);
        // V^T A-frags (m=d=fl, k=4g..4g+3)
        const f16x4 Av0 = *reinterpret_cast<const f16x4*>(&Vt[fl][kb0 + 4 * g]);
        const f16x4 Av1 = *reinterpret_cast<const f16x4*>(&Vt[fl][kb0 + 16 + 4 * g]);

        #pragma unroll
        for (int j = 0; j < 4; ++j) {
            const int qt = w + 4 * j;
            if (qt > 12) continue;

            f32x4 T0 = __builtin_amdgcn_mfma_f32_16x16x16f16(Ak0, Bq[j], zf, 0, 0, 0);
            f32x4 T1 = __builtin_amdgcn_mfma_f32_16x16x16f16(Ak1, Bq[j], zf, 0, 0, 0);

            float s0 = T0[0], s1 = T0[1], s2 = T0[2], s3 = T0[3];
            float s4 = T1[0], s5 = T1[1], s6 = T1[2], s7 = T1[3];
            if (ch == 6) {                      // mask pad k-rows (exp2(-1e30)=0)
                const int kg = kb0 + 4 * g;
                if (kg + 0 >= 196) s0 = -1e30f;
                if (kg + 1 >= 196) s1 = -1e30f;
                if (kg + 2 >= 196) s2 = -1e30f;
                if (kg + 3 >= 196) s3 = -1e30f;
                s4 = -1e30f; s5 = -1e30f; s6 = -1e30f; s7 = -1e30f;
            }
            const float p0 = exp2f(s0), p1 = exp2f(s1);
            const float p2 = exp2f(s2), p3 = exp2f(s3);
            const float p4 = exp2f(s4), p5 = exp2f(s5);
            const float p6 = exp2f(s6), p7 = exp2f(s7);
            lsum[j] += ((p0 + p1) + (p2 + p3)) + ((p4 + p5) + (p6 + p7));

            union { unsigned u[2]; f16x4 v; } pa, pb;
            pa.u[0] = packh2(p0, p1); pa.u[1] = packh2(p2, p3);
            pb.u[0] = packh2(p4, p5); pb.u[1] = packh2(p6, p7);

            accO[j] = __builtin_amdgcn_mfma_f32_16x16x16f16(Av0, pa.v, accO[j], 0, 0, 0);
            accO[j] = __builtin_amdgcn_mfma_f32_16x16x16f16(Av1, pb.v, accO[j], 0, 0, 0);
        }
    }

    #pragma unroll
    for (int j = 0; j < 4; ++j) {
        const int qt = w + 4 * j;
        if (qt > 12) continue;
        float ls = lsum[j];
        ls += __shfl_xor(ls, 16);
        ls += __shfl_xor(ls, 32);
        const int n = qt * 16 + fl;
        if (n < 196) {
            const float inv = 1.f / ls;
            ushort4 o;
            o.x = f2h(accO[j][0] * inv); o.y = f2h(accO[j][1] * inv);
            o.z = f2h(accO[j][2] * inv); o.w = f2h(accO[j][3] * inv);
            const size_t base = ((size_t)((b * 12 + h) * N_ + n) * 12 + c) * 16 + 4 * g;
            *reinterpret_cast<ushort4*>(&xs_out[base]) = o;
        }
    }
}

// ---------------------------------------------------------------------------
// Channel attention + outer-product combine, 4 rows per 256-thread block.
// f16 qkv + f16 xs in; y f16 out.
// ---------------------------------------------------------------------------
__global__ __launch_bounds__(256) void chan_attn_combine4(
    const unsigned short* __restrict__ qkv,
    const unsigned short* __restrict__ xs,
    unsigned short* __restrict__ yh)
{
    const int sub = threadIdx.x >> 6;
    const int t = threadIdx.x & 63;
    const int flat = blockIdx.x * 4 + sub;     // (b*12+h)*196 + n
    const int n = flat % 196;
    const int h = (flat / 196) % 12;
    const int b = flat / 2352;

    __shared__ float sQ[4][12][4], sK[4][12][4], sV[4][12][4], sXc[4][12][4];
    __shared__ float sXs[4][12][16];

    for (int idx = t; idx < 144; idx += 64) {
        const int c = idx / 12, rem = idx % 12, s = rem >> 2, e = rem & 3;
        const float v = h2f(qkv[(size_t)((b * N_ + n) * 12 + c) * NQKV_PAD + s * 48 + h * 4 + e]);
        if (s == 0) sQ[sub][c][e] = v;
        else if (s == 1) sK[sub][c][e] = v;
        else sV[sub][c][e] = v;
    }
    for (int idx = t; idx < 192; idx += 64) {
        const int c = idx >> 4, j = idx & 15;
        sXs[sub][c][j] = h2f(xs[((size_t)flat * 12 + c) * 16 + j]);
    }
    __syncthreads();

    if (t < 12) {
        const int c = t;
        float s[12];
        float m = -INFINITY;
        #pragma unroll
        for (int c2 = 0; c2 < 12; ++c2) {
            float d = 0.f;
            #pragma unroll
            for (int e = 0; e < 4; ++e) d += sQ[sub][c][e] * sK[sub][c2][e];
            s[c2] = d * 0.5f;
            m = fmaxf(m, s[c2]);
        }
        float lsum = 0.f;
        #pragma unroll
        for (int c2 = 0; c2 < 12; ++c2) { s[c2] = __expf(s[c2] - m); lsum += s[c2]; }
        const float inv = 1.f / lsum;
        #pragma unroll
        for (int i = 0; i < 4; ++i) {
            float a = 0.f;
            #pragma unroll
            for (int c2 = 0; c2 < 12; ++c2) a += s[c2] * sV[sub][c2][i];
            sXc[sub][c][i] = a * inv;
        }
    }
    __syncthreads();

    const size_t yrow = ((size_t)(b * N_ + n) * 12 + h) * (size_t)D_;
    #pragma unroll
    for (int k = 0; k < 12; ++k) {
        const float v = sXc[sub][k][t >> 4] * sXs[sub][k][t & 15];
        yh[yrow + k * 64 + t] = f2h(v);
    }
}

// ---------------------------------------------------------------------------
extern "C" void kernel_launch(void* const* d_in, const int* in_sizes, int n_in,
                              void* d_out, int out_size, void* d_ws, size_t ws_size,
                              hipStream_t stream) {
    const float* x       = (const float*)d_in[0];
    const float* w_qkv_c = (const float*)d_in[1];
    const float* w_qkv_s = (const float*)d_in[2];
    const float* w_proj  = (const float*)d_in[3];
    const float* b_proj  = (const float*)d_in[4];
    float* out = (float*)d_out;

    unsigned short* xh     = (unsigned short*)d_ws;               // R x 768 f16
    unsigned short* wqkv_h = xh + (size_t)R_ * KDIM;              // 768 x 768
    unsigned short* wp_h   = wqkv_h + (size_t)768 * 768;
    unsigned short* qkv_h  = wp_h + (size_t)768 * 768;            // R x 768 f16
    unsigned short* xs_h   = qkv_h + (size_t)R_ * NQKV_PAD;       // B*H*N*C*16 f16
    unsigned short* yh = xh;   // alias: x f16 dead after qkv GEMM

    convert_f16<<<(R_ * KDIM) / 1024, 256, 0, stream>>>(x, xh, R_ * KDIM);
    convert_weights<<<(2 * 768 * 768) / 1024, 256, 0, stream>>>(
        w_qkv_c, w_qkv_s, w_proj, wqkv_h, wp_h);

    {
        const int mtiles = R_ / BM, ntiles = NQKV_PAD / BN;
        gemm_f16<<<mtiles * ntiles, 256, 0, stream>>>(
            xh, wqkv_h, nullptr, nullptr, qkv_h, R_, NQKV_PAD, KDIM, ntiles);
    }
    spatial_attn_mfma<<<B_ * H_ * C_, 256, 0, stream>>>(qkv_h, xs_h);
    chan_attn_combine4<<<(B_ * H_ * N_) / 4, 256, 0, stream>>>(qkv_h, xs_h, yh);
    {
        const int mtiles = R_ / BM, ntiles = D_ / BN;
        gemm_f16<<<mtiles * ntiles, 256, 0, stream>>>(
            yh, wp_h, b_proj, out, nullptr, R_, D_, KDIM, ntiles);
    }
}

// Round 21
// 137.191 us; speedup vs baseline: 1.2744x; 1.0405x over previous
//
#include <hip/hip_runtime.h>
#include <math.h>

// Problem constants
#define B_  8
#define N_  196
#define C_  12
#define D_  768
#define H_  12
#define R_  (B_*N_*C_)      // 18816 rows
#define KDIM 768
#define NQKV_PAD 768        // 720 real qkv cols padded to 768

typedef _Float16 f16x8 __attribute__((ext_vector_type(8)));   // 8 f16 = 4 VGPR
typedef _Float16 f16x4 __attribute__((ext_vector_type(4)));   // 4 f16 = 2 VGPR
typedef __attribute__((ext_vector_type(4))) float f32x4;

__device__ inline unsigned short f2h(float f) {
    union { _Float16 h; unsigned short u; } v; v.h = (_Float16)f; return v.u;
}
__device__ inline float h2f(unsigned short u) {
    union { unsigned short u; _Float16 h; } v; v.u = u; return (float)v.h;
}
__device__ inline unsigned packh2(float a, float b) {
    return (unsigned)f2h(a) | ((unsigned)f2h(b) << 16);
}

// ---------------------------------------------------------------------------
// fp32 -> f16 elementwise. n must be a multiple of 4.
// ---------------------------------------------------------------------------
__global__ __launch_bounds__(256) void convert_f16(
    const float* __restrict__ in, unsigned short* __restrict__ outh, int n)
{
    int i = (blockIdx.x * 256 + threadIdx.x) * 4;
    if (i >= n) return;
    float4 v = *reinterpret_cast<const float4*>(in + i);
    ushort4 h;
    h.x = f2h(v.x); h.y = f2h(v.y); h.z = f2h(v.z); h.w = f2h(v.w);
    *reinterpret_cast<ushort4*>(outh + i) = h;
}

// One launch: wqkv (packed 768x768, rows 720+ zero) and wp, single f16 each.
__global__ __launch_bounds__(256) void convert_weights(
    const float* __restrict__ wc, const float* __restrict__ ws,
    const float* __restrict__ wp,
    unsigned short* __restrict__ wqkv_h, unsigned short* __restrict__ wp_h)
{
    int i = (blockIdx.x * 256 + threadIdx.x) * 4;
    unsigned short* dh; float4 v; int off;
    if (i < 768 * 768) {
        const int r = i / 768, k = i % 768;
        v = make_float4(0.f, 0.f, 0.f, 0.f);
        if (r < 144)      v = *reinterpret_cast<const float4*>(wc + r * 768 + k);
        else if (r < 720) v = *reinterpret_cast<const float4*>(ws + (r - 144) * 768 + k);
        dh = wqkv_h; off = i;
    } else {
        off = i - 768 * 768;
        if (off >= 768 * 768) return;
        v = *reinterpret_cast<const float4*>(wp + off);
        dh = wp_h;
    }
    ushort4 h;
    h.x = f2h(v.x); h.y = f2h(v.y); h.z = f2h(v.z); h.w = f2h(v.w);
    *reinterpret_cast<ushort4*>(dh + off) = h;
}

// ---------------------------------------------------------------------------
// Single-f16 MFMA GEMM, BK=64 (r18/r20-verified). Optional f16 output.
// ---------------------------------------------------------------------------
#define BM 128
#define BN 128
#define BK 64

__device__ inline void gload16(const unsigned short* src, void* ldsbase) {
    __builtin_amdgcn_global_load_lds(
        (const __attribute__((address_space(1))) unsigned int*)src,
        (__attribute__((address_space(3))) unsigned int*)ldsbase, 16, 0, 0);
}

__global__ __launch_bounds__(256) void gemm_f16(
    const unsigned short* __restrict__ Ah, const unsigned short* __restrict__ Bh,
    const float* __restrict__ bias,
    float* __restrict__ outp, unsigned short* __restrict__ outh,
    int M, int Nt, int K, int ntiles)
{
    __shared__ unsigned short sA[2][BM][BK];   // 2 x 16 KB
    __shared__ unsigned short sB[2][BN][BK];   // 2 x 16 KB

    const int nwg = gridDim.x;
    const int bid = blockIdx.x;
    const int xcd = bid & 7, slot = bid >> 3;
    const int q = nwg >> 3, r = nwg & 7;
    const int wg = (xcd < r ? xcd * (q + 1) : r * (q + 1) + (xcd - r) * q) + slot;
    const int mt = wg / ntiles, nt = wg - mt * ntiles;   // nt fast: A-panel reuse
    const int m0 = mt * BM, n0 = nt * BN;

    const int tid = threadIdx.x;
    const int w = tid >> 6, l = tid & 63;
    const int fl = l & 15, g = l >> 4;
    const int wr = (w >> 1) * 64, wc = (w & 1) * 64;

    f32x4 acc[4][4];
    #pragma unroll
    for (int i = 0; i < 4; ++i)
        #pragma unroll
        for (int j = 0; j < 4; ++j)
            acc[i][j] = (f32x4){0.f, 0.f, 0.f, 0.f};

    const int srow = w * 32 + (l >> 3);
    const int scol = ((l & 7) ^ (l >> 3)) * 8;     // pre-swizzled source chunk

#define STAGE(buf, kk) {                                                                    \
    const unsigned short* pa = Ah + (size_t)(m0 + srow) * K + (kk) + scol;                  \
    const unsigned short* pb = Bh + (size_t)(n0 + srow) * K + (kk) + scol;                  \
    char* da = (char*)sA + (buf) * 16384 + w * 4096;                                        \
    char* db = (char*)sB + (buf) * 16384 + w * 4096;                                        \
    gload16(pa,           da);                                                              \
    gload16(pa +  8 * K,  da + 1024);                                                       \
    gload16(pa + 16 * K,  da + 2048);                                                       \
    gload16(pa + 24 * K,  da + 3072);                                                       \
    gload16(pb,           db);                                                              \
    gload16(pb +  8 * K,  db + 1024);                                                       \
    gload16(pb + 16 * K,  db + 2048);                                                       \
    gload16(pb + 24 * K,  db + 3072); }

    STAGE(0, 0);                       // 8 loads in flight

    const int KT = K / BK;             // 12
    int cur = 0;
    for (int t = 0; t < KT; ++t) {
        if (t + 1 < KT) {
            STAGE(cur ^ 1, (t + 1) * BK);                      // +8 -> 16 in flight
            asm volatile("s_waitcnt vmcnt(8)" ::: "memory");   // drain tile t only
        } else {
            asm volatile("s_waitcnt vmcnt(0)" ::: "memory");
        }
        asm volatile("s_barrier" ::: "memory");                // tile t visible

        #pragma unroll
        for (int ks = 0; ks < 2; ++ks) {
            const int rcol = ((ks * 4 + g) ^ (fl & 7)) * 8;    // swizzled read col
            f16x8 ah[4];
            #pragma unroll
            for (int fm = 0; fm < 4; ++fm)
                ah[fm] = *reinterpret_cast<const f16x8*>(&sA[cur][wr + fm * 16 + fl][rcol]);
            #pragma unroll
            for (int fn = 0; fn < 4; ++fn) {
                const f16x8 bf = *reinterpret_cast<const f16x8*>(&sB[cur][wc + fn * 16 + fl][rcol]);
                #pragma unroll
                for (int fm = 0; fm < 4; ++fm)
                    acc[fm][fn] = __builtin_amdgcn_mfma_f32_16x16x32_f16(ah[fm], bf, acc[fm][fn], 0, 0, 0);
            }
        }
        asm volatile("s_barrier" ::: "memory");   // WAR fence before restaging [cur]
        cur ^= 1;
    }
#undef STAGE

    const int rg = g * 4;
    if (outh) {
        #pragma unroll
        for (int fm = 0; fm < 4; ++fm)
            #pragma unroll
            for (int fn = 0; fn < 4; ++fn) {
                const int row = m0 + wr + fm * 16 + rg;
                const int col = n0 + wc + fn * 16 + fl;
                #pragma unroll
                for (int rr = 0; rr < 4; ++rr)
                    outh[(size_t)(row + rr) * Nt + col] = f2h(acc[fm][fn][rr]);
            }
    } else {
        #pragma unroll
        for (int fm = 0; fm < 4; ++fm)
            #pragma unroll
            for (int fn = 0; fn < 4; ++fn) {
                const int row = m0 + wr + fm * 16 + rg;
                const int col = n0 + wc + fn * 16 + fl;
                const float bv = bias ? bias[col] : 0.f;
                #pragma unroll
                for (int rr = 0; rr < 4; ++rr)
                    outp[(size_t)(row + rr) * Nt + col] = acc[fm][fn][rr] + bv;
            }
    }
}

// ---------------------------------------------------------------------------
// MFMA spatial attention, all-f16 I/O. THIS ROUND: 2304 blocks — each (b,h,c)
// split into 2 halves by q-tile (half 0: tiles 0..6, half 1: 7..12) -> 9
// waves/SIMD capacity (was 4.5, grid-limited). j-loop depth 2, accO/Bq halved.
// QK and PV via mfma_f32_16x16x16f16 (direct P feed, r19/r20-verified).
// ---------------------------------------------------------------------------
__global__ __launch_bounds__(256) void spatial_attn_mfma(
    const unsigned short* __restrict__ qkv,
    unsigned short* __restrict__ xs_out)
{
    __shared__ unsigned short Kl[224][24];     // f16 K, pad cols
    __shared__ unsigned short Ql[208][24];     // f16 Q (pre-scaled)
    __shared__ unsigned short Vt[16][232];     // f16 V^T [d][k]

    const int bid2 = blockIdx.x;               // 2304 = 1152 x 2
    const int half = bid2 & 1;
    const int bid = bid2 >> 1;
    const int c = bid % 12;
    const int h = (bid / 12) % 12;
    const int b = bid / 144;
    const int tid = threadIdx.x;
    const int w = tid >> 6, l = tid & 63;
    const int fl = l & 15, g = l >> 4;
    const int qbase = half * 7;                // tile range start
    const int ntl = 7 - half;                  // local tile count (7 or 6)

    const float qs = 0.25f * 1.4426950408889634f;   // softmax scale * log2(e)
    for (int idx = tid; idx < N_ * 4; idx += 256) {
        const int n = idx >> 2, eq = (idx & 3) * 4;
        const unsigned short* base =
            qkv + (size_t)((b * N_ + n) * 12 + c) * NQKV_PAD + 144 + h * 16 + eq;
        const ushort4 qv = *reinterpret_cast<const ushort4*>(base);
        const ushort4 kv = *reinterpret_cast<const ushort4*>(base + 192);
        const ushort4 vv = *reinterpret_cast<const ushort4*>(base + 384);
        ushort4 qsc;
        qsc.x = f2h(h2f(qv.x) * qs); qsc.y = f2h(h2f(qv.y) * qs);
        qsc.z = f2h(h2f(qv.z) * qs); qsc.w = f2h(h2f(qv.w) * qs);
        *reinterpret_cast<ushort4*>(&Ql[n][eq]) = qsc;
        *reinterpret_cast<ushort4*>(&Kl[n][eq]) = kv;
        Vt[eq + 0][n] = vv.x;
        Vt[eq + 1][n] = vv.y;
        Vt[eq + 2][n] = vv.z;
        Vt[eq + 3][n] = vv.w;
    }
    for (int idx = tid; idx < 16 * 28; idx += 256) {
        const int d = idx / 28, n = 196 + idx % 28;
        Vt[d][n] = 0;
    }
    __syncthreads();

    f32x4 accO[2];
    float lsum[2];
    #pragma unroll
    for (int j = 0; j < 2; ++j) {
        accO[j] = (f32x4){0.f, 0.f, 0.f, 0.f};
        lsum[j] = 0.f;
    }
    const f32x4 zf = (f32x4){0.f, 0.f, 0.f, 0.f};

    // hoisted Q fragments (ch-invariant); clamp inactive lanes in-bounds
    f16x4 Bq[2];
    #pragma unroll
    for (int j = 0; j < 2; ++j) {
        const int qtl = w + 4 * j;
        const int qt = (qtl < ntl) ? (qbase + qtl) : 12;
        Bq[j] = *reinterpret_cast<const f16x4*>(&Ql[qt * 16 + fl][4 * g]);
    }

    for (int ch = 0; ch < 7; ++ch) {
        const int kb0 = ch * 32;
        const f16x4 Ak0 = *reinterpret_cast<const f16x4*>(&Kl[kb0 + fl][4 * g]);
        const f16x4 Ak1 = *reinterpret_cast<const f16x4*>(&Kl[kb0 + 16 + fl][4 * g]);
        const f16x4 Av0 = *reinterpret_cast<const f16x4*>(&Vt[fl][kb0 + 4 * g]);
        const f16x4 Av1 = *reinterpret_cast<const f16x4*>(&Vt[fl][kb0 + 16 + 4 * g]);

        #pragma unroll
        for (int j = 0; j < 2; ++j) {
            if (w + 4 * j >= ntl) continue;    // wave-uniform

            f32x4 T0 = __builtin_amdgcn_mfma_f32_16x16x16f16(Ak0, Bq[j], zf, 0, 0, 0);
            f32x4 T1 = __builtin_amdgcn_mfma_f32_16x16x16f16(Ak1, Bq[j], zf, 0, 0, 0);

            float s0 = T0[0], s1 = T0[1], s2 = T0[2], s3 = T0[3];
            float s4 = T1[0], s5 = T1[1], s6 = T1[2], s7 = T1[3];
            if (ch == 6) {                      // mask pad k-rows (exp2(-1e30)=0)
                const int kg = kb0 + 4 * g;
                if (kg + 0 >= 196) s0 = -1e30f;
                if (kg + 1 >= 196) s1 = -1e30f;
                if (kg + 2 >= 196) s2 = -1e30f;
                if (kg + 3 >= 196) s3 = -1e30f;
                s4 = -1e30f; s5 = -1e30f; s6 = -1e30f; s7 = -1e30f;
            }
            const float p0 = exp2f(s0), p1 = exp2f(s1);
            const float p2 = exp2f(s2), p3 = exp2f(s3);
            const float p4 = exp2f(s4), p5 = exp2f(s5);
            const float p6 = exp2f(s6), p7 = exp2f(s7);
            lsum[j] += ((p0 + p1) + (p2 + p3)) + ((p4 + p5) + (p6 + p7));

            union { unsigned u[2]; f16x4 v; } pa, pb;
            pa.u[0] = packh2(p0, p1); pa.u[1] = packh2(p2, p3);
            pb.u[0] = packh2(p4, p5); pb.u[1] = packh2(p6, p7);

            accO[j] = __builtin_amdgcn_mfma_f32_16x16x16f16(Av0, pa.v, accO[j], 0, 0, 0);
            accO[j] = __builtin_amdgcn_mfma_f32_16x16x16f16(Av1, pb.v, accO[j], 0, 0, 0);
        }
    }

    #pragma unroll
    for (int j = 0; j < 2; ++j) {
        const int qtl = w + 4 * j;
        if (qtl >= ntl) continue;
        const int qt = qbase + qtl;
        float ls = lsum[j];
        ls += __shfl_xor(ls, 16);
        ls += __shfl_xor(ls, 32);
        const int n = qt * 16 + fl;
        if (n < 196) {
            const float inv = 1.f / ls;
            ushort4 o;
            o.x = f2h(accO[j][0] * inv); o.y = f2h(accO[j][1] * inv);
            o.z = f2h(accO[j][2] * inv); o.w = f2h(accO[j][3] * inv);
            const size_t base = ((size_t)((b * 12 + h) * N_ + n) * 12 + c) * 16 + 4 * g;
            *reinterpret_cast<ushort4*>(&xs_out[base]) = o;
        }
    }
}

// ---------------------------------------------------------------------------
// Channel attention + outer-product combine, 4 rows per 256-thread block.
// f16 qkv + f16 xs in; y f16 out. (r20-verified, unchanged)
// ---------------------------------------------------------------------------
__global__ __launch_bounds__(256) void chan_attn_combine4(
    const unsigned short* __restrict__ qkv,
    const unsigned short* __restrict__ xs,
    unsigned short* __restrict__ yh)
{
    const int sub = threadIdx.x >> 6;
    const int t = threadIdx.x & 63;
    const int flat = blockIdx.x * 4 + sub;     // (b*12+h)*196 + n
    const int n = flat % 196;
    const int h = (flat / 196) % 12;
    const int b = flat / 2352;

    __shared__ float sQ[4][12][4], sK[4][12][4], sV[4][12][4], sXc[4][12][4];
    __shared__ float sXs[4][12][16];

    for (int idx = t; idx < 144; idx += 64) {
        const int c = idx / 12, rem = idx % 12, s = rem >> 2, e = rem & 3;
        const float v = h2f(qkv[(size_t)((b * N_ + n) * 12 + c) * NQKV_PAD + s * 48 + h * 4 + e]);
        if (s == 0) sQ[sub][c][e] = v;
        else if (s == 1) sK[sub][c][e] = v;
        else sV[sub][c][e] = v;
    }
    for (int idx = t; idx < 192; idx += 64) {
        const int c = idx >> 4, j = idx & 15;
        sXs[sub][c][j] = h2f(xs[((size_t)flat * 12 + c) * 16 + j]);
    }
    __syncthreads();

    if (t < 12) {
        const int c = t;
        float s[12];
        float m = -INFINITY;
        #pragma unroll
        for (int c2 = 0; c2 < 12; ++c2) {
            float d = 0.f;
            #pragma unroll
            for (int e = 0; e < 4; ++e) d += sQ[sub][c][e] * sK[sub][c2][e];
            s[c2] = d * 0.5f;
            m = fmaxf(m, s[c2]);
        }
        float lsum = 0.f;
        #pragma unroll
        for (int c2 = 0; c2 < 12; ++c2) { s[c2] = __expf(s[c2] - m); lsum += s[c2]; }
        const float inv = 1.f / lsum;
        #pragma unroll
        for (int i = 0; i < 4; ++i) {
            float a = 0.f;
            #pragma unroll
            for (int c2 = 0; c2 < 12; ++c2) a += s[c2] * sV[sub][c2][i];
            sXc[sub][c][i] = a * inv;
        }
    }
    __syncthreads();

    const size_t yrow = ((size_t)(b * N_ + n) * 12 + h) * (size_t)D_;
    #pragma unroll
    for (int k = 0; k < 12; ++k) {
        const float v = sXc[sub][k][t >> 4] * sXs[sub][k][t & 15];
        yh[yrow + k * 64 + t] = f2h(v);
    }
}

// ---------------------------------------------------------------------------
extern "C" void kernel_launch(void* const* d_in, const int* in_sizes, int n_in,
                              void* d_out, int out_size, void* d_ws, size_t ws_size,
                              hipStream_t stream) {
    const float* x       = (const float*)d_in[0];
    const float* w_qkv_c = (const float*)d_in[1];
    const float* w_qkv_s = (const float*)d_in[2];
    const float* w_proj  = (const float*)d_in[3];
    const float* b_proj  = (const float*)d_in[4];
    float* out = (float*)d_out;

    unsigned short* xh     = (unsigned short*)d_ws;               // R x 768 f16
    unsigned short* wqkv_h = xh + (size_t)R_ * KDIM;              // 768 x 768
    unsigned short* wp_h   = wqkv_h + (size_t)768 * 768;
    unsigned short* qkv_h  = wp_h + (size_t)768 * 768;            // R x 768 f16
    unsigned short* xs_h   = qkv_h + (size_t)R_ * NQKV_PAD;       // B*H*N*C*16 f16
    unsigned short* yh = xh;   // alias: x f16 dead after qkv GEMM

    convert_f16<<<(R_ * KDIM) / 1024, 256, 0, stream>>>(x, xh, R_ * KDIM);
    convert_weights<<<(2 * 768 * 768) / 1024, 256, 0, stream>>>(
        w_qkv_c, w_qkv_s, w_proj, wqkv_h, wp_h);

    {
        const int mtiles = R_ / BM, ntiles = NQKV_PAD / BN;
        gemm_f16<<<mtiles * ntiles, 256, 0, stream>>>(
            xh, wqkv_h, nullptr, nullptr, qkv_h, R_, NQKV_PAD, KDIM, ntiles);
    }
    spatial_attn_mfma<<<B_ * H_ * C_ * 2, 256, 0, stream>>>(qkv_h, xs_h);
    chan_attn_combine4<<<(B_ * H_ * N_) / 4, 256, 0, stream>>>(qkv_h, xs_h, yh);
    {
        const int mtiles = R_ / BM, ntiles = D_ / BN;
        gemm_f16<<<mtiles * ntiles, 256, 0, stream>>>(
            yh, wp_h, b_proj, out, nullptr, R_, D_, KDIM, ntiles);
    }
}

// Round 22
// 136.143 us; speedup vs baseline: 1.2842x; 1.0077x over previous
//
#include <hip/hip_runtime.h>
#include <math.h>

// Problem constants
#define B_  8
#define N_  196
#define C_  12
#define D_  768
#define H_  12
#define R_  (B_*N_*C_)      // 18816 rows
#define KDIM 768
#define NQKV_PAD 768        // 720 real qkv cols padded to 768
#define MPAD 18944          // 74 * 256

typedef _Float16 f16x8 __attribute__((ext_vector_type(8)));   // 8 f16 = 4 VGPR
typedef _Float16 f16x4 __attribute__((ext_vector_type(4)));   // 4 f16 = 2 VGPR
typedef __attribute__((ext_vector_type(4))) float f32x4;

__device__ inline unsigned short f2h(float f) {
    union { _Float16 h; unsigned short u; } v; v.h = (_Float16)f; return v.u;
}
__device__ inline float h2f(unsigned short u) {
    union { unsigned short u; _Float16 h; } v; v.u = u; return (float)v.h;
}
__device__ inline unsigned packh2(float a, float b) {
    return (unsigned)f2h(a) | ((unsigned)f2h(b) << 16);
}

// ---------------------------------------------------------------------------
// fp32 -> f16 elementwise. n must be a multiple of 4.
// ---------------------------------------------------------------------------
__global__ __launch_bounds__(256) void convert_f16(
    const float* __restrict__ in, unsigned short* __restrict__ outh, int n)
{
    int i = (blockIdx.x * 256 + threadIdx.x) * 4;
    if (i >= n) return;
    float4 v = *reinterpret_cast<const float4*>(in + i);
    ushort4 h;
    h.x = f2h(v.x); h.y = f2h(v.y); h.z = f2h(v.z); h.w = f2h(v.w);
    *reinterpret_cast<ushort4*>(outh + i) = h;
}

// One launch: wqkv (packed 768x768, rows 720+ zero) and wp, single f16 each.
__global__ __launch_bounds__(256) void convert_weights(
    const float* __restrict__ wc, const float* __restrict__ ws,
    const float* __restrict__ wp,
    unsigned short* __restrict__ wqkv_h, unsigned short* __restrict__ wp_h)
{
    int i = (blockIdx.x * 256 + threadIdx.x) * 4;
    unsigned short* dh; float4 v; int off;
    if (i < 768 * 768) {
        const int r = i / 768, k = i % 768;
        v = make_float4(0.f, 0.f, 0.f, 0.f);
        if (r < 144)      v = *reinterpret_cast<const float4*>(wc + r * 768 + k);
        else if (r < 720) v = *reinterpret_cast<const float4*>(ws + (r - 144) * 768 + k);
        dh = wqkv_h; off = i;
    } else {
        off = i - 768 * 768;
        if (off >= 768 * 768) return;
        v = *reinterpret_cast<const float4*>(wp + off);
        dh = wp_h;
    }
    ushort4 h;
    h.x = f2h(v.x); h.y = f2h(v.y); h.z = f2h(v.z); h.w = f2h(v.w);
    *reinterpret_cast<ushort4*>(dh + off) = h;
}

// ---------------------------------------------------------------------------
// Single-f16 MFMA GEMM, 256x256 block, 8 waves (512 thr), wave tile 128x64,
// BK=64, 2-phase dbuf (128KB LDS, 1 block/CU, 2 waves/SIMD), counted vmcnt(8),
// both-sides XOR chunk swizzle (r18-verified involution), chunked XCD swizzle.
// FLOP/LDS-byte = 32.8 (was 21.8) — attacks the measured 85 B/cyc LDS ceiling.
// ---------------------------------------------------------------------------
#define BM 256
#define BN 256
#define BK 64

__device__ inline void gload16(const unsigned short* src, void* ldsbase) {
    __builtin_amdgcn_global_load_lds(
        (const __attribute__((address_space(1))) unsigned int*)src,
        (__attribute__((address_space(3))) unsigned int*)ldsbase, 16, 0, 0);
}

__global__ __launch_bounds__(512, 2) void gemm_f16(
    const unsigned short* __restrict__ Ah, const unsigned short* __restrict__ Bh,
    const float* __restrict__ bias,
    float* __restrict__ outp, unsigned short* __restrict__ outh,
    int M, int Nt, int K, int ntiles)
{
    __shared__ unsigned short sA[2][BM][BK];   // 2 x 32 KB
    __shared__ unsigned short sB[2][BN][BK];   // 2 x 32 KB

    const int nwg = gridDim.x;
    const int bid = blockIdx.x;
    const int xcd = bid & 7, slot = bid >> 3;
    const int q = nwg >> 3, r = nwg & 7;
    const int wg = (xcd < r ? xcd * (q + 1) : r * (q + 1) + (xcd - r) * q) + slot;
    const int mt = wg / ntiles, nt = wg - mt * ntiles;   // nt fast: A-panel reuse
    const int m0 = mt * BM, n0 = nt * BN;

    const int tid = threadIdx.x;
    const int w = tid >> 6, l = tid & 63;
    const int fl = l & 15, g = l >> 4;
    const int wr = (w >> 2) * 128;             // wave row base (0 or 128)
    const int wc = (w & 3) * 64;               // wave col base (0,64,128,192)

    f32x4 acc[8][4];
    #pragma unroll
    for (int i = 0; i < 8; ++i)
        #pragma unroll
        for (int j = 0; j < 4; ++j)
            acc[i][j] = (f32x4){0.f, 0.f, 0.f, 0.f};

    // staging: each wave covers rows w*32..w*32+31 of both 256-row tiles via
    // 4 insts of 1KB each. dest row = w*32 + i*8 + (l>>3), chunk = l&7;
    // source chunk pre-swizzled: LDS[row][cb] holds source chunk cb^(row&7).
    const int srow = w * 32 + (l >> 3);
    const int scol = ((l & 7) ^ (l >> 3)) * 8;
    // A-row clamp for last M-tile (stores are guarded; dup reads harmless)
    int arow[4];
    #pragma unroll
    for (int i = 0; i < 4; ++i) {
        int rr = m0 + srow + i * 8;
        arow[i] = rr < M ? rr : (M - 1);
    }

#define STAGE(buf, kk) {                                                                    \
    char* da = (char*)sA + (buf) * 32768 + w * 4096;                                        \
    char* db = (char*)sB + (buf) * 32768 + w * 4096;                                        \
    gload16(Ah + (size_t)arow[0] * K + (kk) + scol, da);                                    \
    gload16(Ah + (size_t)arow[1] * K + (kk) + scol, da + 1024);                             \
    gload16(Ah + (size_t)arow[2] * K + (kk) + scol, da + 2048);                             \
    gload16(Ah + (size_t)arow[3] * K + (kk) + scol, da + 3072);                             \
    const unsigned short* pb = Bh + (size_t)(n0 + srow) * K + (kk) + scol;                  \
    gload16(pb,           db);                                                              \
    gload16(pb +  8 * K,  db + 1024);                                                       \
    gload16(pb + 16 * K,  db + 2048);                                                       \
    gload16(pb + 24 * K,  db + 3072); }

    STAGE(0, 0);                       // 8 loads in flight

    const int KT = K / BK;             // 12
    int cur = 0;
    for (int t = 0; t < KT; ++t) {
        if (t + 1 < KT) {
            STAGE(cur ^ 1, (t + 1) * BK);                      // +8 -> 16 in flight
            asm volatile("s_waitcnt vmcnt(8)" ::: "memory");   // drain tile t only
        } else {
            asm volatile("s_waitcnt vmcnt(0)" ::: "memory");
        }
        asm volatile("s_barrier" ::: "memory");                // tile t visible

        #pragma unroll
        for (int ks = 0; ks < 2; ++ks) {
            const int rcol = ((ks * 4 + g) ^ (fl & 7)) * 8;    // swizzled read col
            f16x8 ah[8];
            #pragma unroll
            for (int fm = 0; fm < 8; ++fm)
                ah[fm] = *reinterpret_cast<const f16x8*>(&sA[cur][wr + fm * 16 + fl][rcol]);
            #pragma unroll
            for (int fn = 0; fn < 4; ++fn) {
                const f16x8 bf = *reinterpret_cast<const f16x8*>(&sB[cur][wc + fn * 16 + fl][rcol]);
                #pragma unroll
                for (int fm = 0; fm < 8; ++fm)
                    acc[fm][fn] = __builtin_amdgcn_mfma_f32_16x16x32_f16(ah[fm], bf, acc[fm][fn], 0, 0, 0);
            }
        }
        asm volatile("s_barrier" ::: "memory");   // WAR fence before restaging [cur]
        cur ^= 1;
    }
#undef STAGE

    const int rg = g * 4;
    if (outh) {
        #pragma unroll
        for (int fm = 0; fm < 8; ++fm)
            #pragma unroll
            for (int fn = 0; fn < 4; ++fn) {
                const int row = m0 + wr + fm * 16 + rg;
                const int col = n0 + wc + fn * 16 + fl;
                #pragma unroll
                for (int rr = 0; rr < 4; ++rr)
                    if (row + rr < M)
                        outh[(size_t)(row + rr) * Nt + col] = f2h(acc[fm][fn][rr]);
            }
    } else {
        #pragma unroll
        for (int fm = 0; fm < 8; ++fm)
            #pragma unroll
            for (int fn = 0; fn < 4; ++fn) {
                const int row = m0 + wr + fm * 16 + rg;
                const int col = n0 + wc + fn * 16 + fl;
                const float bv = bias ? bias[col] : 0.f;
                #pragma unroll
                for (int rr = 0; rr < 4; ++rr)
                    if (row + rr < M)
                        outp[(size_t)(row + rr) * Nt + col] = acc[fm][fn][rr] + bv;
            }
    }
}

// ---------------------------------------------------------------------------
// MFMA spatial attention, all-f16 I/O, 2304 blocks (r21-verified). Unchanged.
// ---------------------------------------------------------------------------
__global__ __launch_bounds__(256) void spatial_attn_mfma(
    const unsigned short* __restrict__ qkv,
    unsigned short* __restrict__ xs_out)
{
    __shared__ unsigned short Kl[224][24];     // f16 K, pad cols
    __shared__ unsigned short Ql[208][24];     // f16 Q (pre-scaled)
    __shared__ unsigned short Vt[16][232];     // f16 V^T [d][k]

    const int bid2 = blockIdx.x;               // 2304 = 1152 x 2
    const int half = bid2 & 1;
    const int bid = bid2 >> 1;
    const int c = bid % 12;
    const int h = (bid / 12) % 12;
    const int b = bid / 144;
    const int tid = threadIdx.x;
    const int w = tid >> 6, l = tid & 63;
    const int fl = l & 15, g = l >> 4;
    const int qbase = half * 7;                // tile range start
    const int ntl = 7 - half;                  // local tile count (7 or 6)

    const float qs = 0.25f * 1.4426950408889634f;   // softmax scale * log2(e)
    for (int idx = tid; idx < N_ * 4; idx += 256) {
        const int n = idx >> 2, eq = (idx & 3) * 4;
        const unsigned short* base =
            qkv + (size_t)((b * N_ + n) * 12 + c) * NQKV_PAD + 144 + h * 16 + eq;
        const ushort4 qv = *reinterpret_cast<const ushort4*>(base);
        const ushort4 kv = *reinterpret_cast<const ushort4*>(base + 192);
        const ushort4 vv = *reinterpret_cast<const ushort4*>(base + 384);
        ushort4 qsc;
        qsc.x = f2h(h2f(qv.x) * qs); qsc.y = f2h(h2f(qv.y) * qs);
        qsc.z = f2h(h2f(qv.z) * qs); qsc.w = f2h(h2f(qv.w) * qs);
        *reinterpret_cast<ushort4*>(&Ql[n][eq]) = qsc;
        *reinterpret_cast<ushort4*>(&Kl[n][eq]) = kv;
        Vt[eq + 0][n] = vv.x;
        Vt[eq + 1][n] = vv.y;
        Vt[eq + 2][n] = vv.z;
        Vt[eq + 3][n] = vv.w;
    }
    for (int idx = tid; idx < 16 * 28; idx += 256) {
        const int d = idx / 28, n = 196 + idx % 28;
        Vt[d][n] = 0;
    }
    __syncthreads();

    f32x4 accO[2];
    float lsum[2];
    #pragma unroll
    for (int j = 0; j < 2; ++j) {
        accO[j] = (f32x4){0.f, 0.f, 0.f, 0.f};
        lsum[j] = 0.f;
    }
    const f32x4 zf = (f32x4){0.f, 0.f, 0.f, 0.f};

    f16x4 Bq[2];
    #pragma unroll
    for (int j = 0; j < 2; ++j) {
        const int qtl = w + 4 * j;
        const int qt = (qtl < ntl) ? (qbase + qtl) : 12;
        Bq[j] = *reinterpret_cast<const f16x4*>(&Ql[qt * 16 + fl][4 * g]);
    }

    for (int ch = 0; ch < 7; ++ch) {
        const int kb0 = ch * 32;
        const f16x4 Ak0 = *reinterpret_cast<const f16x4*>(&Kl[kb0 + fl][4 * g]);
        const f16x4 Ak1 = *reinterpret_cast<const f16x4*>(&Kl[kb0 + 16 + fl][4 * g]);
        const f16x4 Av0 = *reinterpret_cast<const f16x4*>(&Vt[fl][kb0 + 4 * g]);
        const f16x4 Av1 = *reinterpret_cast<const f16x4*>(&Vt[fl][kb0 + 16 + 4 * g]);

        #pragma unroll
        for (int j = 0; j < 2; ++j) {
            if (w + 4 * j >= ntl) continue;    // wave-uniform

            f32x4 T0 = __builtin_amdgcn_mfma_f32_16x16x16f16(Ak0, Bq[j], zf, 0, 0, 0);
            f32x4 T1 = __builtin_amdgcn_mfma_f32_16x16x16f16(Ak1, Bq[j], zf, 0, 0, 0);

            float s0 = T0[0], s1 = T0[1], s2 = T0[2], s3 = T0[3];
            float s4 = T1[0], s5 = T1[1], s6 = T1[2], s7 = T1[3];
            if (ch == 6) {                      // mask pad k-rows (exp2(-1e30)=0)
                const int kg = kb0 + 4 * g;
                if (kg + 0 >= 196) s0 = -1e30f;
                if (kg + 1 >= 196) s1 = -1e30f;
                if (kg + 2 >= 196) s2 = -1e30f;
                if (kg + 3 >= 196) s3 = -1e30f;
                s4 = -1e30f; s5 = -1e30f; s6 = -1e30f; s7 = -1e30f;
            }
            const float p0 = exp2f(s0), p1 = exp2f(s1);
            const float p2 = exp2f(s2), p3 = exp2f(s3);
            const float p4 = exp2f(s4), p5 = exp2f(s5);
            const float p6 = exp2f(s6), p7 = exp2f(s7);
            lsum[j] += ((p0 + p1) + (p2 + p3)) + ((p4 + p5) + (p6 + p7));

            union { unsigned u[2]; f16x4 v; } pa, pb;
            pa.u[0] = packh2(p0, p1); pa.u[1] = packh2(p2, p3);
            pb.u[0] = packh2(p4, p5); pb.u[1] = packh2(p6, p7);

            accO[j] = __builtin_amdgcn_mfma_f32_16x16x16f16(Av0, pa.v, accO[j], 0, 0, 0);
            accO[j] = __builtin_amdgcn_mfma_f32_16x16x16f16(Av1, pb.v, accO[j], 0, 0, 0);
        }
    }

    #pragma unroll
    for (int j = 0; j < 2; ++j) {
        const int qtl = w + 4 * j;
        if (qtl >= ntl) continue;
        const int qt = qbase + qtl;
        float ls = lsum[j];
        ls += __shfl_xor(ls, 16);
        ls += __shfl_xor(ls, 32);
        const int n = qt * 16 + fl;
        if (n < 196) {
            const float inv = 1.f / ls;
            ushort4 o;
            o.x = f2h(accO[j][0] * inv); o.y = f2h(accO[j][1] * inv);
            o.z = f2h(accO[j][2] * inv); o.w = f2h(accO[j][3] * inv);
            const size_t base = ((size_t)((b * 12 + h) * N_ + n) * 12 + c) * 16 + 4 * g;
            *reinterpret_cast<ushort4*>(&xs_out[base]) = o;
        }
    }
}

// ---------------------------------------------------------------------------
// Channel attention + outer-product combine, 4 rows per 256-thread block.
// f16 qkv + f16 xs in; y f16 out. (r20-verified, unchanged)
// ---------------------------------------------------------------------------
__global__ __launch_bounds__(256) void chan_attn_combine4(
    const unsigned short* __restrict__ qkv,
    const unsigned short* __restrict__ xs,
    unsigned short* __restrict__ yh)
{
    const int sub = threadIdx.x >> 6;
    const int t = threadIdx.x & 63;
    const int flat = blockIdx.x * 4 + sub;     // (b*12+h)*196 + n
    const int n = flat % 196;
    const int h = (flat / 196) % 12;
    const int b = flat / 2352;

    __shared__ float sQ[4][12][4], sK[4][12][4], sV[4][12][4], sXc[4][12][4];
    __shared__ float sXs[4][12][16];

    for (int idx = t; idx < 144; idx += 64) {
        const int c = idx / 12, rem = idx % 12, s = rem >> 2, e = rem & 3;
        const float v = h2f(qkv[(size_t)((b * N_ + n) * 12 + c) * NQKV_PAD + s * 48 + h * 4 + e]);
        if (s == 0) sQ[sub][c][e] = v;
        else if (s == 1) sK[sub][c][e] = v;
        else sV[sub][c][e] = v;
    }
    for (int idx = t; idx < 192; idx += 64) {
        const int c = idx >> 4, j = idx & 15;
        sXs[sub][c][j] = h2f(xs[((size_t)flat * 12 + c) * 16 + j]);
    }
    __syncthreads();

    if (t < 12) {
        const int c = t;
        float s[12];
        float m = -INFINITY;
        #pragma unroll
        for (int c2 = 0; c2 < 12; ++c2) {
            float d = 0.f;
            #pragma unroll
            for (int e = 0; e < 4; ++e) d += sQ[sub][c][e] * sK[sub][c2][e];
            s[c2] = d * 0.5f;
            m = fmaxf(m, s[c2]);
        }
        float lsum = 0.f;
        #pragma unroll
        for (int c2 = 0; c2 < 12; ++c2) { s[c2] = __expf(s[c2] - m); lsum += s[c2]; }
        const float inv = 1.f / lsum;
        #pragma unroll
        for (int i = 0; i < 4; ++i) {
            float a = 0.f;
            #pragma unroll
            for (int c2 = 0; c2 < 12; ++c2) a += s[c2] * sV[sub][c2][i];
            sXc[sub][c][i] = a * inv;
        }
    }
    __syncthreads();

    const size_t yrow = ((size_t)(b * N_ + n) * 12 + h) * (size_t)D_;
    #pragma unroll
    for (int k = 0; k < 12; ++k) {
        const float v = sXc[sub][k][t >> 4] * sXs[sub][k][t & 15];
        yh[yrow + k * 64 + t] = f2h(v);
    }
}

// ---------------------------------------------------------------------------
extern "C" void kernel_launch(void* const* d_in, const int* in_sizes, int n_in,
                              void* d_out, int out_size, void* d_ws, size_t ws_size,
                              hipStream_t stream) {
    const float* x       = (const float*)d_in[0];
    const float* w_qkv_c = (const float*)d_in[1];
    const float* w_qkv_s = (const float*)d_in[2];
    const float* w_proj  = (const float*)d_in[3];
    const float* b_proj  = (const float*)d_in[4];
    float* out = (float*)d_out;

    unsigned short* xh     = (unsigned short*)d_ws;               // R x 768 f16
    unsigned short* wqkv_h = xh + (size_t)R_ * KDIM;              // 768 x 768
    unsigned short* wp_h   = wqkv_h + (size_t)768 * 768;
    unsigned short* qkv_h  = wp_h + (size_t)768 * 768;            // R x 768 f16
    unsigned short* xs_h   = qkv_h + (size_t)R_ * NQKV_PAD;       // B*H*N*C*16 f16
    unsigned short* yh = xh;   // alias: x f16 dead after qkv GEMM

    convert_f16<<<(R_ * KDIM) / 1024, 256, 0, stream>>>(x, xh, R_ * KDIM);
    convert_weights<<<(2 * 768 * 768) / 1024, 256, 0, stream>>>(
        w_qkv_c, w_qkv_s, w_proj, wqkv_h, wp_h);

    {
        const int mtiles = MPAD / BM, ntiles = NQKV_PAD / BN;    // 74 x 3
        gemm_f16<<<mtiles * ntiles, 512, 0, stream>>>(
            xh, wqkv_h, nullptr, nullptr, qkv_h, R_, NQKV_PAD, KDIM, ntiles);
    }
    spatial_attn_mfma<<<B_ * H_ * C_ * 2, 256, 0, stream>>>(qkv_h, xs_h);
    chan_attn_combine4<<<(B_ * H_ * N_) / 4, 256, 0, stream>>>(qkv_h, xs_h, yh);
    {
        const int mtiles = MPAD / BM, ntiles = D_ / BN;          // 74 x 3
        gemm_f16<<<mtiles * ntiles, 512, 0, stream>>>(
            yh, wp_h, b_proj, out, nullptr, R_, D_, KDIM, ntiles);
    }
}

// Round 23
// 135.839 us; speedup vs baseline: 1.2871x; 1.0022x over previous
//
#include <hip/hip_runtime.h>
#include <math.h>

// Problem constants
#define B_  8
#define N_  196
#define C_  12
#define D_  768
#define H_  12
#define R_  (B_*N_*C_)      // 18816 rows
#define KDIM 768
#define NQKV_PAD 768        // 720 real qkv cols padded to 768

typedef _Float16 f16x8 __attribute__((ext_vector_type(8)));   // 8 f16 = 4 VGPR
typedef _Float16 f16x4 __attribute__((ext_vector_type(4)));   // 4 f16 = 2 VGPR
typedef __attribute__((ext_vector_type(4))) float f32x4;

__device__ inline unsigned short f2h(float f) {
    union { _Float16 h; unsigned short u; } v; v.h = (_Float16)f; return v.u;
}
__device__ inline float h2f(unsigned short u) {
    union { unsigned short u; _Float16 h; } v; v.u = u; return (float)v.h;
}
__device__ inline unsigned packh2(float a, float b) {
    return (unsigned)f2h(a) | ((unsigned)f2h(b) << 16);
}

// ---------------------------------------------------------------------------
// Single merged conversion launch:
//   region 0: x (R*768 fp32 -> f16)
//   region 1: wqkv packed (768x768; rows<144 wc, 144..719 ws, rest zero)
//   region 2: wp (768x768)
// ---------------------------------------------------------------------------
__global__ __launch_bounds__(256) void convert_all(
    const float* __restrict__ x,
    const float* __restrict__ wc, const float* __restrict__ ws,
    const float* __restrict__ wp,
    unsigned short* __restrict__ xh,
    unsigned short* __restrict__ wqkv_h, unsigned short* __restrict__ wp_h)
{
    int i = (blockIdx.x * 256 + threadIdx.x) * 4;
    const int NX = R_ * KDIM;
    float4 v; unsigned short* dh; int off;
    if (i < NX) {
        v = *reinterpret_cast<const float4*>(x + i);
        dh = xh; off = i;
    } else if (i < NX + 768 * 768) {
        off = i - NX;
        const int r = off / 768, k = off % 768;
        v = make_float4(0.f, 0.f, 0.f, 0.f);
        if (r < 144)      v = *reinterpret_cast<const float4*>(wc + r * 768 + k);
        else if (r < 720) v = *reinterpret_cast<const float4*>(ws + (r - 144) * 768 + k);
        dh = wqkv_h;
    } else {
        off = i - NX - 768 * 768;
        if (off >= 768 * 768) return;
        v = *reinterpret_cast<const float4*>(wp + off);
        dh = wp_h;
    }
    ushort4 h;
    h.x = f2h(v.x); h.y = f2h(v.y); h.z = f2h(v.z); h.w = f2h(v.w);
    *reinterpret_cast<ushort4*>(dh + off) = h;
}

// ---------------------------------------------------------------------------
// Single-f16 MFMA GEMM, 128x128, BK=64, 4 waves, 2-phase dbuf (64KB LDS,
// 2 blocks/CU), counted vmcnt(8), both-sides XOR chunk swizzle (0 conflicts,
// r18/r21-verified), chunked XCD swizzle, nt-fast. Optional f16 output.
// ---------------------------------------------------------------------------
#define BM 128
#define BN 128
#define BK 64

__device__ inline void gload16(const unsigned short* src, void* ldsbase) {
    __builtin_amdgcn_global_load_lds(
        (const __attribute__((address_space(1))) unsigned int*)src,
        (__attribute__((address_space(3))) unsigned int*)ldsbase, 16, 0, 0);
}

__global__ __launch_bounds__(256) void gemm_f16(
    const unsigned short* __restrict__ Ah, const unsigned short* __restrict__ Bh,
    const float* __restrict__ bias,
    float* __restrict__ outp, unsigned short* __restrict__ outh,
    int M, int Nt, int K, int ntiles)
{
    __shared__ unsigned short sA[2][BM][BK];   // 2 x 16 KB
    __shared__ unsigned short sB[2][BN][BK];   // 2 x 16 KB

    const int nwg = gridDim.x;
    const int bid = blockIdx.x;
    const int xcd = bid & 7, slot = bid >> 3;
    const int q = nwg >> 3, r = nwg & 7;
    const int wg = (xcd < r ? xcd * (q + 1) : r * (q + 1) + (xcd - r) * q) + slot;
    const int mt = wg / ntiles, nt = wg - mt * ntiles;   // nt fast: A-panel reuse
    const int m0 = mt * BM, n0 = nt * BN;

    const int tid = threadIdx.x;
    const int w = tid >> 6, l = tid & 63;
    const int fl = l & 15, g = l >> 4;
    const int wr = (w >> 1) * 64, wc = (w & 1) * 64;

    f32x4 acc[4][4];
    #pragma unroll
    for (int i = 0; i < 4; ++i)
        #pragma unroll
        for (int j = 0; j < 4; ++j)
            acc[i][j] = (f32x4){0.f, 0.f, 0.f, 0.f};

    const int srow = w * 32 + (l >> 3);
    const int scol = ((l & 7) ^ (l >> 3)) * 8;     // pre-swizzled source chunk

#define STAGE(buf, kk) {                                                                    \
    const unsigned short* pa = Ah + (size_t)(m0 + srow) * K + (kk) + scol;                  \
    const unsigned short* pb = Bh + (size_t)(n0 + srow) * K + (kk) + scol;                  \
    char* da = (char*)sA + (buf) * 16384 + w * 4096;                                        \
    char* db = (char*)sB + (buf) * 16384 + w * 4096;                                        \
    gload16(pa,           da);                                                              \
    gload16(pa +  8 * K,  da + 1024);                                                       \
    gload16(pa + 16 * K,  da + 2048);                                                       \
    gload16(pa + 24 * K,  da + 3072);                                                       \
    gload16(pb,           db);                                                              \
    gload16(pb +  8 * K,  db + 1024);                                                       \
    gload16(pb + 16 * K,  db + 2048);                                                       \
    gload16(pb + 24 * K,  db + 3072); }

    STAGE(0, 0);                       // 8 loads in flight

    const int KT = K / BK;             // 12
    int cur = 0;
    for (int t = 0; t < KT; ++t) {
        if (t + 1 < KT) {
            STAGE(cur ^ 1, (t + 1) * BK);                      // +8 -> 16 in flight
            asm volatile("s_waitcnt vmcnt(8)" ::: "memory");   // drain tile t only
        } else {
            asm volatile("s_waitcnt vmcnt(0)" ::: "memory");
        }
        asm volatile("s_barrier" ::: "memory");                // tile t visible

        #pragma unroll
        for (int ks = 0; ks < 2; ++ks) {
            const int rcol = ((ks * 4 + g) ^ (fl & 7)) * 8;    // swizzled read col
            f16x8 ah[4];
            #pragma unroll
            for (int fm = 0; fm < 4; ++fm)
                ah[fm] = *reinterpret_cast<const f16x8*>(&sA[cur][wr + fm * 16 + fl][rcol]);
            #pragma unroll
            for (int fn = 0; fn < 4; ++fn) {
                const f16x8 bf = *reinterpret_cast<const f16x8*>(&sB[cur][wc + fn * 16 + fl][rcol]);
                #pragma unroll
                for (int fm = 0; fm < 4; ++fm)
                    acc[fm][fn] = __builtin_amdgcn_mfma_f32_16x16x32_f16(ah[fm], bf, acc[fm][fn], 0, 0, 0);
            }
        }
        asm volatile("s_barrier" ::: "memory");   // WAR fence before restaging [cur]
        cur ^= 1;
    }
#undef STAGE

    const int rg = g * 4;
    if (outh) {
        #pragma unroll
        for (int fm = 0; fm < 4; ++fm)
            #pragma unroll
            for (int fn = 0; fn < 4; ++fn) {
                const int row = m0 + wr + fm * 16 + rg;
                const int col = n0 + wc + fn * 16 + fl;
                #pragma unroll
                for (int rr = 0; rr < 4; ++rr)
                    outh[(size_t)(row + rr) * Nt + col] = f2h(acc[fm][fn][rr]);
            }
    } else {
        #pragma unroll
        for (int fm = 0; fm < 4; ++fm)
            #pragma unroll
            for (int fn = 0; fn < 4; ++fn) {
                const int row = m0 + wr + fm * 16 + rg;
                const int col = n0 + wc + fn * 16 + fl;
                const float bv = bias ? bias[col] : 0.f;
                #pragma unroll
                for (int rr = 0; rr < 4; ++rr)
                    outp[(size_t)(row + rr) * Nt + col] = acc[fm][fn][rr] + bv;
            }
    }
}

// ---------------------------------------------------------------------------
// MFMA spatial attention, all-f16 I/O, 2304 blocks (r21-verified). Unchanged.
// ---------------------------------------------------------------------------
__global__ __launch_bounds__(256) void spatial_attn_mfma(
    const unsigned short* __restrict__ qkv,
    unsigned short* __restrict__ xs_out)
{
    __shared__ unsigned short Kl[224][24];     // f16 K, pad cols
    __shared__ unsigned short Ql[208][24];     // f16 Q (pre-scaled)
    __shared__ unsigned short Vt[16][232];     // f16 V^T [d][k]

    const int bid2 = blockIdx.x;               // 2304 = 1152 x 2
    const int half = bid2 & 1;
    const int bid = bid2 >> 1;
    const int c = bid % 12;
    const int h = (bid / 12) % 12;
    const int b = bid / 144;
    const int tid = threadIdx.x;
    const int w = tid >> 6, l = tid & 63;
    const int fl = l & 15, g = l >> 4;
    const int qbase = half * 7;                // tile range start
    const int ntl = 7 - half;                  // local tile count (7 or 6)

    const float qs = 0.25f * 1.4426950408889634f;   // softmax scale * log2(e)
    for (int idx = tid; idx < N_ * 4; idx += 256) {
        const int n = idx >> 2, eq = (idx & 3) * 4;
        const unsigned short* base =
            qkv + (size_t)((b * N_ + n) * 12 + c) * NQKV_PAD + 144 + h * 16 + eq;
        const ushort4 qv = *reinterpret_cast<const ushort4*>(base);
        const ushort4 kv = *reinterpret_cast<const ushort4*>(base + 192);
        const ushort4 vv = *reinterpret_cast<const ushort4*>(base + 384);
        ushort4 qsc;
        qsc.x = f2h(h2f(qv.x) * qs); qsc.y = f2h(h2f(qv.y) * qs);
        qsc.z = f2h(h2f(qv.z) * qs); qsc.w = f2h(h2f(qv.w) * qs);
        *reinterpret_cast<ushort4*>(&Ql[n][eq]) = qsc;
        *reinterpret_cast<ushort4*>(&Kl[n][eq]) = kv;
        Vt[eq + 0][n] = vv.x;
        Vt[eq + 1][n] = vv.y;
        Vt[eq + 2][n] = vv.z;
        Vt[eq + 3][n] = vv.w;
    }
    for (int idx = tid; idx < 16 * 28; idx += 256) {
        const int d = idx / 28, n = 196 + idx % 28;
        Vt[d][n] = 0;
    }
    __syncthreads();

    f32x4 accO[2];
    float lsum[2];
    #pragma unroll
    for (int j = 0; j < 2; ++j) {
        accO[j] = (f32x4){0.f, 0.f, 0.f, 0.f};
        lsum[j] = 0.f;
    }
    const f32x4 zf = (f32x4){0.f, 0.f, 0.f, 0.f};

    f16x4 Bq[2];
    #pragma unroll
    for (int j = 0; j < 2; ++j) {
        const int qtl = w + 4 * j;
        const int qt = (qtl < ntl) ? (qbase + qtl) : 12;
        Bq[j] = *reinterpret_cast<const f16x4*>(&Ql[qt * 16 + fl][4 * g]);
    }

    for (int ch = 0; ch < 7; ++ch) {
        const int kb0 = ch * 32;
        const f16x4 Ak0 = *reinterpret_cast<const f16x4*>(&Kl[kb0 + fl][4 * g]);
        const f16x4 Ak1 = *reinterpret_cast<const f16x4*>(&Kl[kb0 + 16 + fl][4 * g]);
        const f16x4 Av0 = *reinterpret_cast<const f16x4*>(&Vt[fl][kb0 + 4 * g]);
        const f16x4 Av1 = *reinterpret_cast<const f16x4*>(&Vt[fl][kb0 + 16 + 4 * g]);

        #pragma unroll
        for (int j = 0; j < 2; ++j) {
            if (w + 4 * j >= ntl) continue;    // wave-uniform

            f32x4 T0 = __builtin_amdgcn_mfma_f32_16x16x16f16(Ak0, Bq[j], zf, 0, 0, 0);
            f32x4 T1 = __builtin_amdgcn_mfma_f32_16x16x16f16(Ak1, Bq[j], zf, 0, 0, 0);

            float s0 = T0[0], s1 = T0[1], s2 = T0[2], s3 = T0[3];
            float s4 = T1[0], s5 = T1[1], s6 = T1[2], s7 = T1[3];
            if (ch == 6) {                      // mask pad k-rows (exp2(-1e30)=0)
                const int kg = kb0 + 4 * g;
                if (kg + 0 >= 196) s0 = -1e30f;
                if (kg + 1 >= 196) s1 = -1e30f;
                if (kg + 2 >= 196) s2 = -1e30f;
                if (kg + 3 >= 196) s3 = -1e30f;
                s4 = -1e30f; s5 = -1e30f; s6 = -1e30f; s7 = -1e30f;
            }
            const float p0 = exp2f(s0), p1 = exp2f(s1);
            const float p2 = exp2f(s2), p3 = exp2f(s3);
            const float p4 = exp2f(s4), p5 = exp2f(s5);
            const float p6 = exp2f(s6), p7 = exp2f(s7);
            lsum[j] += ((p0 + p1) + (p2 + p3)) + ((p4 + p5) + (p6 + p7));

            union { unsigned u[2]; f16x4 v; } pa, pb;
            pa.u[0] = packh2(p0, p1); pa.u[1] = packh2(p2, p3);
            pb.u[0] = packh2(p4, p5); pb.u[1] = packh2(p6, p7);

            accO[j] = __builtin_amdgcn_mfma_f32_16x16x16f16(Av0, pa.v, accO[j], 0, 0, 0);
            accO[j] = __builtin_amdgcn_mfma_f32_16x16x16f16(Av1, pb.v, accO[j], 0, 0, 0);
        }
    }

    #pragma unroll
    for (int j = 0; j < 2; ++j) {
        const int qtl = w + 4 * j;
        if (qtl >= ntl) continue;
        const int qt = qbase + qtl;
        float ls = lsum[j];
        ls += __shfl_xor(ls, 16);
        ls += __shfl_xor(ls, 32);
        const int n = qt * 16 + fl;
        if (n < 196) {
            const float inv = 1.f / ls;
            ushort4 o;
            o.x = f2h(accO[j][0] * inv); o.y = f2h(accO[j][1] * inv);
            o.z = f2h(accO[j][2] * inv); o.w = f2h(accO[j][3] * inv);
            const size_t base = ((size_t)((b * 12 + h) * N_ + n) * 12 + c) * 16 + 4 * g;
            *reinterpret_cast<ushort4*>(&xs_out[base]) = o;
        }
    }
}

// ---------------------------------------------------------------------------
// Channel attention + outer-product combine, 4 rows per 256-thread block.
// f16 qkv + f16 xs in; y f16 out. (r20-verified, unchanged)
// ---------------------------------------------------------------------------
__global__ __launch_bounds__(256) void chan_attn_combine4(
    const unsigned short* __restrict__ qkv,
    const unsigned short* __restrict__ xs,
    unsigned short* __restrict__ yh)
{
    const int sub = threadIdx.x >> 6;
    const int t = threadIdx.x & 63;
    const int flat = blockIdx.x * 4 + sub;     // (b*12+h)*196 + n
    const int n = flat % 196;
    const int h = (flat / 196) % 12;
    const int b = flat / 2352;

    __shared__ float sQ[4][12][4], sK[4][12][4], sV[4][12][4], sXc[4][12][4];
    __shared__ float sXs[4][12][16];

    for (int idx = t; idx < 144; idx += 64) {
        const int c = idx / 12, rem = idx % 12, s = rem >> 2, e = rem & 3;
        const float v = h2f(qkv[(size_t)((b * N_ + n) * 12 + c) * NQKV_PAD + s * 48 + h * 4 + e]);
        if (s == 0) sQ[sub][c][e] = v;
        else if (s == 1) sK[sub][c][e] = v;
        else sV[sub][c][e] = v;
    }
    for (int idx = t; idx < 192; idx += 64) {
        const int c = idx >> 4, j = idx & 15;
        sXs[sub][c][j] = h2f(xs[((size_t)flat * 12 + c) * 16 + j]);
    }
    __syncthreads();

    if (t < 12) {
        const int c = t;
        float s[12];
        float m = -INFINITY;
        #pragma unroll
        for (int c2 = 0; c2 < 12; ++c2) {
            float d = 0.f;
            #pragma unroll
            for (int e = 0; e < 4; ++e) d += sQ[sub][c][e] * sK[sub][c2][e];
            s[c2] = d * 0.5f;
            m = fmaxf(m, s[c2]);
        }
        float lsum = 0.f;
        #pragma unroll
        for (int c2 = 0; c2 < 12; ++c2) { s[c2] = __expf(s[c2] - m); lsum += s[c2]; }
        const float inv = 1.f / lsum;
        #pragma unroll
        for (int i = 0; i < 4; ++i) {
            float a = 0.f;
            #pragma unroll
            for (int c2 = 0; c2 < 12; ++c2) a += s[c2] * sV[sub][c2][i];
            sXc[sub][c][i] = a * inv;
        }
    }
    __syncthreads();

    const size_t yrow = ((size_t)(b * N_ + n) * 12 + h) * (size_t)D_;
    #pragma unroll
    for (int k = 0; k < 12; ++k) {
        const float v = sXc[sub][k][t >> 4] * sXs[sub][k][t & 15];
        yh[yrow + k * 64 + t] = f2h(v);
    }
}

// ---------------------------------------------------------------------------
extern "C" void kernel_launch(void* const* d_in, const int* in_sizes, int n_in,
                              void* d_out, int out_size, void* d_ws, size_t ws_size,
                              hipStream_t stream) {
    const float* x       = (const float*)d_in[0];
    const float* w_qkv_c = (const float*)d_in[1];
    const float* w_qkv_s = (const float*)d_in[2];
    const float* w_proj  = (const float*)d_in[3];
    const float* b_proj  = (const float*)d_in[4];
    float* out = (float*)d_out;

    unsigned short* xh     = (unsigned short*)d_ws;               // R x 768 f16
    unsigned short* wqkv_h = xh + (size_t)R_ * KDIM;              // 768 x 768
    unsigned short* wp_h   = wqkv_h + (size_t)768 * 768;
    unsigned short* qkv_h  = wp_h + (size_t)768 * 768;            // R x 768 f16
    unsigned short* xs_h   = qkv_h + (size_t)R_ * NQKV_PAD;       // B*H*N*C*16 f16
    unsigned short* yh = xh;   // alias: x f16 dead after qkv GEMM

    {
        const int total = (R_ * KDIM + 2 * 768 * 768) / 4;
        convert_all<<<(total + 255) / 256, 256, 0, stream>>>(
            x, w_qkv_c, w_qkv_s, w_proj, xh, wqkv_h, wp_h);
    }
    {
        const int mtiles = R_ / BM, ntiles = NQKV_PAD / BN;      // 147 x 6
        gemm_f16<<<mtiles * ntiles, 256, 0, stream>>>(
            xh, wqkv_h, nullptr, nullptr, qkv_h, R_, NQKV_PAD, KDIM, ntiles);
    }
    spatial_attn_mfma<<<B_ * H_ * C_ * 2, 256, 0, stream>>>(qkv_h, xs_h);
    chan_attn_combine4<<<(B_ * H_ * N_) / 4, 256, 0, stream>>>(qkv_h, xs_h, yh);
    {
        const int mtiles = R_ / BM, ntiles = D_ / BN;            // 147 x 6
        gemm_f16<<<mtiles * ntiles, 256, 0, stream>>>(
            yh, wp_h, b_proj, out, nullptr, R_, D_, KDIM, ntiles);
    }
}

// Round 24
// 132.258 us; speedup vs baseline: 1.3219x; 1.0271x over previous
//
#include <hip/hip_runtime.h>
#include <math.h>

// Problem constants
#define B_  8
#define N_  196
#define C_  12
#define D_  768
#define H_  12
#define R_  (B_*N_*C_)      // 18816 rows
#define KDIM 768
#define NQKV_PAD 768        // 720 real qkv cols padded to 768

typedef _Float16 f16x8 __attribute__((ext_vector_type(8)));   // 8 f16 = 4 VGPR
typedef _Float16 f16x4 __attribute__((ext_vector_type(4)));   // 4 f16 = 2 VGPR
typedef __attribute__((ext_vector_type(4))) float f32x4;

__device__ inline unsigned short f2h(float f) {
    union { _Float16 h; unsigned short u; } v; v.h = (_Float16)f; return v.u;
}
__device__ inline float h2f(unsigned short u) {
    union { unsigned short u; _Float16 h; } v; v.u = u; return (float)v.h;
}
__device__ inline unsigned packh2(float a, float b) {
    return (unsigned)f2h(a) | ((unsigned)f2h(b) << 16);
}

// ---------------------------------------------------------------------------
// Single merged conversion launch (r23-verified).
// ---------------------------------------------------------------------------
__global__ __launch_bounds__(256) void convert_all(
    const float* __restrict__ x,
    const float* __restrict__ wc, const float* __restrict__ ws,
    const float* __restrict__ wp,
    unsigned short* __restrict__ xh,
    unsigned short* __restrict__ wqkv_h, unsigned short* __restrict__ wp_h)
{
    int i = (blockIdx.x * 256 + threadIdx.x) * 4;
    const int NX = R_ * KDIM;
    float4 v; unsigned short* dh; int off;
    if (i < NX) {
        v = *reinterpret_cast<const float4*>(x + i);
        dh = xh; off = i;
    } else if (i < NX + 768 * 768) {
        off = i - NX;
        const int r = off / 768, k = off % 768;
        v = make_float4(0.f, 0.f, 0.f, 0.f);
        if (r < 144)      v = *reinterpret_cast<const float4*>(wc + r * 768 + k);
        else if (r < 720) v = *reinterpret_cast<const float4*>(ws + (r - 144) * 768 + k);
        dh = wqkv_h;
    } else {
        off = i - NX - 768 * 768;
        if (off >= 768 * 768) return;
        v = *reinterpret_cast<const float4*>(wp + off);
        dh = wp_h;
    }
    ushort4 h;
    h.x = f2h(v.x); h.y = f2h(v.y); h.z = f2h(v.z); h.w = f2h(v.w);
    *reinterpret_cast<ushort4*>(dh + off) = h;
}

// ---------------------------------------------------------------------------
// Single-f16 MFMA GEMM, 128x128, BK=64. THIS ROUND: 8 waves (512 thr),
// wave tile 64x32 (acc[4][2]) — doubles waves/CU (16, 4/SIMD) at the same
// 2-blocks/CU LDS shape for latency hiding. Staging 4 gloads/wave,
// counted vmcnt(4). Swizzle involution unchanged (row&7 == l>>3).
// ---------------------------------------------------------------------------
#define BM 128
#define BN 128
#define BK 64

__device__ inline void gload16(const unsigned short* src, void* ldsbase) {
    __builtin_amdgcn_global_load_lds(
        (const __attribute__((address_space(1))) unsigned int*)src,
        (__attribute__((address_space(3))) unsigned int*)ldsbase, 16, 0, 0);
}

__global__ __launch_bounds__(512, 2) void gemm_f16(
    const unsigned short* __restrict__ Ah, const unsigned short* __restrict__ Bh,
    const float* __restrict__ bias,
    float* __restrict__ outp, unsigned short* __restrict__ outh,
    int M, int Nt, int K, int ntiles)
{
    __shared__ unsigned short sA[2][BM][BK];   // 2 x 16 KB
    __shared__ unsigned short sB[2][BN][BK];   // 2 x 16 KB

    const int nwg = gridDim.x;
    const int bid = blockIdx.x;
    const int xcd = bid & 7, slot = bid >> 3;
    const int q = nwg >> 3, r = nwg & 7;
    const int wg = (xcd < r ? xcd * (q + 1) : r * (q + 1) + (xcd - r) * q) + slot;
    const int mt = wg / ntiles, nt = wg - mt * ntiles;   // nt fast: A-panel reuse
    const int m0 = mt * BM, n0 = nt * BN;

    const int tid = threadIdx.x;
    const int w = tid >> 6, l = tid & 63;
    const int fl = l & 15, g = l >> 4;
    const int wr = (w >> 2) * 64;              // wave row base (0 or 64)
    const int wc = (w & 3) * 32;               // wave col base (0,32,64,96)

    f32x4 acc[4][2];
    #pragma unroll
    for (int i = 0; i < 4; ++i)
        #pragma unroll
        for (int j = 0; j < 2; ++j)
            acc[i][j] = (f32x4){0.f, 0.f, 0.f, 0.f};

    // staging: each of 8 waves covers 16 rows of A and of B (2 x 1KB each).
    // dest row = w*16 + (l>>3) + {0,8}; chunk = l&7.  row&7 == l>>3, so the
    // pre-swizzled source chunk (l&7)^(l>>3) keeps the verified involution.
    const int srow = w * 16 + (l >> 3);
    const int scol = ((l & 7) ^ (l >> 3)) * 8;

#define STAGE(buf, kk) {                                                                    \
    const unsigned short* pa = Ah + (size_t)(m0 + srow) * K + (kk) + scol;                  \
    const unsigned short* pb = Bh + (size_t)(n0 + srow) * K + (kk) + scol;                  \
    char* da = (char*)sA + (buf) * 16384 + w * 2048;                                        \
    char* db = (char*)sB + (buf) * 16384 + w * 2048;                                        \
    gload16(pa,          da);                                                               \
    gload16(pa + 8 * K,  da + 1024);                                                        \
    gload16(pb,          db);                                                               \
    gload16(pb + 8 * K,  db + 1024); }

    STAGE(0, 0);                       // 4 loads in flight

    const int KT = K / BK;             // 12
    int cur = 0;
    for (int t = 0; t < KT; ++t) {
        if (t + 1 < KT) {
            STAGE(cur ^ 1, (t + 1) * BK);                      // +4 -> 8 in flight
            asm volatile("s_waitcnt vmcnt(4)" ::: "memory");   // drain tile t only
        } else {
            asm volatile("s_waitcnt vmcnt(0)" ::: "memory");
        }
        asm volatile("s_barrier" ::: "memory");                // tile t visible

        #pragma unroll
        for (int ks = 0; ks < 2; ++ks) {
            const int rcol = ((ks * 4 + g) ^ (fl & 7)) * 8;    // swizzled read col
            f16x8 ah[4];
            #pragma unroll
            for (int fm = 0; fm < 4; ++fm)
                ah[fm] = *reinterpret_cast<const f16x8*>(&sA[cur][wr + fm * 16 + fl][rcol]);
            #pragma unroll
            for (int fn = 0; fn < 2; ++fn) {
                const f16x8 bf = *reinterpret_cast<const f16x8*>(&sB[cur][wc + fn * 16 + fl][rcol]);
                #pragma unroll
                for (int fm = 0; fm < 4; ++fm)
                    acc[fm][fn] = __builtin_amdgcn_mfma_f32_16x16x32_f16(ah[fm], bf, acc[fm][fn], 0, 0, 0);
            }
        }
        asm volatile("s_barrier" ::: "memory");   // WAR fence before restaging [cur]
        cur ^= 1;
    }
#undef STAGE

    const int rg = g * 4;
    if (outh) {
        #pragma unroll
        for (int fm = 0; fm < 4; ++fm)
            #pragma unroll
            for (int fn = 0; fn < 2; ++fn) {
                const int row = m0 + wr + fm * 16 + rg;
                const int col = n0 + wc + fn * 16 + fl;
                #pragma unroll
                for (int rr = 0; rr < 4; ++rr)
                    outh[(size_t)(row + rr) * Nt + col] = f2h(acc[fm][fn][rr]);
            }
    } else {
        #pragma unroll
        for (int fm = 0; fm < 4; ++fm)
            #pragma unroll
            for (int fn = 0; fn < 2; ++fn) {
                const int row = m0 + wr + fm * 16 + rg;
                const int col = n0 + wc + fn * 16 + fl;
                const float bv = bias ? bias[col] : 0.f;
                #pragma unroll
                for (int rr = 0; rr < 4; ++rr)
                    outp[(size_t)(row + rr) * Nt + col] = acc[fm][fn][rr] + bv;
            }
    }
}

// ---------------------------------------------------------------------------
// MFMA spatial attention, all-f16 I/O, 2304 blocks (r21-verified). Unchanged.
// ---------------------------------------------------------------------------
__global__ __launch_bounds__(256) void spatial_attn_mfma(
    const unsigned short* __restrict__ qkv,
    unsigned short* __restrict__ xs_out)
{
    __shared__ unsigned short Kl[224][24];     // f16 K, pad cols
    __shared__ unsigned short Ql[208][24];     // f16 Q (pre-scaled)
    __shared__ unsigned short Vt[16][232];     // f16 V^T [d][k]

    const int bid2 = blockIdx.x;               // 2304 = 1152 x 2
    const int half = bid2 & 1;
    const int bid = bid2 >> 1;
    const int c = bid % 12;
    const int h = (bid / 12) % 12;
    const int b = bid / 144;
    const int tid = threadIdx.x;
    const int w = tid >> 6, l = tid & 63;
    const int fl = l & 15, g = l >> 4;
    const int qbase = half * 7;                // tile range start
    const int ntl = 7 - half;                  // local tile count (7 or 6)

    const float qs = 0.25f * 1.4426950408889634f;   // softmax scale * log2(e)
    for (int idx = tid; idx < N_ * 4; idx += 256) {
        const int n = idx >> 2, eq = (idx & 3) * 4;
        const unsigned short* base =
            qkv + (size_t)((b * N_ + n) * 12 + c) * NQKV_PAD + 144 + h * 16 + eq;
        const ushort4 qv = *reinterpret_cast<const ushort4*>(base);
        const ushort4 kv = *reinterpret_cast<const ushort4*>(base + 192);
        const ushort4 vv = *reinterpret_cast<const ushort4*>(base + 384);
        ushort4 qsc;
        qsc.x = f2h(h2f(qv.x) * qs); qsc.y = f2h(h2f(qv.y) * qs);
        qsc.z = f2h(h2f(qv.z) * qs); qsc.w = f2h(h2f(qv.w) * qs);
        *reinterpret_cast<ushort4*>(&Ql[n][eq]) = qsc;
        *reinterpret_cast<ushort4*>(&Kl[n][eq]) = kv;
        Vt[eq + 0][n] = vv.x;
        Vt[eq + 1][n] = vv.y;
        Vt[eq + 2][n] = vv.z;
        Vt[eq + 3][n] = vv.w;
    }
    for (int idx = tid; idx < 16 * 28; idx += 256) {
        const int d = idx / 28, n = 196 + idx % 28;
        Vt[d][n] = 0;
    }
    __syncthreads();

    f32x4 accO[2];
    float lsum[2];
    #pragma unroll
    for (int j = 0; j < 2; ++j) {
        accO[j] = (f32x4){0.f, 0.f, 0.f, 0.f};
        lsum[j] = 0.f;
    }
    const f32x4 zf = (f32x4){0.f, 0.f, 0.f, 0.f};

    f16x4 Bq[2];
    #pragma unroll
    for (int j = 0; j < 2; ++j) {
        const int qtl = w + 4 * j;
        const int qt = (qtl < ntl) ? (qbase + qtl) : 12;
        Bq[j] = *reinterpret_cast<const f16x4*>(&Ql[qt * 16 + fl][4 * g]);
    }

    for (int ch = 0; ch < 7; ++ch) {
        const int kb0 = ch * 32;
        const f16x4 Ak0 = *reinterpret_cast<const f16x4*>(&Kl[kb0 + fl][4 * g]);
        const f16x4 Ak1 = *reinterpret_cast<const f16x4*>(&Kl[kb0 + 16 + fl][4 * g]);
        const f16x4 Av0 = *reinterpret_cast<const f16x4*>(&Vt[fl][kb0 + 4 * g]);
        const f16x4 Av1 = *reinterpret_cast<const f16x4*>(&Vt[fl][kb0 + 16 + 4 * g]);

        #pragma unroll
        for (int j = 0; j < 2; ++j) {
            if (w + 4 * j >= ntl) continue;    // wave-uniform

            f32x4 T0 = __builtin_amdgcn_mfma_f32_16x16x16f16(Ak0, Bq[j], zf, 0, 0, 0);
            f32x4 T1 = __builtin_amdgcn_mfma_f32_16x16x16f16(Ak1, Bq[j], zf, 0, 0, 0);

            float s0 = T0[0], s1 = T0[1], s2 = T0[2], s3 = T0[3];
            float s4 = T1[0], s5 = T1[1], s6 = T1[2], s7 = T1[3];
            if (ch == 6) {                      // mask pad k-rows (exp2(-1e30)=0)
                const int kg = kb0 + 4 * g;
                if (kg + 0 >= 196) s0 = -1e30f;
                if (kg + 1 >= 196) s1 = -1e30f;
                if (kg + 2 >= 196) s2 = -1e30f;
                if (kg + 3 >= 196) s3 = -1e30f;
                s4 = -1e30f; s5 = -1e30f; s6 = -1e30f; s7 = -1e30f;
            }
            const float p0 = exp2f(s0), p1 = exp2f(s1);
            const float p2 = exp2f(s2), p3 = exp2f(s3);
            const float p4 = exp2f(s4), p5 = exp2f(s5);
            const float p6 = exp2f(s6), p7 = exp2f(s7);
            lsum[j] += ((p0 + p1) + (p2 + p3)) + ((p4 + p5) + (p6 + p7));

            union { unsigned u[2]; f16x4 v; } pa, pb;
            pa.u[0] = packh2(p0, p1); pa.u[1] = packh2(p2, p3);
            pb.u[0] = packh2(p4, p5); pb.u[1] = packh2(p6, p7);

            accO[j] = __builtin_amdgcn_mfma_f32_16x16x16f16(Av0, pa.v, accO[j], 0, 0, 0);
            accO[j] = __builtin_amdgcn_mfma_f32_16x16x16f16(Av1, pb.v, accO[j], 0, 0, 0);
        }
    }

    #pragma unroll
    for (int j = 0; j < 2; ++j) {
        const int qtl = w + 4 * j;
        if (qtl >= ntl) continue;
        const int qt = qbase + qtl;
        float ls = lsum[j];
        ls += __shfl_xor(ls, 16);
        ls += __shfl_xor(ls, 32);
        const int n = qt * 16 + fl;
        if (n < 196) {
            const float inv = 1.f / ls;
            ushort4 o;
            o.x = f2h(accO[j][0] * inv); o.y = f2h(accO[j][1] * inv);
            o.z = f2h(accO[j][2] * inv); o.w = f2h(accO[j][3] * inv);
            const size_t base = ((size_t)((b * 12 + h) * N_ + n) * 12 + c) * 16 + 4 * g;
            *reinterpret_cast<ushort4*>(&xs_out[base]) = o;
        }
    }
}

// ---------------------------------------------------------------------------
// Channel attention + outer-product combine, 4 rows per 256-thread block.
// f16 qkv + f16 xs in; y f16 out. (r20-verified, unchanged)
// ---------------------------------------------------------------------------
__global__ __launch_bounds__(256) void chan_attn_combine4(
    const unsigned short* __restrict__ qkv,
    const unsigned short* __restrict__ xs,
    unsigned short* __restrict__ yh)
{
    const int sub = threadIdx.x >> 6;
    const int t = threadIdx.x & 63;
    const int flat = blockIdx.x * 4 + sub;     // (b*12+h)*196 + n
    const int n = flat % 196;
    const int h = (flat / 196) % 12;
    const int b = flat / 2352;

    __shared__ float sQ[4][12][4], sK[4][12][4], sV[4][12][4], sXc[4][12][4];
    __shared__ float sXs[4][12][16];

    for (int idx = t; idx < 144; idx += 64) {
        const int c = idx / 12, rem = idx % 12, s = rem >> 2, e = rem & 3;
        const float v = h2f(qkv[(size_t)((b * N_ + n) * 12 + c) * NQKV_PAD + s * 48 + h * 4 + e]);
        if (s == 0) sQ[sub][c][e] = v;
        else if (s == 1) sK[sub][c][e] = v;
        else sV[sub][c][e] = v;
    }
    for (int idx = t; idx < 192; idx += 64) {
        const int c = idx >> 4, j = idx & 15;
        sXs[sub][c][j] = h2f(xs[((size_t)flat * 12 + c) * 16 + j]);
    }
    __syncthreads();

    if (t < 12) {
        const int c = t;
        float s[12];
        float m = -INFINITY;
        #pragma unroll
        for (int c2 = 0; c2 < 12; ++c2) {
            float d = 0.f;
            #pragma unroll
            for (int e = 0; e < 4; ++e) d += sQ[sub][c][e] * sK[sub][c2][e];
            s[c2] = d * 0.5f;
            m = fmaxf(m, s[c2]);
        }
        float lsum = 0.f;
        #pragma unroll
        for (int c2 = 0; c2 < 12; ++c2) { s[c2] = __expf(s[c2] - m); lsum += s[c2]; }
        const float inv = 1.f / lsum;
        #pragma unroll
        for (int i = 0; i < 4; ++i) {
            float a = 0.f;
            #pragma unroll
            for (int c2 = 0; c2 < 12; ++c2) a += s[c2] * sV[sub][c2][i];
            sXc[sub][c][i] = a * inv;
        }
    }
    __syncthreads();

    const size_t yrow = ((size_t)(b * N_ + n) * 12 + h) * (size_t)D_;
    #pragma unroll
    for (int k = 0; k < 12; ++k) {
        const float v = sXc[sub][k][t >> 4] * sXs[sub][k][t & 15];
        yh[yrow + k * 64 + t] = f2h(v);
    }
}

// ---------------------------------------------------------------------------
extern "C" void kernel_launch(void* const* d_in, const int* in_sizes, int n_in,
                              void* d_out, int out_size, void* d_ws, size_t ws_size,
                              hipStream_t stream) {
    const float* x       = (const float*)d_in[0];
    const float* w_qkv_c = (const float*)d_in[1];
    const float* w_qkv_s = (const float*)d_in[2];
    const float* w_proj  = (const float*)d_in[3];
    const float* b_proj  = (const float*)d_in[4];
    float* out = (float*)d_out;

    unsigned short* xh     = (unsigned short*)d_ws;               // R x 768 f16
    unsigned short* wqkv_h = xh + (size_t)R_ * KDIM;              // 768 x 768
    unsigned short* wp_h   = wqkv_h + (size_t)768 * 768;
    unsigned short* qkv_h  = wp_h + (size_t)768 * 768;            // R x 768 f16
    unsigned short* xs_h   = qkv_h + (size_t)R_ * NQKV_PAD;       // B*H*N*C*16 f16
    unsigned short* yh = xh;   // alias: x f16 dead after qkv GEMM

    {
        const int total = (R_ * KDIM + 2 * 768 * 768) / 4;
        convert_all<<<(total + 255) / 256, 256, 0, stream>>>(
            x, w_qkv_c, w_qkv_s, w_proj, xh, wqkv_h, wp_h);
    }
    {
        const int mtiles = R_ / BM, ntiles = NQKV_PAD / BN;      // 147 x 6
        gemm_f16<<<mtiles * ntiles, 512, 0, stream>>>(
            xh, wqkv_h, nullptr, nullptr, qkv_h, R_, NQKV_PAD, KDIM, ntiles);
    }
    spatial_attn_mfma<<<B_ * H_ * C_ * 2, 256, 0, stream>>>(qkv_h, xs_h);
    chan_attn_combine4<<<(B_ * H_ * N_) / 4, 256, 0, stream>>>(qkv_h, xs_h, yh);
    {
        const int mtiles = R_ / BM, ntiles = D_ / BN;            // 147 x 6
        gemm_f16<<<mtiles * ntiles, 512, 0, stream>>>(
            yh, wp_h, b_proj, out, nullptr, R_, D_, KDIM, ntiles);
    }
}

// Round 26
// 130.411 us; speedup vs baseline: 1.3407x; 1.0142x over previous
//
#include <hip/hip_runtime.h>
#include <math.h>

// Problem constants
#define B_  8
#define N_  196
#define C_  12
#define D_  768
#define H_  12
#define R_  (B_*N_*C_)      // 18816 rows
#define KDIM 768
#define NQKV_PAD 768        // 720 real qkv cols padded to 768

typedef _Float16 f16x8 __attribute__((ext_vector_type(8)));   // 8 f16 = 4 VGPR
typedef _Float16 f16x4 __attribute__((ext_vector_type(4)));   // 4 f16 = 2 VGPR
typedef __fp16 fp16x2 __attribute__((ext_vector_type(2)));    // cvt_pkrtz return type
typedef __attribute__((ext_vector_type(4))) float f32x4;

__device__ inline unsigned short f2h(float f) {
    union { _Float16 h; unsigned short u; } v; v.h = (_Float16)f; return v.u;
}
__device__ inline float h2f(unsigned short u) {
    union { unsigned short u; _Float16 h; } v; v.u = u; return (float)v.h;
}
// single-instruction packed f32x2 -> f16x2 (RTZ)
__device__ inline unsigned pk2u(float a, float b) {
    union { fp16x2 h; unsigned u; } v;
    v.h = __builtin_amdgcn_cvt_pkrtz(a, b);
    return v.u;
}

// ---------------------------------------------------------------------------
// Single merged conversion launch (r23-verified; pkrtz converts).
// ---------------------------------------------------------------------------
__global__ __launch_bounds__(256) void convert_all(
    const float* __restrict__ x,
    const float* __restrict__ wc, const float* __restrict__ ws,
    const float* __restrict__ wp,
    unsigned short* __restrict__ xh,
    unsigned short* __restrict__ wqkv_h, unsigned short* __restrict__ wp_h)
{
    int i = (blockIdx.x * 256 + threadIdx.x) * 4;
    const int NX = R_ * KDIM;
    float4 v; unsigned short* dh; int off;
    if (i < NX) {
        v = *reinterpret_cast<const float4*>(x + i);
        dh = xh; off = i;
    } else if (i < NX + 768 * 768) {
        off = i - NX;
        const int r = off / 768, k = off % 768;
        v = make_float4(0.f, 0.f, 0.f, 0.f);
        if (r < 144)      v = *reinterpret_cast<const float4*>(wc + r * 768 + k);
        else if (r < 720) v = *reinterpret_cast<const float4*>(ws + (r - 144) * 768 + k);
        dh = wqkv_h;
    } else {
        off = i - NX - 768 * 768;
        if (off >= 768 * 768) return;
        v = *reinterpret_cast<const float4*>(wp + off);
        dh = wp_h;
    }
    uint2 h;
    h.x = pk2u(v.x, v.y);
    h.y = pk2u(v.z, v.w);
    *reinterpret_cast<uint2*>(dh + off) = h;
}

// ---------------------------------------------------------------------------
// Single-f16 MFMA GEMM, 128x128, BK=64, 8 waves (r24-verified). Unchanged.
// ---------------------------------------------------------------------------
#define BM 128
#define BN 128
#define BK 64

__device__ inline void gload16(const unsigned short* src, void* ldsbase) {
    __builtin_amdgcn_global_load_lds(
        (const __attribute__((address_space(1))) unsigned int*)src,
        (__attribute__((address_space(3))) unsigned int*)ldsbase, 16, 0, 0);
}

__global__ __launch_bounds__(512, 2) void gemm_f16(
    const unsigned short* __restrict__ Ah, const unsigned short* __restrict__ Bh,
    const float* __restrict__ bias,
    float* __restrict__ outp, unsigned short* __restrict__ outh,
    int M, int Nt, int K, int ntiles)
{
    __shared__ unsigned short sA[2][BM][BK];   // 2 x 16 KB
    __shared__ unsigned short sB[2][BN][BK];   // 2 x 16 KB

    const int nwg = gridDim.x;
    const int bid = blockIdx.x;
    const int xcd = bid & 7, slot = bid >> 3;
    const int q = nwg >> 3, r = nwg & 7;
    const int wg = (xcd < r ? xcd * (q + 1) : r * (q + 1) + (xcd - r) * q) + slot;
    const int mt = wg / ntiles, nt = wg - mt * ntiles;   // nt fast: A-panel reuse
    const int m0 = mt * BM, n0 = nt * BN;

    const int tid = threadIdx.x;
    const int w = tid >> 6, l = tid & 63;
    const int fl = l & 15, g = l >> 4;
    const int wr = (w >> 2) * 64;              // wave row base (0 or 64)
    const int wc = (w & 3) * 32;               // wave col base (0,32,64,96)

    f32x4 acc[4][2];
    #pragma unroll
    for (int i = 0; i < 4; ++i)
        #pragma unroll
        for (int j = 0; j < 2; ++j)
            acc[i][j] = (f32x4){0.f, 0.f, 0.f, 0.f};

    const int srow = w * 16 + (l >> 3);
    const int scol = ((l & 7) ^ (l >> 3)) * 8;

#define STAGE(buf, kk) {                                                                    \
    const unsigned short* pa = Ah + (size_t)(m0 + srow) * K + (kk) + scol;                  \
    const unsigned short* pb = Bh + (size_t)(n0 + srow) * K + (kk) + scol;                  \
    char* da = (char*)sA + (buf) * 16384 + w * 2048;                                        \
    char* db = (char*)sB + (buf) * 16384 + w * 2048;                                        \
    gload16(pa,          da);                                                               \
    gload16(pa + 8 * K,  da + 1024);                                                        \
    gload16(pb,          db);                                                               \
    gload16(pb + 8 * K,  db + 1024); }

    STAGE(0, 0);                       // 4 loads in flight

    const int KT = K / BK;             // 12
    int cur = 0;
    for (int t = 0; t < KT; ++t) {
        if (t + 1 < KT) {
            STAGE(cur ^ 1, (t + 1) * BK);                      // +4 -> 8 in flight
            asm volatile("s_waitcnt vmcnt(4)" ::: "memory");   // drain tile t only
        } else {
            asm volatile("s_waitcnt vmcnt(0)" ::: "memory");
        }
        asm volatile("s_barrier" ::: "memory");                // tile t visible

        #pragma unroll
        for (int ks = 0; ks < 2; ++ks) {
            const int rcol = ((ks * 4 + g) ^ (fl & 7)) * 8;    // swizzled read col
            f16x8 ah[4];
            #pragma unroll
            for (int fm = 0; fm < 4; ++fm)
                ah[fm] = *reinterpret_cast<const f16x8*>(&sA[cur][wr + fm * 16 + fl][rcol]);
            #pragma unroll
            for (int fn = 0; fn < 2; ++fn) {
                const f16x8 bf = *reinterpret_cast<const f16x8*>(&sB[cur][wc + fn * 16 + fl][rcol]);
                #pragma unroll
                for (int fm = 0; fm < 4; ++fm)
                    acc[fm][fn] = __builtin_amdgcn_mfma_f32_16x16x32_f16(ah[fm], bf, acc[fm][fn], 0, 0, 0);
            }
        }
        asm volatile("s_barrier" ::: "memory");   // WAR fence before restaging [cur]
        cur ^= 1;
    }
#undef STAGE

    const int rg = g * 4;
    if (outh) {
        #pragma unroll
        for (int fm = 0; fm < 4; ++fm)
            #pragma unroll
            for (int fn = 0; fn < 2; ++fn) {
                const int row = m0 + wr + fm * 16 + rg;
                const int col = n0 + wc + fn * 16 + fl;
                #pragma unroll
                for (int rr = 0; rr < 4; ++rr)
                    outh[(size_t)(row + rr) * Nt + col] = f2h(acc[fm][fn][rr]);
            }
    } else {
        #pragma unroll
        for (int fm = 0; fm < 4; ++fm)
            #pragma unroll
            for (int fn = 0; fn < 2; ++fn) {
                const int row = m0 + wr + fm * 16 + rg;
                const int col = n0 + wc + fn * 16 + fl;
                const float bv = bias ? bias[col] : 0.f;
                #pragma unroll
                for (int rr = 0; rr < 4; ++rr)
                    outp[(size_t)(row + rr) * Nt + col] = acc[fm][fn][rr] + bv;
            }
    }
}

// ---------------------------------------------------------------------------
// MFMA spatial attention, all-f16 I/O, 2304 blocks.
//  - P-pack & Q staging via v_cvt_pkrtz (1 VALU op per f32 pair)
//  - Vt padded [16][232] -> [16][236]: stride 118 dw == 22 mod 32 -> gcd 2
// ---------------------------------------------------------------------------
__global__ __launch_bounds__(256) void spatial_attn_mfma(
    const unsigned short* __restrict__ qkv,
    unsigned short* __restrict__ xs_out)
{
    __shared__ unsigned short Kl[224][24];     // f16 K, pad cols
    __shared__ unsigned short Ql[208][24];     // f16 Q (pre-scaled)
    __shared__ unsigned short Vt[16][236];     // f16 V^T [d][k], padded

    const int bid2 = blockIdx.x;               // 2304 = 1152 x 2
    const int half = bid2 & 1;
    const int bid = bid2 >> 1;
    const int c = bid % 12;
    const int h = (bid / 12) % 12;
    const int b = bid / 144;
    const int tid = threadIdx.x;
    const int w = tid >> 6, l = tid & 63;
    const int fl = l & 15, g = l >> 4;
    const int qbase = half * 7;                // tile range start
    const int ntl = 7 - half;                  // local tile count (7 or 6)

    const float qs = 0.25f * 1.4426950408889634f;   // softmax scale * log2(e)
    for (int idx = tid; idx < N_ * 4; idx += 256) {
        const int n = idx >> 2, eq = (idx & 3) * 4;
        const unsigned short* base =
            qkv + (size_t)((b * N_ + n) * 12 + c) * NQKV_PAD + 144 + h * 16 + eq;
        const ushort4 qv = *reinterpret_cast<const ushort4*>(base);
        const ushort4 kv = *reinterpret_cast<const ushort4*>(base + 192);
        const ushort4 vv = *reinterpret_cast<const ushort4*>(base + 384);
        uint2 qsc;
        qsc.x = pk2u(h2f(qv.x) * qs, h2f(qv.y) * qs);
        qsc.y = pk2u(h2f(qv.z) * qs, h2f(qv.w) * qs);
        *reinterpret_cast<uint2*>(&Ql[n][eq]) = qsc;
        *reinterpret_cast<ushort4*>(&Kl[n][eq]) = kv;
        Vt[eq + 0][n] = vv.x;
        Vt[eq + 1][n] = vv.y;
        Vt[eq + 2][n] = vv.z;
        Vt[eq + 3][n] = vv.w;
    }
    for (int idx = tid; idx < 16 * 28; idx += 256) {
        const int d = idx / 28, n = 196 + idx % 28;
        Vt[d][n] = 0;
    }
    __syncthreads();

    f32x4 accO[2];
    float lsum[2];
    #pragma unroll
    for (int j = 0; j < 2; ++j) {
        accO[j] = (f32x4){0.f, 0.f, 0.f, 0.f};
        lsum[j] = 0.f;
    }
    const f32x4 zf = (f32x4){0.f, 0.f, 0.f, 0.f};

    f16x4 Bq[2];
    #pragma unroll
    for (int j = 0; j < 2; ++j) {
        const int qtl = w + 4 * j;
        const int qt = (qtl < ntl) ? (qbase + qtl) : 12;
        Bq[j] = *reinterpret_cast<const f16x4*>(&Ql[qt * 16 + fl][4 * g]);
    }

    for (int ch = 0; ch < 7; ++ch) {
        const int kb0 = ch * 32;
        const f16x4 Ak0 = *reinterpret_cast<const f16x4*>(&Kl[kb0 + fl][4 * g]);
        const f16x4 Ak1 = *reinterpret_cast<const f16x4*>(&Kl[kb0 + 16 + fl][4 * g]);
        const f16x4 Av0 = *reinterpret_cast<const f16x4*>(&Vt[fl][kb0 + 4 * g]);
        const f16x4 Av1 = *reinterpret_cast<const f16x4*>(&Vt[fl][kb0 + 16 + 4 * g]);

        #pragma unroll
        for (int j = 0; j < 2; ++j) {
            if (w + 4 * j >= ntl) continue;    // wave-uniform

            f32x4 T0 = __builtin_amdgcn_mfma_f32_16x16x16f16(Ak0, Bq[j], zf, 0, 0, 0);
            f32x4 T1 = __builtin_amdgcn_mfma_f32_16x16x16f16(Ak1, Bq[j], zf, 0, 0, 0);

            float s0 = T0[0], s1 = T0[1], s2 = T0[2], s3 = T0[3];
            float s4 = T1[0], s5 = T1[1], s6 = T1[2], s7 = T1[3];
            if (ch == 6) {                      // mask pad k-rows (exp2(-1e30)=0)
                const int kg = kb0 + 4 * g;
                if (kg + 0 >= 196) s0 = -1e30f;
                if (kg + 1 >= 196) s1 = -1e30f;
                if (kg + 2 >= 196) s2 = -1e30f;
                if (kg + 3 >= 196) s3 = -1e30f;
                s4 = -1e30f; s5 = -1e30f; s6 = -1e30f; s7 = -1e30f;
            }
            const float p0 = exp2f(s0), p1 = exp2f(s1);
            const float p2 = exp2f(s2), p3 = exp2f(s3);
            const float p4 = exp2f(s4), p5 = exp2f(s5);
            const float p6 = exp2f(s6), p7 = exp2f(s7);
            lsum[j] += ((p0 + p1) + (p2 + p3)) + ((p4 + p5) + (p6 + p7));

            union { unsigned u[2]; f16x4 v; } pa, pb;
            pa.u[0] = pk2u(p0, p1); pa.u[1] = pk2u(p2, p3);
            pb.u[0] = pk2u(p4, p5); pb.u[1] = pk2u(p6, p7);

            accO[j] = __builtin_amdgcn_mfma_f32_16x16x16f16(Av0, pa.v, accO[j], 0, 0, 0);
            accO[j] = __builtin_amdgcn_mfma_f32_16x16x16f16(Av1, pb.v, accO[j], 0, 0, 0);
        }
    }

    #pragma unroll
    for (int j = 0; j < 2; ++j) {
        const int qtl = w + 4 * j;
        if (qtl >= ntl) continue;
        const int qt = qbase + qtl;
        float ls = lsum[j];
        ls += __shfl_xor(ls, 16);
        ls += __shfl_xor(ls, 32);
        const int n = qt * 16 + fl;
        if (n < 196) {
            const float inv = 1.f / ls;
            uint2 o;
            o.x = pk2u(accO[j][0] * inv, accO[j][1] * inv);
            o.y = pk2u(accO[j][2] * inv, accO[j][3] * inv);
            const size_t base = ((size_t)((b * 12 + h) * N_ + n) * 12 + c) * 16 + 4 * g;
            *reinterpret_cast<uint2*>(&xs_out[base]) = o;
        }
    }
}

// ---------------------------------------------------------------------------
// Channel attention + outer-product combine, 4 rows per 256-thread block.
// f16 qkv + f16 xs in; y f16 out. (r20-verified, unchanged)
// ---------------------------------------------------------------------------
__global__ __launch_bounds__(256) void chan_attn_combine4(
    const unsigned short* __restrict__ qkv,
    const unsigned short* __restrict__ xs,
    unsigned short* __restrict__ yh)
{
    const int sub = threadIdx.x >> 6;
    const int t = threadIdx.x & 63;
    const int flat = blockIdx.x * 4 + sub;     // (b*12+h)*196 + n
    const int n = flat % 196;
    const int h = (flat / 196) % 12;
    const int b = flat / 2352;

    __shared__ float sQ[4][12][4], sK[4][12][4], sV[4][12][4], sXc[4][12][4];
    __shared__ float sXs[4][12][16];

    for (int idx = t; idx < 144; idx += 64) {
        const int c = idx / 12, rem = idx % 12, s = rem >> 2, e = rem & 3;
        const float v = h2f(qkv[(size_t)((b * N_ + n) * 12 + c) * NQKV_PAD + s * 48 + h * 4 + e]);
        if (s == 0) sQ[sub][c][e] = v;
        else if (s == 1) sK[sub][c][e] = v;
        else sV[sub][c][e] = v;
    }
    for (int idx = t; idx < 192; idx += 64) {
        const int c = idx >> 4, j = idx & 15;
        sXs[sub][c][j] = h2f(xs[((size_t)flat * 12 + c) * 16 + j]);
    }
    __syncthreads();

    if (t < 12) {
        const int c = t;
        float s[12];
        float m = -INFINITY;
        #pragma unroll
        for (int c2 = 0; c2 < 12; ++c2) {
            float d = 0.f;
            #pragma unroll
            for (int e = 0; e < 4; ++e) d += sQ[sub][c][e] * sK[sub][c2][e];
            s[c2] = d * 0.5f;
            m = fmaxf(m, s[c2]);
        }
        float lsum = 0.f;
        #pragma unroll
        for (int c2 = 0; c2 < 12; ++c2) { s[c2] = __expf(s[c2] - m); lsum += s[c2]; }
        const float inv = 1.f / lsum;
        #pragma unroll
        for (int i = 0; i < 4; ++i) {
            float a = 0.f;
            #pragma unroll
            for (int c2 = 0; c2 < 12; ++c2) a += s[c2] * sV[sub][c2][i];
            sXc[sub][c][i] = a * inv;
        }
    }
    __syncthreads();

    const size_t yrow = ((size_t)(b * N_ + n) * 12 + h) * (size_t)D_;
    #pragma unroll
    for (int k = 0; k < 12; ++k) {
        const float v = sXc[sub][k][t >> 4] * sXs[sub][k][t & 15];
        yh[yrow + k * 64 + t] = f2h(v);
    }
}

// ---------------------------------------------------------------------------
extern "C" void kernel_launch(void* const* d_in, const int* in_sizes, int n_in,
                              void* d_out, int out_size, void* d_ws, size_t ws_size,
                              hipStream_t stream) {
    const float* x       = (const float*)d_in[0];
    const float* w_qkv_c = (const float*)d_in[1];
    const float* w_qkv_s = (const float*)d_in[2];
    const float* w_proj  = (const float*)d_in[3];
    const float* b_proj  = (const float*)d_in[4];
    float* out = (float*)d_out;

    unsigned short* xh     = (unsigned short*)d_ws;               // R x 768 f16
    unsigned short* wqkv_h = xh + (size_t)R_ * KDIM;              // 768 x 768
    unsigned short* wp_h   = wqkv_h + (size_t)768 * 768;
    unsigned short* qkv_h  = wp_h + (size_t)768 * 768;            // R x 768 f16
    unsigned short* xs_h   = qkv_h + (size_t)R_ * NQKV_PAD;       // B*H*N*C*16 f16
    unsigned short* yh = xh;   // alias: x f16 dead after qkv GEMM

    {
        const int total = (R_ * KDIM + 2 * 768 * 768) / 4;
        convert_all<<<(total + 255) / 256, 256, 0, stream>>>(
            x, w_qkv_c, w_qkv_s, w_proj, xh, wqkv_h, wp_h);
    }
    {
        const int mtiles = R_ / BM, ntiles = NQKV_PAD / BN;      // 147 x 6
        gemm_f16<<<mtiles * ntiles, 512, 0, stream>>>(
            xh, wqkv_h, nullptr, nullptr, qkv_h, R_, NQKV_PAD, KDIM, ntiles);
    }
    spatial_attn_mfma<<<B_ * H_ * C_ * 2, 256, 0, stream>>>(qkv_h, xs_h);
    chan_attn_combine4<<<(B_ * H_ * N_) / 4, 256, 0, stream>>>(qkv_h, xs_h, yh);
    {
        const int mtiles = R_ / BM, ntiles = D_ / BN;            // 147 x 6
        gemm_f16<<<mtiles * ntiles, 512, 0, stream>>>(
            yh, wp_h, b_proj, out, nullptr, R_, D_, KDIM, ntiles);
    }
}

// Round 27
// 126.803 us; speedup vs baseline: 1.3788x; 1.0285x over previous
//
#include <hip/hip_runtime.h>
#include <math.h>

// Problem constants
#define B_  8
#define N_  196
#define C_  12
#define D_  768
#define H_  12
#define R_  (B_*N_*C_)      // 18816 rows
#define KDIM 768
#define NQKV_PAD 768        // 720 real qkv cols padded to 768

typedef _Float16 f16x8 __attribute__((ext_vector_type(8)));   // 8 f16 = 4 VGPR
typedef _Float16 f16x4 __attribute__((ext_vector_type(4)));   // 4 f16 = 2 VGPR
typedef __fp16 fp16x2 __attribute__((ext_vector_type(2)));    // cvt_pkrtz return type
typedef __attribute__((ext_vector_type(4))) float f32x4;

__device__ inline unsigned short f2h(float f) {
    union { _Float16 h; unsigned short u; } v; v.h = (_Float16)f; return v.u;
}
__device__ inline float h2f(unsigned short u) {
    union { unsigned short u; _Float16 h; } v; v.u = u; return (float)v.h;
}
// single-instruction packed f32x2 -> f16x2 (RTZ)
__device__ inline unsigned pk2u(float a, float b) {
    union { fp16x2 h; unsigned u; } v;
    v.h = __builtin_amdgcn_cvt_pkrtz(a, b);
    return v.u;
}

// ---------------------------------------------------------------------------
// Weights-only conversion (x conversion now fused into gemm1).
//   region 0: wqkv packed (768x768; rows<144 wc, 144..719 ws, rest zero)
//   region 1: wp (768x768)
// ---------------------------------------------------------------------------
__global__ __launch_bounds__(256) void convert_weights(
    const float* __restrict__ wc, const float* __restrict__ ws,
    const float* __restrict__ wp,
    unsigned short* __restrict__ wqkv_h, unsigned short* __restrict__ wp_h)
{
    int i = (blockIdx.x * 256 + threadIdx.x) * 4;
    float4 v; unsigned short* dh; int off;
    if (i < 768 * 768) {
        off = i;
        const int r = off / 768, k = off % 768;
        v = make_float4(0.f, 0.f, 0.f, 0.f);
        if (r < 144)      v = *reinterpret_cast<const float4*>(wc + r * 768 + k);
        else if (r < 720) v = *reinterpret_cast<const float4*>(ws + (r - 144) * 768 + k);
        dh = wqkv_h;
    } else {
        off = i - 768 * 768;
        if (off >= 768 * 768) return;
        v = *reinterpret_cast<const float4*>(wp + off);
        dh = wp_h;
    }
    uint2 h;
    h.x = pk2u(v.x, v.y);
    h.y = pk2u(v.z, v.w);
    *reinterpret_cast<uint2*>(dh + off) = h;
}

#define BM 128
#define BN 128
#define BK 64

__device__ inline void gload16(const unsigned short* src, void* ldsbase) {
    __builtin_amdgcn_global_load_lds(
        (const __attribute__((address_space(1))) unsigned int*)src,
        (__attribute__((address_space(3))) unsigned int*)ldsbase, 16, 0, 0);
}

// ---------------------------------------------------------------------------
// FUSED qkv GEMM: A = x in fp32 (reg-staged: global f32 -> pkrtz -> ds_write
// into the same swizzled layout), B = wqkv f16 via global_load_lds.
// 128x128, BK=64, 8 waves, 2-phase dbuf, counted vmcnt, f16 output.
// vmcnt FIFO per iter: prev issued [B(t)x2, Aregs(t+1)x4]; this iter issues
// [B(t+1)x2] then waits vmcnt(2) -> B(t)+Aregs(t+1) done, B(t+1) in flight.
// lgkmcnt(0) before mid-barrier publishes A(t+1) writes (read next iter).
// ---------------------------------------------------------------------------
__global__ __launch_bounds__(512, 2) void gemm_qkv_fused(
    const float* __restrict__ Af, const unsigned short* __restrict__ Bh,
    unsigned short* __restrict__ outh, int M, int Nt, int K, int ntiles)
{
    __shared__ unsigned short sA[2][BM][BK];   // 2 x 16 KB
    __shared__ unsigned short sB[2][BN][BK];   // 2 x 16 KB

    const int nwg = gridDim.x;
    const int bid = blockIdx.x;
    const int xcd = bid & 7, slot = bid >> 3;
    const int q = nwg >> 3, r = nwg & 7;
    const int wg = (xcd < r ? xcd * (q + 1) : r * (q + 1) + (xcd - r) * q) + slot;
    const int mt = wg / ntiles, nt = wg - mt * ntiles;   // nt fast: A-panel reuse
    const int m0 = mt * BM, n0 = nt * BN;

    const int tid = threadIdx.x;
    const int w = tid >> 6, l = tid & 63;
    const int fl = l & 15, g = l >> 4;
    const int wr = (w >> 2) * 64;              // wave row base
    const int wc = (w & 3) * 32;               // wave col base

    f32x4 acc[4][2];
    #pragma unroll
    for (int i = 0; i < 4; ++i)
        #pragma unroll
        for (int j = 0; j < 2; ++j)
            acc[i][j] = (f32x4){0.f, 0.f, 0.f, 0.f};

    const int srow = w * 16 + (l >> 3);
    const int scol = ((l & 7) ^ (l >> 3)) * 8;

    float4 a0, a1, a2, a3;                     // A f32 staging regs (one k-tile)

#define LOADA(kk) {                                                                         \
    const float* paf = Af + (size_t)(m0 + srow) * K + (kk) + scol;                          \
    a0 = *reinterpret_cast<const float4*>(paf);                                             \
    a1 = *reinterpret_cast<const float4*>(paf + 4);                                         \
    a2 = *reinterpret_cast<const float4*>(paf + 8 * K);                                     \
    a3 = *reinterpret_cast<const float4*>(paf + 8 * K + 4); }

#define WRITEA(buf) {                                                                       \
    char* da = (char*)sA + (buf) * 16384 + w * 2048 + l * 16;                               \
    uint4 v0 = { pk2u(a0.x,a0.y), pk2u(a0.z,a0.w), pk2u(a1.x,a1.y), pk2u(a1.z,a1.w) };      \
    uint4 v1 = { pk2u(a2.x,a2.y), pk2u(a2.z,a2.w), pk2u(a3.x,a3.y), pk2u(a3.z,a3.w) };      \
    *reinterpret_cast<uint4*>(da) = v0;                                                     \
    *reinterpret_cast<uint4*>(da + 1024) = v1; }

#define STAGEB(buf, kk) {                                                                   \
    const unsigned short* pb = Bh + (size_t)(n0 + srow) * K + (kk) + scol;                  \
    char* db = (char*)sB + (buf) * 16384 + w * 2048;                                        \
    gload16(pb,          db);                                                               \
    gload16(pb + 8 * K,  db + 1024); }

    // prologue
    LOADA(0);                                  // 4 vm
    STAGEB(0, 0);                              // 2 vm
    asm volatile("s_waitcnt vmcnt(2)" ::: "memory");    // A(0) regs done
    WRITEA(0);
    LOADA(BK);                                 // aregs(1), 4 vm
    asm volatile("s_waitcnt lgkmcnt(0)" ::: "memory");  // A(0) writes done

    const int KT = K / BK;             // 12
    int cur = 0;
    for (int t = 0; t < KT; ++t) {
        if (t + 1 < KT) {
            STAGEB(cur ^ 1, (t + 1) * BK);                     // 2 vm
            asm volatile("s_waitcnt vmcnt(2)" ::: "memory");   // B(t)+aregs(t+1) done
            WRITEA(cur ^ 1);                                   // A(t+1) -> buf^1
            if (t + 2 < KT) LOADA((t + 2) * BK);               // aregs(t+2), 4 vm
            asm volatile("s_waitcnt lgkmcnt(0)" ::: "memory"); // publish A(t+1)
        } else {
            asm volatile("s_waitcnt vmcnt(0) lgkmcnt(0)" ::: "memory");
        }
        asm volatile("s_barrier" ::: "memory");                // buf[cur] ready

        #pragma unroll
        for (int ks = 0; ks < 2; ++ks) {
            const int rcol = ((ks * 4 + g) ^ (fl & 7)) * 8;
            f16x8 ah[4];
            #pragma unroll
            for (int fm = 0; fm < 4; ++fm)
                ah[fm] = *reinterpret_cast<const f16x8*>(&sA[cur][wr + fm * 16 + fl][rcol]);
            #pragma unroll
            for (int fn = 0; fn < 2; ++fn) {
                const f16x8 bf = *reinterpret_cast<const f16x8*>(&sB[cur][wc + fn * 16 + fl][rcol]);
                #pragma unroll
                for (int fm = 0; fm < 4; ++fm)
                    acc[fm][fn] = __builtin_amdgcn_mfma_f32_16x16x32_f16(ah[fm], bf, acc[fm][fn], 0, 0, 0);
            }
        }
        asm volatile("s_barrier" ::: "memory");   // WAR fence before restaging [cur]
        cur ^= 1;
    }
#undef LOADA
#undef WRITEA
#undef STAGEB

    const int rg = g * 4;
    #pragma unroll
    for (int fm = 0; fm < 4; ++fm)
        #pragma unroll
        for (int fn = 0; fn < 2; ++fn) {
            const int row = m0 + wr + fm * 16 + rg;
            const int col = n0 + wc + fn * 16 + fl;
            #pragma unroll
            for (int rr = 0; rr < 4; ++rr)
                outh[(size_t)(row + rr) * Nt + col] = f2h(acc[fm][fn][rr]);
        }
}

// ---------------------------------------------------------------------------
// Single-f16 MFMA GEMM (r24-verified, proj only: fp32 out + bias).
// ---------------------------------------------------------------------------
__global__ __launch_bounds__(512, 2) void gemm_f16(
    const unsigned short* __restrict__ Ah, const unsigned short* __restrict__ Bh,
    const float* __restrict__ bias,
    float* __restrict__ outp, int M, int Nt, int K, int ntiles)
{
    __shared__ unsigned short sA[2][BM][BK];   // 2 x 16 KB
    __shared__ unsigned short sB[2][BN][BK];   // 2 x 16 KB

    const int nwg = gridDim.x;
    const int bid = blockIdx.x;
    const int xcd = bid & 7, slot = bid >> 3;
    const int q = nwg >> 3, r = nwg & 7;
    const int wg = (xcd < r ? xcd * (q + 1) : r * (q + 1) + (xcd - r) * q) + slot;
    const int mt = wg / ntiles, nt = wg - mt * ntiles;
    const int m0 = mt * BM, n0 = nt * BN;

    const int tid = threadIdx.x;
    const int w = tid >> 6, l = tid & 63;
    const int fl = l & 15, g = l >> 4;
    const int wr = (w >> 2) * 64;
    const int wc = (w & 3) * 32;

    f32x4 acc[4][2];
    #pragma unroll
    for (int i = 0; i < 4; ++i)
        #pragma unroll
        for (int j = 0; j < 2; ++j)
            acc[i][j] = (f32x4){0.f, 0.f, 0.f, 0.f};

    const int srow = w * 16 + (l >> 3);
    const int scol = ((l & 7) ^ (l >> 3)) * 8;

#define STAGE(buf, kk) {                                                                    \
    const unsigned short* pa = Ah + (size_t)(m0 + srow) * K + (kk) + scol;                  \
    const unsigned short* pb = Bh + (size_t)(n0 + srow) * K + (kk) + scol;                  \
    char* da = (char*)sA + (buf) * 16384 + w * 2048;                                        \
    char* db = (char*)sB + (buf) * 16384 + w * 2048;                                        \
    gload16(pa,          da);                                                               \
    gload16(pa + 8 * K,  da + 1024);                                                        \
    gload16(pb,          db);                                                               \
    gload16(pb + 8 * K,  db + 1024); }

    STAGE(0, 0);

    const int KT = K / BK;             // 12
    int cur = 0;
    for (int t = 0; t < KT; ++t) {
        if (t + 1 < KT) {
            STAGE(cur ^ 1, (t + 1) * BK);
            asm volatile("s_waitcnt vmcnt(4)" ::: "memory");
        } else {
            asm volatile("s_waitcnt vmcnt(0)" ::: "memory");
        }
        asm volatile("s_barrier" ::: "memory");

        #pragma unroll
        for (int ks = 0; ks < 2; ++ks) {
            const int rcol = ((ks * 4 + g) ^ (fl & 7)) * 8;
            f16x8 ah[4];
            #pragma unroll
            for (int fm = 0; fm < 4; ++fm)
                ah[fm] = *reinterpret_cast<const f16x8*>(&sA[cur][wr + fm * 16 + fl][rcol]);
            #pragma unroll
            for (int fn = 0; fn < 2; ++fn) {
                const f16x8 bf = *reinterpret_cast<const f16x8*>(&sB[cur][wc + fn * 16 + fl][rcol]);
                #pragma unroll
                for (int fm = 0; fm < 4; ++fm)
                    acc[fm][fn] = __builtin_amdgcn_mfma_f32_16x16x32_f16(ah[fm], bf, acc[fm][fn], 0, 0, 0);
            }
        }
        asm volatile("s_barrier" ::: "memory");
        cur ^= 1;
    }
#undef STAGE

    const int rg = g * 4;
    #pragma unroll
    for (int fm = 0; fm < 4; ++fm)
        #pragma unroll
        for (int fn = 0; fn < 2; ++fn) {
            const int row = m0 + wr + fm * 16 + rg;
            const int col = n0 + wc + fn * 16 + fl;
            const float bv = bias[col];
            #pragma unroll
            for (int rr = 0; rr < 4; ++rr)
                outp[(size_t)(row + rr) * Nt + col] = acc[fm][fn][rr] + bv;
        }
}

// ---------------------------------------------------------------------------
// MFMA spatial attention (r26-verified: pkrtz, Vt pad, 2304 blocks). Unchanged.
// ---------------------------------------------------------------------------
__global__ __launch_bounds__(256) void spatial_attn_mfma(
    const unsigned short* __restrict__ qkv,
    unsigned short* __restrict__ xs_out)
{
    __shared__ unsigned short Kl[224][24];
    __shared__ unsigned short Ql[208][24];
    __shared__ unsigned short Vt[16][236];

    const int bid2 = blockIdx.x;               // 2304 = 1152 x 2
    const int half = bid2 & 1;
    const int bid = bid2 >> 1;
    const int c = bid % 12;
    const int h = (bid / 12) % 12;
    const int b = bid / 144;
    const int tid = threadIdx.x;
    const int w = tid >> 6, l = tid & 63;
    const int fl = l & 15, g = l >> 4;
    const int qbase = half * 7;
    const int ntl = 7 - half;

    const float qs = 0.25f * 1.4426950408889634f;
    for (int idx = tid; idx < N_ * 4; idx += 256) {
        const int n = idx >> 2, eq = (idx & 3) * 4;
        const unsigned short* base =
            qkv + (size_t)((b * N_ + n) * 12 + c) * NQKV_PAD + 144 + h * 16 + eq;
        const ushort4 qv = *reinterpret_cast<const ushort4*>(base);
        const ushort4 kv = *reinterpret_cast<const ushort4*>(base + 192);
        const ushort4 vv = *reinterpret_cast<const ushort4*>(base + 384);
        uint2 qsc;
        qsc.x = pk2u(h2f(qv.x) * qs, h2f(qv.y) * qs);
        qsc.y = pk2u(h2f(qv.z) * qs, h2f(qv.w) * qs);
        *reinterpret_cast<uint2*>(&Ql[n][eq]) = qsc;
        *reinterpret_cast<ushort4*>(&Kl[n][eq]) = kv;
        Vt[eq + 0][n] = vv.x;
        Vt[eq + 1][n] = vv.y;
        Vt[eq + 2][n] = vv.z;
        Vt[eq + 3][n] = vv.w;
    }
    for (int idx = tid; idx < 16 * 28; idx += 256) {
        const int d = idx / 28, n = 196 + idx % 28;
        Vt[d][n] = 0;
    }
    __syncthreads();

    f32x4 accO[2];
    float lsum[2];
    #pragma unroll
    for (int j = 0; j < 2; ++j) {
        accO[j] = (f32x4){0.f, 0.f, 0.f, 0.f};
        lsum[j] = 0.f;
    }
    const f32x4 zf = (f32x4){0.f, 0.f, 0.f, 0.f};

    f16x4 Bq[2];
    #pragma unroll
    for (int j = 0; j < 2; ++j) {
        const int qtl = w + 4 * j;
        const int qt = (qtl < ntl) ? (qbase + qtl) : 12;
        Bq[j] = *reinterpret_cast<const f16x4*>(&Ql[qt * 16 + fl][4 * g]);
    }

    for (int ch = 0; ch < 7; ++ch) {
        const int kb0 = ch * 32;
        const f16x4 Ak0 = *reinterpret_cast<const f16x4*>(&Kl[kb0 + fl][4 * g]);
        const f16x4 Ak1 = *reinterpret_cast<const f16x4*>(&Kl[kb0 + 16 + fl][4 * g]);
        const f16x4 Av0 = *reinterpret_cast<const f16x4*>(&Vt[fl][kb0 + 4 * g]);
        const f16x4 Av1 = *reinterpret_cast<const f16x4*>(&Vt[fl][kb0 + 16 + 4 * g]);

        #pragma unroll
        for (int j = 0; j < 2; ++j) {
            if (w + 4 * j >= ntl) continue;

            f32x4 T0 = __builtin_amdgcn_mfma_f32_16x16x16f16(Ak0, Bq[j], zf, 0, 0, 0);
            f32x4 T1 = __builtin_amdgcn_mfma_f32_16x16x16f16(Ak1, Bq[j], zf, 0, 0, 0);

            float s0 = T0[0], s1 = T0[1], s2 = T0[2], s3 = T0[3];
            float s4 = T1[0], s5 = T1[1], s6 = T1[2], s7 = T1[3];
            if (ch == 6) {
                const int kg = kb0 + 4 * g;
                if (kg + 0 >= 196) s0 = -1e30f;
                if (kg + 1 >= 196) s1 = -1e30f;
                if (kg + 2 >= 196) s2 = -1e30f;
                if (kg + 3 >= 196) s3 = -1e30f;
                s4 = -1e30f; s5 = -1e30f; s6 = -1e30f; s7 = -1e30f;
            }
            const float p0 = exp2f(s0), p1 = exp2f(s1);
            const float p2 = exp2f(s2), p3 = exp2f(s3);
            const float p4 = exp2f(s4), p5 = exp2f(s5);
            const float p6 = exp2f(s6), p7 = exp2f(s7);
            lsum[j] += ((p0 + p1) + (p2 + p3)) + ((p4 + p5) + (p6 + p7));

            union { unsigned u[2]; f16x4 v; } pa, pb;
            pa.u[0] = pk2u(p0, p1); pa.u[1] = pk2u(p2, p3);
            pb.u[0] = pk2u(p4, p5); pb.u[1] = pk2u(p6, p7);

            accO[j] = __builtin_amdgcn_mfma_f32_16x16x16f16(Av0, pa.v, accO[j], 0, 0, 0);
            accO[j] = __builtin_amdgcn_mfma_f32_16x16x16f16(Av1, pb.v, accO[j], 0, 0, 0);
        }
    }

    #pragma unroll
    for (int j = 0; j < 2; ++j) {
        const int qtl = w + 4 * j;
        if (qtl >= ntl) continue;
        const int qt = qbase + qtl;
        float ls = lsum[j];
        ls += __shfl_xor(ls, 16);
        ls += __shfl_xor(ls, 32);
        const int n = qt * 16 + fl;
        if (n < 196) {
            const float inv = 1.f / ls;
            uint2 o;
            o.x = pk2u(accO[j][0] * inv, accO[j][1] * inv);
            o.y = pk2u(accO[j][2] * inv, accO[j][3] * inv);
            const size_t base = ((size_t)((b * 12 + h) * N_ + n) * 12 + c) * 16 + 4 * g;
            *reinterpret_cast<uint2*>(&xs_out[base]) = o;
        }
    }
}

// ---------------------------------------------------------------------------
// Channel attention + combine (r20-verified). Unchanged.
// ---------------------------------------------------------------------------
__global__ __launch_bounds__(256) void chan_attn_combine4(
    const unsigned short* __restrict__ qkv,
    const unsigned short* __restrict__ xs,
    unsigned short* __restrict__ yh)
{
    const int sub = threadIdx.x >> 6;
    const int t = threadIdx.x & 63;
    const int flat = blockIdx.x * 4 + sub;
    const int n = flat % 196;
    const int h = (flat / 196) % 12;
    const int b = flat / 2352;

    __shared__ float sQ[4][12][4], sK[4][12][4], sV[4][12][4], sXc[4][12][4];
    __shared__ float sXs[4][12][16];

    for (int idx = t; idx < 144; idx += 64) {
        const int c = idx / 12, rem = idx % 12, s = rem >> 2, e = rem & 3;
        const float v = h2f(qkv[(size_t)((b * N_ + n) * 12 + c) * NQKV_PAD + s * 48 + h * 4 + e]);
        if (s == 0) sQ[sub][c][e] = v;
        else if (s == 1) sK[sub][c][e] = v;
        else sV[sub][c][e] = v;
    }
    for (int idx = t; idx < 192; idx += 64) {
        const int c = idx >> 4, j = idx & 15;
        sXs[sub][c][j] = h2f(xs[((size_t)flat * 12 + c) * 16 + j]);
    }
    __syncthreads();

    if (t < 12) {
        const int c = t;
        float s[12];
        float m = -INFINITY;
        #pragma unroll
        for (int c2 = 0; c2 < 12; ++c2) {
            float d = 0.f;
            #pragma unroll
            for (int e = 0; e < 4; ++e) d += sQ[sub][c][e] * sK[sub][c2][e];
            s[c2] = d * 0.5f;
            m = fmaxf(m, s[c2]);
        }
        float lsum = 0.f;
        #pragma unroll
        for (int c2 = 0; c2 < 12; ++c2) { s[c2] = __expf(s[c2] - m); lsum += s[c2]; }
        const float inv = 1.f / lsum;
        #pragma unroll
        for (int i = 0; i < 4; ++i) {
            float a = 0.f;
            #pragma unroll
            for (int c2 = 0; c2 < 12; ++c2) a += s[c2] * sV[sub][c2][i];
            sXc[sub][c][i] = a * inv;
        }
    }
    __syncthreads();

    const size_t yrow = ((size_t)(b * N_ + n) * 12 + h) * (size_t)D_;
    #pragma unroll
    for (int k = 0; k < 12; ++k) {
        const float v = sXc[sub][k][t >> 4] * sXs[sub][k][t & 15];
        yh[yrow + k * 64 + t] = f2h(v);
    }
}

// ---------------------------------------------------------------------------
extern "C" void kernel_launch(void* const* d_in, const int* in_sizes, int n_in,
                              void* d_out, int out_size, void* d_ws, size_t ws_size,
                              hipStream_t stream) {
    const float* x       = (const float*)d_in[0];
    const float* w_qkv_c = (const float*)d_in[1];
    const float* w_qkv_s = (const float*)d_in[2];
    const float* w_proj  = (const float*)d_in[3];
    const float* b_proj  = (const float*)d_in[4];
    float* out = (float*)d_out;

    unsigned short* yh     = (unsigned short*)d_ws;               // R x 768 f16 (y)
    unsigned short* wqkv_h = yh + (size_t)R_ * KDIM;              // 768 x 768
    unsigned short* wp_h   = wqkv_h + (size_t)768 * 768;
    unsigned short* qkv_h  = wp_h + (size_t)768 * 768;            // R x 768 f16
    unsigned short* xs_h   = qkv_h + (size_t)R_ * NQKV_PAD;       // B*H*N*C*16 f16

    {
        const int total = (2 * 768 * 768) / 4;
        convert_weights<<<(total + 255) / 256, 256, 0, stream>>>(
            w_qkv_c, w_qkv_s, w_proj, wqkv_h, wp_h);
    }
    {
        const int mtiles = R_ / BM, ntiles = NQKV_PAD / BN;      // 147 x 6
        gemm_qkv_fused<<<mtiles * ntiles, 512, 0, stream>>>(
            x, wqkv_h, qkv_h, R_, NQKV_PAD, KDIM, ntiles);
    }
    spatial_attn_mfma<<<B_ * H_ * C_ * 2, 256, 0, stream>>>(qkv_h, xs_h);
    chan_attn_combine4<<<(B_ * H_ * N_) / 4, 256, 0, stream>>>(qkv_h, xs_h, yh);
    {
        const int mtiles = R_ / BM, ntiles = D_ / BN;            // 147 x 6
        gemm_f16<<<mtiles * ntiles, 512, 0, stream>>>(
            yh, wp_h, b_proj, out, R_, D_, KDIM, ntiles);
    }
}

// Round 28
// 123.378 us; speedup vs baseline: 1.4171x; 1.0278x over previous
//
#include <hip/hip_runtime.h>
#include <math.h>

// Problem constants
#define B_  8
#define N_  196
#define C_  12
#define D_  768
#define H_  12
#define R_  (B_*N_*C_)      // 18816 rows
#define KDIM 768
#define NQKV_PAD 768        // 720 real qkv cols padded to 768

typedef _Float16 f16x8 __attribute__((ext_vector_type(8)));   // 8 f16 = 4 VGPR
typedef _Float16 f16x4 __attribute__((ext_vector_type(4)));   // 4 f16 = 2 VGPR
typedef __fp16 fp16x2 __attribute__((ext_vector_type(2)));    // cvt_pkrtz return type
typedef __attribute__((ext_vector_type(4))) float f32x4;

__device__ inline unsigned short f2h(float f) {
    union { _Float16 h; unsigned short u; } v; v.h = (_Float16)f; return v.u;
}
__device__ inline float h2f(unsigned short u) {
    union { unsigned short u; _Float16 h; } v; v.u = u; return (float)v.h;
}
// single-instruction packed f32x2 -> f16x2 (RTZ)
__device__ inline unsigned pk2u(float a, float b) {
    union { fp16x2 h; unsigned u; } v;
    v.h = __builtin_amdgcn_cvt_pkrtz(a, b);
    return v.u;
}
// scale both f16 halves of a packed word
__device__ inline unsigned scale2(unsigned u, float s) {
    return pk2u(h2f((unsigned short)(u & 0xffff)) * s,
                h2f((unsigned short)(u >> 16)) * s);
}

// ---------------------------------------------------------------------------
// Weights-only conversion (r27-verified).
// ---------------------------------------------------------------------------
__global__ __launch_bounds__(256) void convert_weights(
    const float* __restrict__ wc, const float* __restrict__ ws,
    const float* __restrict__ wp,
    unsigned short* __restrict__ wqkv_h, unsigned short* __restrict__ wp_h)
{
    int i = (blockIdx.x * 256 + threadIdx.x) * 4;
    float4 v; unsigned short* dh; int off;
    if (i < 768 * 768) {
        off = i;
        const int r = off / 768, k = off % 768;
        v = make_float4(0.f, 0.f, 0.f, 0.f);
        if (r < 144)      v = *reinterpret_cast<const float4*>(wc + r * 768 + k);
        else if (r < 720) v = *reinterpret_cast<const float4*>(ws + (r - 144) * 768 + k);
        dh = wqkv_h;
    } else {
        off = i - 768 * 768;
        if (off >= 768 * 768) return;
        v = *reinterpret_cast<const float4*>(wp + off);
        dh = wp_h;
    }
    uint2 h;
    h.x = pk2u(v.x, v.y);
    h.y = pk2u(v.z, v.w);
    *reinterpret_cast<uint2*>(dh + off) = h;
}

#define BM 128
#define BN 128
#define BK 64

__device__ inline void gload16(const unsigned short* src, void* ldsbase) {
    __builtin_amdgcn_global_load_lds(
        (const __attribute__((address_space(1))) unsigned int*)src,
        (__attribute__((address_space(3))) unsigned int*)ldsbase, 16, 0, 0);
}

// ---------------------------------------------------------------------------
// FUSED qkv GEMM (r27-verified). Unchanged.
// ---------------------------------------------------------------------------
__global__ __launch_bounds__(512, 2) void gemm_qkv_fused(
    const float* __restrict__ Af, const unsigned short* __restrict__ Bh,
    unsigned short* __restrict__ outh, int M, int Nt, int K, int ntiles)
{
    __shared__ unsigned short sA[2][BM][BK];   // 2 x 16 KB
    __shared__ unsigned short sB[2][BN][BK];   // 2 x 16 KB

    const int nwg = gridDim.x;
    const int bid = blockIdx.x;
    const int xcd = bid & 7, slot = bid >> 3;
    const int q = nwg >> 3, r = nwg & 7;
    const int wg = (xcd < r ? xcd * (q + 1) : r * (q + 1) + (xcd - r) * q) + slot;
    const int mt = wg / ntiles, nt = wg - mt * ntiles;   // nt fast: A-panel reuse
    const int m0 = mt * BM, n0 = nt * BN;

    const int tid = threadIdx.x;
    const int w = tid >> 6, l = tid & 63;
    const int fl = l & 15, g = l >> 4;
    const int wr = (w >> 2) * 64;              // wave row base
    const int wc = (w & 3) * 32;               // wave col base

    f32x4 acc[4][2];
    #pragma unroll
    for (int i = 0; i < 4; ++i)
        #pragma unroll
        for (int j = 0; j < 2; ++j)
            acc[i][j] = (f32x4){0.f, 0.f, 0.f, 0.f};

    const int srow = w * 16 + (l >> 3);
    const int scol = ((l & 7) ^ (l >> 3)) * 8;

    float4 a0, a1, a2, a3;                     // A f32 staging regs (one k-tile)

#define LOADA(kk) {                                                                         \
    const float* paf = Af + (size_t)(m0 + srow) * K + (kk) + scol;                          \
    a0 = *reinterpret_cast<const float4*>(paf);                                             \
    a1 = *reinterpret_cast<const float4*>(paf + 4);                                         \
    a2 = *reinterpret_cast<const float4*>(paf + 8 * K);                                     \
    a3 = *reinterpret_cast<const float4*>(paf + 8 * K + 4); }

#define WRITEA(buf) {                                                                       \
    char* da = (char*)sA + (buf) * 16384 + w * 2048 + l * 16;                               \
    uint4 v0 = { pk2u(a0.x,a0.y), pk2u(a0.z,a0.w), pk2u(a1.x,a1.y), pk2u(a1.z,a1.w) };      \
    uint4 v1 = { pk2u(a2.x,a2.y), pk2u(a2.z,a2.w), pk2u(a3.x,a3.y), pk2u(a3.z,a3.w) };      \
    *reinterpret_cast<uint4*>(da) = v0;                                                     \
    *reinterpret_cast<uint4*>(da + 1024) = v1; }

#define STAGEB(buf, kk) {                                                                   \
    const unsigned short* pb = Bh + (size_t)(n0 + srow) * K + (kk) + scol;                  \
    char* db = (char*)sB + (buf) * 16384 + w * 2048;                                        \
    gload16(pb,          db);                                                               \
    gload16(pb + 8 * K,  db + 1024); }

    // prologue
    LOADA(0);                                  // 4 vm
    STAGEB(0, 0);                              // 2 vm
    asm volatile("s_waitcnt vmcnt(2)" ::: "memory");    // A(0) regs done
    WRITEA(0);
    LOADA(BK);                                 // aregs(1), 4 vm
    asm volatile("s_waitcnt lgkmcnt(0)" ::: "memory");  // A(0) writes done

    const int KT = K / BK;             // 12
    int cur = 0;
    for (int t = 0; t < KT; ++t) {
        if (t + 1 < KT) {
            STAGEB(cur ^ 1, (t + 1) * BK);                     // 2 vm
            asm volatile("s_waitcnt vmcnt(2)" ::: "memory");   // B(t)+aregs(t+1) done
            WRITEA(cur ^ 1);                                   // A(t+1) -> buf^1
            if (t + 2 < KT) LOADA((t + 2) * BK);               // aregs(t+2), 4 vm
            asm volatile("s_waitcnt lgkmcnt(0)" ::: "memory"); // publish A(t+1)
        } else {
            asm volatile("s_waitcnt vmcnt(0) lgkmcnt(0)" ::: "memory");
        }
        asm volatile("s_barrier" ::: "memory");                // buf[cur] ready

        #pragma unroll
        for (int ks = 0; ks < 2; ++ks) {
            const int rcol = ((ks * 4 + g) ^ (fl & 7)) * 8;
            f16x8 ah[4];
            #pragma unroll
            for (int fm = 0; fm < 4; ++fm)
                ah[fm] = *reinterpret_cast<const f16x8*>(&sA[cur][wr + fm * 16 + fl][rcol]);
            #pragma unroll
            for (int fn = 0; fn < 2; ++fn) {
                const f16x8 bf = *reinterpret_cast<const f16x8*>(&sB[cur][wc + fn * 16 + fl][rcol]);
                #pragma unroll
                for (int fm = 0; fm < 4; ++fm)
                    acc[fm][fn] = __builtin_amdgcn_mfma_f32_16x16x32_f16(ah[fm], bf, acc[fm][fn], 0, 0, 0);
            }
        }
        asm volatile("s_barrier" ::: "memory");   // WAR fence before restaging [cur]
        cur ^= 1;
    }
#undef LOADA
#undef WRITEA
#undef STAGEB

    const int rg = g * 4;
    #pragma unroll
    for (int fm = 0; fm < 4; ++fm)
        #pragma unroll
        for (int fn = 0; fn < 2; ++fn) {
            const int row = m0 + wr + fm * 16 + rg;
            const int col = n0 + wc + fn * 16 + fl;
            #pragma unroll
            for (int rr = 0; rr < 4; ++rr)
                outh[(size_t)(row + rr) * Nt + col] = f2h(acc[fm][fn][rr]);
        }
}

// ---------------------------------------------------------------------------
// Single-f16 MFMA GEMM (r24-verified, proj only: fp32 out + bias).
// ---------------------------------------------------------------------------
__global__ __launch_bounds__(512, 2) void gemm_f16(
    const unsigned short* __restrict__ Ah, const unsigned short* __restrict__ Bh,
    const float* __restrict__ bias,
    float* __restrict__ outp, int M, int Nt, int K, int ntiles)
{
    __shared__ unsigned short sA[2][BM][BK];   // 2 x 16 KB
    __shared__ unsigned short sB[2][BN][BK];   // 2 x 16 KB

    const int nwg = gridDim.x;
    const int bid = blockIdx.x;
    const int xcd = bid & 7, slot = bid >> 3;
    const int q = nwg >> 3, r = nwg & 7;
    const int wg = (xcd < r ? xcd * (q + 1) : r * (q + 1) + (xcd - r) * q) + slot;
    const int mt = wg / ntiles, nt = wg - mt * ntiles;
    const int m0 = mt * BM, n0 = nt * BN;

    const int tid = threadIdx.x;
    const int w = tid >> 6, l = tid & 63;
    const int fl = l & 15, g = l >> 4;
    const int wr = (w >> 2) * 64;
    const int wc = (w & 3) * 32;

    f32x4 acc[4][2];
    #pragma unroll
    for (int i = 0; i < 4; ++i)
        #pragma unroll
        for (int j = 0; j < 2; ++j)
            acc[i][j] = (f32x4){0.f, 0.f, 0.f, 0.f};

    const int srow = w * 16 + (l >> 3);
    const int scol = ((l & 7) ^ (l >> 3)) * 8;

#define STAGE(buf, kk) {                                                                    \
    const unsigned short* pa = Ah + (size_t)(m0 + srow) * K + (kk) + scol;                  \
    const unsigned short* pb = Bh + (size_t)(n0 + srow) * K + (kk) + scol;                  \
    char* da = (char*)sA + (buf) * 16384 + w * 2048;                                        \
    char* db = (char*)sB + (buf) * 16384 + w * 2048;                                        \
    gload16(pa,          da);                                                               \
    gload16(pa + 8 * K,  da + 1024);                                                        \
    gload16(pb,          db);                                                               \
    gload16(pb + 8 * K,  db + 1024); }

    STAGE(0, 0);

    const int KT = K / BK;             // 12
    int cur = 0;
    for (int t = 0; t < KT; ++t) {
        if (t + 1 < KT) {
            STAGE(cur ^ 1, (t + 1) * BK);
            asm volatile("s_waitcnt vmcnt(4)" ::: "memory");
        } else {
            asm volatile("s_waitcnt vmcnt(0)" ::: "memory");
        }
        asm volatile("s_barrier" ::: "memory");

        #pragma unroll
        for (int ks = 0; ks < 2; ++ks) {
            const int rcol = ((ks * 4 + g) ^ (fl & 7)) * 8;
            f16x8 ah[4];
            #pragma unroll
            for (int fm = 0; fm < 4; ++fm)
                ah[fm] = *reinterpret_cast<const f16x8*>(&sA[cur][wr + fm * 16 + fl][rcol]);
            #pragma unroll
            for (int fn = 0; fn < 2; ++fn) {
                const f16x8 bf = *reinterpret_cast<const f16x8*>(&sB[cur][wc + fn * 16 + fl][rcol]);
                #pragma unroll
                for (int fm = 0; fm < 4; ++fm)
                    acc[fm][fn] = __builtin_amdgcn_mfma_f32_16x16x32_f16(ah[fm], bf, acc[fm][fn], 0, 0, 0);
            }
        }
        asm volatile("s_barrier" ::: "memory");
        cur ^= 1;
    }
#undef STAGE

    const int rg = g * 4;
    #pragma unroll
    for (int fm = 0; fm < 4; ++fm)
        #pragma unroll
        for (int fn = 0; fn < 2; ++fn) {
            const int row = m0 + wr + fm * 16 + rg;
            const int col = n0 + wc + fn * 16 + fl;
            const float bv = bias[col];
            #pragma unroll
            for (int rr = 0; rr < 4; ++rr)
                outp[(size_t)(row + rr) * Nt + col] = acc[fm][fn][rr] + bv;
        }
}

// ---------------------------------------------------------------------------
// MFMA spatial attention. THIS ROUND: 16B uint4 staging (392 iters, was 784).
// ---------------------------------------------------------------------------
__global__ __launch_bounds__(256) void spatial_attn_mfma(
    const unsigned short* __restrict__ qkv,
    unsigned short* __restrict__ xs_out)
{
    __shared__ unsigned short Kl[224][24];
    __shared__ unsigned short Ql[208][24];
    __shared__ unsigned short Vt[16][236];

    const int bid2 = blockIdx.x;               // 2304 = 1152 x 2
    const int half = bid2 & 1;
    const int bid = bid2 >> 1;
    const int c = bid % 12;
    const int h = (bid / 12) % 12;
    const int b = bid / 144;
    const int tid = threadIdx.x;
    const int w = tid >> 6, l = tid & 63;
    const int fl = l & 15, g = l >> 4;
    const int qbase = half * 7;
    const int ntl = 7 - half;

    const float qs = 0.25f * 1.4426950408889634f;
    for (int idx = tid; idx < N_ * 2; idx += 256) {
        const int n = idx >> 1, eh = (idx & 1) * 8;   // 8 f16 per load
        const unsigned short* base =
            qkv + (size_t)((b * N_ + n) * 12 + c) * NQKV_PAD + 144 + h * 16 + eh;
        const uint4 q4 = *reinterpret_cast<const uint4*>(base);
        const uint4 k4 = *reinterpret_cast<const uint4*>(base + 192);
        const uint4 v4 = *reinterpret_cast<const uint4*>(base + 384);
        uint4 qsc;
        qsc.x = scale2(q4.x, qs); qsc.y = scale2(q4.y, qs);
        qsc.z = scale2(q4.z, qs); qsc.w = scale2(q4.w, qs);
        *reinterpret_cast<uint4*>(&Ql[n][eh]) = qsc;
        *reinterpret_cast<uint4*>(&Kl[n][eh]) = k4;
        Vt[eh + 0][n] = (unsigned short)(v4.x & 0xffff);
        Vt[eh + 1][n] = (unsigned short)(v4.x >> 16);
        Vt[eh + 2][n] = (unsigned short)(v4.y & 0xffff);
        Vt[eh + 3][n] = (unsigned short)(v4.y >> 16);
        Vt[eh + 4][n] = (unsigned short)(v4.z & 0xffff);
        Vt[eh + 5][n] = (unsigned short)(v4.z >> 16);
        Vt[eh + 6][n] = (unsigned short)(v4.w & 0xffff);
        Vt[eh + 7][n] = (unsigned short)(v4.w >> 16);
    }
    for (int idx = tid; idx < 16 * 28; idx += 256) {
        const int d = idx / 28, n = 196 + idx % 28;
        Vt[d][n] = 0;
    }
    __syncthreads();

    f32x4 accO[2];
    float lsum[2];
    #pragma unroll
    for (int j = 0; j < 2; ++j) {
        accO[j] = (f32x4){0.f, 0.f, 0.f, 0.f};
        lsum[j] = 0.f;
    }
    const f32x4 zf = (f32x4){0.f, 0.f, 0.f, 0.f};

    f16x4 Bq[2];
    #pragma unroll
    for (int j = 0; j < 2; ++j) {
        const int qtl = w + 4 * j;
        const int qt = (qtl < ntl) ? (qbase + qtl) : 12;
        Bq[j] = *reinterpret_cast<const f16x4*>(&Ql[qt * 16 + fl][4 * g]);
    }

    for (int ch = 0; ch < 7; ++ch) {
        const int kb0 = ch * 32;
        const f16x4 Ak0 = *reinterpret_cast<const f16x4*>(&Kl[kb0 + fl][4 * g]);
        const f16x4 Ak1 = *reinterpret_cast<const f16x4*>(&Kl[kb0 + 16 + fl][4 * g]);
        const f16x4 Av0 = *reinterpret_cast<const f16x4*>(&Vt[fl][kb0 + 4 * g]);
        const f16x4 Av1 = *reinterpret_cast<const f16x4*>(&Vt[fl][kb0 + 16 + 4 * g]);

        #pragma unroll
        for (int j = 0; j < 2; ++j) {
            if (w + 4 * j >= ntl) continue;

            f32x4 T0 = __builtin_amdgcn_mfma_f32_16x16x16f16(Ak0, Bq[j], zf, 0, 0, 0);
            f32x4 T1 = __builtin_amdgcn_mfma_f32_16x16x16f16(Ak1, Bq[j], zf, 0, 0, 0);

            float s0 = T0[0], s1 = T0[1], s2 = T0[2], s3 = T0[3];
            float s4 = T1[0], s5 = T1[1], s6 = T1[2], s7 = T1[3];
            if (ch == 6) {
                const int kg = kb0 + 4 * g;
                if (kg + 0 >= 196) s0 = -1e30f;
                if (kg + 1 >= 196) s1 = -1e30f;
                if (kg + 2 >= 196) s2 = -1e30f;
                if (kg + 3 >= 196) s3 = -1e30f;
                s4 = -1e30f; s5 = -1e30f; s6 = -1e30f; s7 = -1e30f;
            }
            const float p0 = exp2f(s0), p1 = exp2f(s1);
            const float p2 = exp2f(s2), p3 = exp2f(s3);
            const float p4 = exp2f(s4), p5 = exp2f(s5);
            const float p6 = exp2f(s6), p7 = exp2f(s7);
            lsum[j] += ((p0 + p1) + (p2 + p3)) + ((p4 + p5) + (p6 + p7));

            union { unsigned u[2]; f16x4 v; } pa, pb;
            pa.u[0] = pk2u(p0, p1); pa.u[1] = pk2u(p2, p3);
            pb.u[0] = pk2u(p4, p5); pb.u[1] = pk2u(p6, p7);

            accO[j] = __builtin_amdgcn_mfma_f32_16x16x16f16(Av0, pa.v, accO[j], 0, 0, 0);
            accO[j] = __builtin_amdgcn_mfma_f32_16x16x16f16(Av1, pb.v, accO[j], 0, 0, 0);
        }
    }

    #pragma unroll
    for (int j = 0; j < 2; ++j) {
        const int qtl = w + 4 * j;
        if (qtl >= ntl) continue;
        const int qt = qbase + qtl;
        float ls = lsum[j];
        ls += __shfl_xor(ls, 16);
        ls += __shfl_xor(ls, 32);
        const int n = qt * 16 + fl;
        if (n < 196) {
            const float inv = 1.f / ls;
            uint2 o;
            o.x = pk2u(accO[j][0] * inv, accO[j][1] * inv);
            o.y = pk2u(accO[j][2] * inv, accO[j][3] * inv);
            const size_t base = ((size_t)((b * 12 + h) * N_ + n) * 12 + c) * 16 + 4 * g;
            *reinterpret_cast<uint2*>(&xs_out[base]) = o;
        }
    }
}

// ---------------------------------------------------------------------------
// Channel attention + combine. THIS ROUND: vectorized ushort4 staging.
// ---------------------------------------------------------------------------
__global__ __launch_bounds__(256) void chan_attn_combine4(
    const unsigned short* __restrict__ qkv,
    const unsigned short* __restrict__ xs,
    unsigned short* __restrict__ yh)
{
    const int sub = threadIdx.x >> 6;
    const int t = threadIdx.x & 63;
    const int flat = blockIdx.x * 4 + sub;
    const int n = flat % 196;
    const int h = (flat / 196) % 12;
    const int b = flat / 2352;

    __shared__ float sQ[4][12][4], sK[4][12][4], sV[4][12][4], sXc[4][12][4];
    __shared__ float sXs[4][12][16];

    if (t < 36) {                              // (c, s) pairs: 12 x 3
        const int cc = t / 3, s = t % 3;
        const unsigned short* p =
            qkv + (size_t)((b * N_ + n) * 12 + cc) * NQKV_PAD + s * 48 + h * 4;
        const ushort4 v4 = *reinterpret_cast<const ushort4*>(p);
        float* dst = (s == 0) ? &sQ[sub][cc][0] : (s == 1) ? &sK[sub][cc][0] : &sV[sub][cc][0];
        dst[0] = h2f(v4.x); dst[1] = h2f(v4.y); dst[2] = h2f(v4.z); dst[3] = h2f(v4.w);
    }
    if (t < 48) {                              // (c, j-group): 12 x 4
        const int cc = t >> 2, j0 = (t & 3) * 4;
        const ushort4 v4 =
            *reinterpret_cast<const ushort4*>(&xs[((size_t)flat * 12 + cc) * 16 + j0]);
        sXs[sub][cc][j0 + 0] = h2f(v4.x);
        sXs[sub][cc][j0 + 1] = h2f(v4.y);
        sXs[sub][cc][j0 + 2] = h2f(v4.z);
        sXs[sub][cc][j0 + 3] = h2f(v4.w);
    }
    __syncthreads();

    if (t < 12) {
        const int c = t;
        float s[12];
        float m = -INFINITY;
        #pragma unroll
        for (int c2 = 0; c2 < 12; ++c2) {
            float d = 0.f;
            #pragma unroll
            for (int e = 0; e < 4; ++e) d += sQ[sub][c][e] * sK[sub][c2][e];
            s[c2] = d * 0.5f;
            m = fmaxf(m, s[c2]);
        }
        float lsum = 0.f;
        #pragma unroll
        for (int c2 = 0; c2 < 12; ++c2) { s[c2] = __expf(s[c2] - m); lsum += s[c2]; }
        const float inv = 1.f / lsum;
        #pragma unroll
        for (int i = 0; i < 4; ++i) {
            float a = 0.f;
            #pragma unroll
            for (int c2 = 0; c2 < 12; ++c2) a += s[c2] * sV[sub][c2][i];
            sXc[sub][c][i] = a * inv;
        }
    }
    __syncthreads();

    const size_t yrow = ((size_t)(b * N_ + n) * 12 + h) * (size_t)D_;
    #pragma unroll
    for (int k = 0; k < 12; ++k) {
        const float v = sXc[sub][k][t >> 4] * sXs[sub][k][t & 15];
        yh[yrow + k * 64 + t] = f2h(v);
    }
}

// ---------------------------------------------------------------------------
extern "C" void kernel_launch(void* const* d_in, const int* in_sizes, int n_in,
                              void* d_out, int out_size, void* d_ws, size_t ws_size,
                              hipStream_t stream) {
    const float* x       = (const float*)d_in[0];
    const float* w_qkv_c = (const float*)d_in[1];
    const float* w_qkv_s = (const float*)d_in[2];
    const float* w_proj  = (const float*)d_in[3];
    const float* b_proj  = (const float*)d_in[4];
    float* out = (float*)d_out;

    unsigned short* yh     = (unsigned short*)d_ws;               // R x 768 f16 (y)
    unsigned short* wqkv_h = yh + (size_t)R_ * KDIM;              // 768 x 768
    unsigned short* wp_h   = wqkv_h + (size_t)768 * 768;
    unsigned short* qkv_h  = wp_h + (size_t)768 * 768;            // R x 768 f16
    unsigned short* xs_h   = qkv_h + (size_t)R_ * NQKV_PAD;       // B*H*N*C*16 f16

    {
        const int total = (2 * 768 * 768) / 4;
        convert_weights<<<(total + 255) / 256, 256, 0, stream>>>(
            w_qkv_c, w_qkv_s, w_proj, wqkv_h, wp_h);
    }
    {
        const int mtiles = R_ / BM, ntiles = NQKV_PAD / BN;      // 147 x 6
        gemm_qkv_fused<<<mtiles * ntiles, 512, 0, stream>>>(
            x, wqkv_h, qkv_h, R_, NQKV_PAD, KDIM, ntiles);
    }
    spatial_attn_mfma<<<B_ * H_ * C_ * 2, 256, 0, stream>>>(qkv_h, xs_h);
    chan_attn_combine4<<<(B_ * H_ * N_) / 4, 256, 0, stream>>>(qkv_h, xs_h, yh);
    {
        const int mtiles = R_ / BM, ntiles = D_ / BN;            // 147 x 6
        gemm_f16<<<mtiles * ntiles, 512, 0, stream>>>(
            yh, wp_h, b_proj, out, R_, D_, KDIM, ntiles);
    }
}